// Round 2
// baseline (17774.715 us; speedup 1.0000x reference)
//
#include <hip/hip_runtime.h>

// MM_LSTM_Age_v2: 22-LSTM recurrent model on MI355X.
// Time-chunked pipeline (chunk size CH adapted to ws_size):
//   k0a/k0b weight transpose+bf16 -> per chunk: k1 eco xW -> rec<0> ->
//   gemm<0> (data/att xW) -> rec<1> -> gemm<1> (ts xW, prod fused) -> rec<2>
//   -> after last chunk: k7 dense1 -> k8 dense2+final.
// Recurrences: 8 column-WGs x 2 batch-WGs per LSTM, Wr bf16 resident in LDS,
// h broadcast via double-buffered global + device-scope atomic group barrier,
// c-state carried across chunks in global cstate.

#define TT 365

typedef short bf16x8 __attribute__((ext_vector_type(8)));
typedef unsigned short u16x8 __attribute__((ext_vector_type(8)));
typedef float f32x4 __attribute__((ext_vector_type(4)));

__device__ __forceinline__ float b2f(unsigned short u) {
  union { unsigned u32; float f; } v; v.u32 = ((unsigned)u) << 16; return v.f;
}
__device__ __forceinline__ unsigned short f2b(float f) {
  union { float f; unsigned u32; } v; v.f = f;
  unsigned u = v.u32;
  u = u + 0x7FFFu + ((u >> 16) & 1u);   // RNE
  return (unsigned short)(u >> 16);
}
__device__ __forceinline__ float sigf(float x) { return 1.0f / (1.0f + __expf(-x)); }
__device__ __forceinline__ float tanh_(float x) { return 2.0f / (1.0f + __expf(-2.0f * x)) - 1.0f; }

// ------------------------------------------------ k0a: Wr transpose -> bf16
// wr_swz layout per (lstm,wg): [kb 8][col 128][ks 32], col = gate*32+hi
__global__ __launch_bounds__(256) void k0a_wr(const float* __restrict__ eco_Wr,
    const float* __restrict__ data_Wr, const float* __restrict__ att_Wr,
    const float* __restrict__ ts_Wr, unsigned short* __restrict__ wr_swz)
{
  __shared__ float ls[32 * 133];
  const int kb = blockIdx.x, wg = blockIdx.y, l = blockIdx.z, tid = threadIdx.x;
  const float* src;
  if (l == 0) src = eco_Wr;
  else if (l < 15) { int d = l - 1; src = ((d & 1) ? att_Wr : data_Wr) + (size_t)(d >> 1) * 262144; }
  else src = ts_Wr + (size_t)(l - 15) * 262144;
  for (int e = tid; e < 4096; e += 256) {
    int ks = e >> 7, col = e & 127;
    int gate = col >> 5, hi = col & 31;
    ls[ks * 133 + col] = src[(size_t)(kb * 32 + ks) * 1024 + gate * 256 + wg * 32 + hi];
  }
  __syncthreads();
  unsigned short* out = wr_swz + (((size_t)l * 8 + wg) * 8 + kb) * 4096;
  for (int e = tid; e < 4096; e += 256) {
    int col = e >> 5, ks = e & 31;
    out[e] = f2b(ls[ks * 133 + col]);
  }
}

// ------------------------------------------------ k0b: Wk transpose -> bf16
// wk layout per lstm: [kb 8][col 1024][ks 32] (data/att: K rows 4..259)
__global__ __launch_bounds__(256) void k0b_wk(const float* __restrict__ data_Wk,
    const float* __restrict__ att_Wk, const float* __restrict__ ts_Wk,
    unsigned short* __restrict__ wk_da, unsigned short* __restrict__ wk_ts)
{
  __shared__ float ls[32 * 261];
  const int cc = blockIdx.x, kb = blockIdx.y, d = blockIdx.z, tid = threadIdx.x;
  const float* src; unsigned short* dst; int roff;
  if (d < 14) { src = ((d & 1) ? att_Wk : data_Wk) + (size_t)(d >> 1) * 266240;
                dst = wk_da + (size_t)d * 262144; roff = 4; }
  else { src = ts_Wk + (size_t)(d - 14) * 262144;
         dst = wk_ts + (size_t)(d - 14) * 262144; roff = 0; }
  for (int e = tid; e < 8192; e += 256) {
    int ks = e >> 8, c2 = e & 255;
    ls[ks * 261 + c2] = src[(size_t)(roff + kb * 32 + ks) * 1024 + cc * 256 + c2];
  }
  __syncthreads();
  for (int e = tid; e < 8192; e += 256) {
    int col2 = e >> 5, ks = e & 31;
    dst[(size_t)kb * 32768 + (cc * 256 + col2) * 32 + ks] = f2b(ls[ks * 261 + col2]);
  }
}

// ------------------------------------------------ k1: eco xW (chunk-local out)
__global__ __launch_bounds__(256) void k1_ecoxw(const float* __restrict__ inputs,
    const float* __restrict__ eco_Wk, const float* __restrict__ eco_b,
    unsigned short* __restrict__ xw_eco, int t0)
{
  __shared__ float Asl[64 * 35];
  __shared__ float Bsl[35 * 256];
  const int tl = blockIdx.x, ct = blockIdx.y, tid = threadIdx.x;
  const int tg = t0 + tl;
  for (int i = tid; i < 64 * 35; i += 256) {
    int b = i / 35, k = i - b * 35;
    int col = (k < 20) ? k : (k + 7);          // eco input = cols [0..19, 27..41]
    Asl[i] = inputs[((size_t)b * TT + tg) * 42 + col];
  }
  for (int i = tid; i < 35 * 256; i += 256) {
    int k = i >> 8, c = i & 255;
    Bsl[i] = eco_Wk[(size_t)k * 1024 + ct * 256 + c];
  }
  __syncthreads();
  const float bias = eco_b[ct * 256 + tid];
  for (int r = 0; r < 64; ++r) {
    float s = bias;
    #pragma unroll
    for (int k = 0; k < 35; ++k) s += Asl[r * 35 + k] * Bsl[k * 256 + tid];
    xw_eco[((size_t)tl * 64 + r) * 1024 + ct * 256 + tid] = f2b(s);
  }
}

// ------------------------------------------------ recurrence
// grid (wg 8, bg 2, l). 256 threads. Per WG: 32 batch rows x 32 hidden units.
// xw/hs pointers are chunk bases (local t = t - t0); hbrd/bars use global t.
template<int STAGE>
__global__ __launch_bounds__(256, 1) void rec_kernel(
    const unsigned short* __restrict__ wr_swz_g,
    const unsigned short* __restrict__ xw_base,
    unsigned short* __restrict__ hbrd_base,
    int* __restrict__ bars,
    unsigned short* __restrict__ hsA,
    unsigned short* __restrict__ hsB,
    float* __restrict__ h_last,
    float* __restrict__ cstate,
    int t0, int t1)
{
  __shared__ __align__(16) unsigned short WR[8 * 128 * 40];  // 81920 B
  __shared__ __align__(16) unsigned short Hs[8 * 32 * 40];   // 20480 B
  __shared__ float zsh[32 * 132];                            // 16896 B
  __shared__ float cst[32 * 32];                             //  4096 B

  const int tid = threadIdx.x;
  const int wg = blockIdx.x;
  const int bg = blockIdx.y;
  const int l  = blockIdx.z;
  const int len = t1 - t0;
  const int lg = (STAGE == 0) ? 0 : (STAGE == 1 ? 1 + l : 15 + l);
  const unsigned short* xw = xw_base + (size_t)l * len * 65536;
  const unsigned short* wr_g = wr_swz_g + ((size_t)lg * 8 + wg) * 32768;
  unsigned short* hbrd = hbrd_base + (size_t)(lg * 2 + bg) * 16384;
  int* bar = bars + (lg * 2 + bg) * 16;
  float* cs = cstate + (((size_t)lg * 8 + wg) * 2 + bg) * 1024;
  unsigned short* hs_out = nullptr;
  if (STAGE == 0) hs_out = hsA;
  else if (STAGE == 1) hs_out = ((l & 1) ? hsB : hsA) + (size_t)(l >> 1) * len * 16384;
  const bool act_sig = (STAGE == 1) && (l & 1);

  // stage Wr slice into LDS (fragment-ordered in global; add pad-40)
  for (int i = tid * 8; i < 32768; i += 2048) {
    int kb = i >> 12; int rr = i & 4095; int col = rr >> 5; int ks = rr & 31;
    *(uint4*)&WR[(kb * 128 + col) * 40 + ks] = *(const uint4*)&wr_g[i];
  }
  if (t0 == 0) { for (int i = tid; i < 1024; i += 256) cst[i] = 0.0f; }
  else         { for (int i = tid; i < 1024; i += 256) cst[i] = cs[i]; }

  const int lane = tid & 63;
  const int w = tid >> 6;       // wave == gate index
  const int c = lane & 15;
  const int grp = lane >> 4;

  int xoff[16];
  #pragma unroll
  for (int rt = 0; rt < 2; ++rt)
    #pragma unroll
    for (int ct = 0; ct < 2; ++ct)
      #pragma unroll
      for (int rg = 0; rg < 4; ++rg)
        xoff[(rt * 2 + ct) * 4 + rg] =
            (bg * 32 + rt * 16 + grp * 4 + rg) * 1024 + w * 256 + wg * 32 + ct * 16 + c;

  unsigned short xva[16], xvb[16];
  #pragma unroll
  for (int i = 0; i < 16; ++i) xva[i] = xw[xoff[i]];
  __syncthreads();

  auto step = [&](int t, unsigned short (&cur)[16], unsigned short (&nxt)[16]) {
    if (t > t0) {
      if (tid == 0) {
        while (__hip_atomic_load(bar, __ATOMIC_ACQUIRE, __HIP_MEMORY_SCOPE_AGENT) < 8 * t) {
          __builtin_amdgcn_s_sleep(1);
        }
      }
      __syncthreads();
    }
    {  // load h broadcast -> Hs (fragment swizzle, pad 40)
      const unsigned short* hb = hbrd + (t & 1) * 8192;
      #pragma unroll
      for (int i = 0; i < 4; ++i) {
        int e = tid * 8 + i * 2048;
        int row = e >> 8; int k = e & 255; int kb = k >> 5; int ks = k & 31;
        *(uint4*)&Hs[(kb * 32 + row) * 40 + ks] = *(const uint4*)&hb[e];
      }
    }
    __syncthreads();
    f32x4 acc[4];
    #pragma unroll
    for (int i = 0; i < 4; ++i)
      #pragma unroll
      for (int rg = 0; rg < 4; ++rg)
        acc[i][rg] = b2f(cur[i * 4 + rg]);     // acc init = xW[t] (bias folded)
    if (t + 1 < t1) {                          // prefetch xW[t+1] into regs
      const unsigned short* xw1 = xw + (size_t)(t + 1 - t0) * 65536;
      #pragma unroll
      for (int i = 0; i < 16; ++i) nxt[i] = xw1[xoff[i]];
    }
    #pragma unroll
    for (int kb = 0; kb < 8; ++kb) {
      bf16x8 a0 = *(const bf16x8*)&Hs[(kb * 32 + c) * 40 + grp * 8];
      bf16x8 a1 = *(const bf16x8*)&Hs[(kb * 32 + 16 + c) * 40 + grp * 8];
      bf16x8 b0 = *(const bf16x8*)&WR[(kb * 128 + w * 32 + c) * 40 + grp * 8];
      bf16x8 b1 = *(const bf16x8*)&WR[(kb * 128 + w * 32 + 16 + c) * 40 + grp * 8];
      acc[0] = __builtin_amdgcn_mfma_f32_16x16x32_bf16(a0, b0, acc[0], 0, 0, 0);
      acc[1] = __builtin_amdgcn_mfma_f32_16x16x32_bf16(a0, b1, acc[1], 0, 0, 0);
      acc[2] = __builtin_amdgcn_mfma_f32_16x16x32_bf16(a1, b0, acc[2], 0, 0, 0);
      acc[3] = __builtin_amdgcn_mfma_f32_16x16x32_bf16(a1, b1, acc[3], 0, 0, 0);
    }
    #pragma unroll
    for (int i = 0; i < 4; ++i) {
      int rt = i >> 1, ct = i & 1;
      #pragma unroll
      for (int rg = 0; rg < 4; ++rg) {
        int row = rt * 16 + grp * 4 + rg;
        int colL = w * 32 + ct * 16 + c;
        zsh[row * 132 + colL] = acc[i][rg];
      }
    }
    __syncthreads();
    {  // elementwise LSTM cell update
      int u = tid;
      #pragma unroll
      for (int it = 0; it < 4; ++it, u += 256) {
        int row = u >> 5; int hi = u & 31;
        float zi = zsh[row * 132 + hi];
        float zf = zsh[row * 132 + 32 + hi];
        float zg = zsh[row * 132 + 64 + hi];
        float zo = zsh[row * 132 + 96 + hi];
        float c0 = cst[u];
        float iv = sigf(zi), fv = sigf(zf), ov = sigf(zo);
        float gv = act_sig ? sigf(zg) : tanh_(zg);
        float cn = fv * c0 + iv * gv;
        float hv = ov * (act_sig ? sigf(cn) : tanh_(cn));
        cst[u] = cn;
        unsigned short h16 = f2b(hv);
        hbrd[((t + 1) & 1) * 8192 + row * 256 + wg * 32 + hi] = h16;
        if (STAGE != 2) {
          hs_out[((size_t)(t - t0) * 64 + bg * 32 + row) * 256 + wg * 32 + hi] = h16;
        } else if (t == TT - 1) {
          h_last[(size_t)l * 16384 + (bg * 32 + row) * 256 + wg * 32 + hi] = hv;
        }
      }
    }
    __threadfence();
    __syncthreads();
    if (tid == 0) __hip_atomic_fetch_add(bar, 1, __ATOMIC_RELEASE, __HIP_MEMORY_SCOPE_AGENT);
  };

  for (int t = t0; t < t1; t += 2) {
    step(t, xva, xvb);
    if (t + 1 < t1) step(t + 1, xvb, xva);
  }
  // persist c-state for next chunk (same thread->unit mapping as updates)
  for (int i = tid; i < 1024; i += 256) cs[i] = cst[i];
}

// ------------------------------------------------ xW GEMMs
// MODE 0: data/att xW (A = hs_eco chunk, +4 special K-rows in epilogue)
// MODE 1: ts xW (A = data_hs*att_hs fused product, chunk)
// grid (tl len, nt 8, z). out tile 64x128, K=256 in two halves.
template<int MODE>
__global__ __launch_bounds__(256, 2) void gemm_xw(
    const unsigned short* __restrict__ A1,
    const unsigned short* __restrict__ A2,
    const unsigned short* __restrict__ Bsw_base,
    const float* __restrict__ spWk_d, const float* __restrict__ spWk_a,
    const float* __restrict__ bias_d, const float* __restrict__ bias_a,
    const float* __restrict__ inputs,
    unsigned short* __restrict__ xw_out_base,
    int t0)
{
  __shared__ __align__(16) unsigned short Als[4 * 64 * 40];    // 20480 B (reused as out-stage)
  __shared__ __align__(16) unsigned short Bls[4 * 128 * 40];   // 40960 B
  __shared__ float a_sp[64 * 4];
  __shared__ float b_sp[4 * 128];
  __shared__ float bias_s[128];

  const int tid = threadIdx.x;
  const int tl = blockIdx.x, nt = blockIdx.y, z = blockIdx.z;
  const int len = gridDim.x;
  const int tg = t0 + tl;

  const unsigned short* Apt;
  const unsigned short* Apt2 = nullptr;
  const unsigned short* Bsw;
  const float* bias;
  unsigned short* xw_out;
  int br;
  if (MODE == 0) {
    br = z >> 1;
    Apt = A1;
    Bsw = Bsw_base + (size_t)z * 262144;
    bias = ((z & 1) ? bias_a : bias_d) + br * 1024;
  } else {
    br = z;
    Apt  = A1 + (size_t)z * len * 16384;
    Apt2 = A2 + (size_t)z * len * 16384;
    Bsw = Bsw_base + (size_t)z * 262144;
    bias = bias_d + z * 1024;
  }
  xw_out = xw_out_base + ((size_t)z * len + tl) * 65536;

  if (MODE == 0) {
    const float* spWk = ((z & 1) ? spWk_a : spWk_d) + (size_t)br * 266240;
    for (int i = tid; i < 4 * 128; i += 256) {
      int j = i >> 7; int cl = i & 127;
      b_sp[i] = spWk[(size_t)j * 1024 + nt * 128 + cl];
    }
    if (tid < 64) {
      const float* ip = inputs + ((size_t)tid * TT + tg) * 42;
      a_sp[tid * 4 + 0] = ip[20 + br];
      a_sp[tid * 4 + 1] = ip[27];
      a_sp[tid * 4 + 2] = ip[27 + br + 1];
      a_sp[tid * 4 + 3] = ip[27 + br + 8];
    }
  }
  if (tid < 128) bias_s[tid] = bias[nt * 128 + tid];

  const int lane = tid & 63, w = tid >> 6, c = lane & 15, grp = lane >> 4;
  f32x4 acc[8] = {};

  for (int kh = 0; kh < 2; ++kh) {
    #pragma unroll
    for (int ii = 0; ii < 4; ++ii) {       // A: 64 rows x 128 k
      int e = tid * 8 + ii * 2048;
      int row = e >> 7; int k = e & 127; int kb = k >> 5; int ks = k & 31;
      size_t g = ((size_t)tl * 64 + row) * 256 + kh * 128 + k;
      if (MODE == 0) {
        *(uint4*)&Als[(kb * 64 + row) * 40 + ks] = *(const uint4*)&Apt[g];
      } else {
        u16x8 vd = *(const u16x8*)&Apt[g];
        u16x8 va = *(const u16x8*)&Apt2[g];
        u16x8 vp;
        #pragma unroll
        for (int j = 0; j < 8; ++j) vp[j] = f2b(b2f(vd[j]) * b2f(va[j]));
        *(u16x8*)&Als[(kb * 64 + row) * 40 + ks] = vp;
      }
    }
    #pragma unroll
    for (int ii = 0; ii < 8; ++ii) {       // B: 128 cols x 128 k
      int e = tid * 8 + ii * 2048;
      int kbl = e >> 12; int rr = e & 4095; int cl = rr >> 5; int ks = rr & 31;
      size_t g = ((size_t)((kh * 4 + kbl) * 1024 + nt * 128 + cl)) * 32 + ks;
      *(uint4*)&Bls[(kbl * 128 + cl) * 40 + ks] = *(const uint4*)&Bsw[g];
    }
    __syncthreads();
    #pragma unroll
    for (int kbl = 0; kbl < 4; ++kbl) {
      bf16x8 a[4]; bf16x8 b[2];
      #pragma unroll
      for (int rt = 0; rt < 4; ++rt) a[rt] = *(const bf16x8*)&Als[(kbl * 64 + rt * 16 + c) * 40 + grp * 8];
      #pragma unroll
      for (int ct = 0; ct < 2; ++ct) b[ct] = *(const bf16x8*)&Bls[(kbl * 128 + w * 32 + ct * 16 + c) * 40 + grp * 8];
      #pragma unroll
      for (int rt = 0; rt < 4; ++rt)
        #pragma unroll
        for (int ct = 0; ct < 2; ++ct)
          acc[rt * 2 + ct] = __builtin_amdgcn_mfma_f32_16x16x32_bf16(a[rt], b[ct], acc[rt * 2 + ct], 0, 0, 0);
    }
    __syncthreads();
  }
  // epilogue -> staged bf16 tile (reuse Als), then coalesced 16B stores
  unsigned short* ostg = Als;
  #pragma unroll
  for (int i = 0; i < 8; ++i) {
    int rt = i >> 1, ct = i & 1;
    #pragma unroll
    for (int rg = 0; rg < 4; ++rg) {
      int row = rt * 16 + grp * 4 + rg;
      int colL = w * 32 + ct * 16 + c;
      float zv = acc[i][rg] + bias_s[colL];
      if (MODE == 0) {
        #pragma unroll
        for (int j = 0; j < 4; ++j) zv += a_sp[row * 4 + j] * b_sp[j * 128 + colL];
      }
      ostg[row * 128 + colL] = f2b(zv);
    }
  }
  __syncthreads();
  #pragma unroll
  for (int ii = 0; ii < 4; ++ii) {
    int e = tid * 8 + ii * 2048;
    int row = e >> 7; int cl = e & 127;
    *(uint4*)&xw_out[(size_t)row * 1024 + nt * 128 + cl] = *(const uint4*)&ostg[e];
  }
}

// ------------------------------------------------ head
__global__ __launch_bounds__(256) void k7_d1(const float* __restrict__ h_last,
    const float* __restrict__ d1_W, const float* __restrict__ d1_b, float* __restrict__ d1o)
{
  __shared__ float Asl[64 * 256];
  __shared__ float Bsl[256 * 64];
  const int nt = blockIdx.x, br = blockIdx.y, tid = threadIdx.x;
  const float* hl = h_last + (size_t)br * 16384;
  for (int i = tid; i < 16384; i += 256) Asl[i] = hl[i];
  const float* wp = d1_W + (size_t)br * 65536 + nt * 64;
  for (int i = tid; i < 16384; i += 256) {
    int k = i >> 6, cl = i & 63;
    Bsl[i] = wp[(size_t)k * 256 + cl];
  }
  __syncthreads();
  const int cl = tid & 63, rq = tid >> 6;
  float s[16];
  const float bias = d1_b[br * 256 + nt * 64 + cl];
  #pragma unroll
  for (int i = 0; i < 16; ++i) s[i] = bias;
  for (int k = 0; k < 256; ++k) {
    float bv = Bsl[k * 64 + cl];
    #pragma unroll
    for (int i = 0; i < 16; ++i) s[i] += Asl[(rq * 16 + i) * 256 + k] * bv;
  }
  #pragma unroll
  for (int i = 0; i < 16; ++i)
    d1o[(size_t)br * 16384 + (rq * 16 + i) * 256 + nt * 64 + cl] = fmaxf(s[i], 0.0f);
}

__global__ __launch_bounds__(256) void k8_head(const float* __restrict__ d1o,
    const float* __restrict__ d2_W, const float* __restrict__ d2_b,
    const float* __restrict__ df_W, const float* __restrict__ df_b,
    const float* __restrict__ inputs, float* __restrict__ out)
{
  __shared__ float Asl[64 * 256];
  __shared__ float Bsl[256 * 64];
  __shared__ float d2sT[64 * 65];
  __shared__ float wfs[68];
  const int br = blockIdx.x, tid = threadIdx.x;
  for (int i = tid; i < 16384; i += 256) Asl[i] = d1o[(size_t)br * 16384 + i];
  for (int i = tid; i < 16384; i += 256) Bsl[i] = d2_W[(size_t)br * 16384 + i];
  if (tid < 67) wfs[tid] = df_W[br * 67 + tid];
  __syncthreads();
  const int cl = tid & 63, rq = tid >> 6;
  float s[16];
  const float bias = d2_b[br * 64 + cl];
  #pragma unroll
  for (int i = 0; i < 16; ++i) s[i] = bias;
  for (int k = 0; k < 256; ++k) {
    float bv = Bsl[k * 64 + cl];
    #pragma unroll
    for (int i = 0; i < 16; ++i) s[i] += Asl[(rq * 16 + i) * 256 + k] * bv;
  }
  #pragma unroll
  for (int i = 0; i < 16; ++i) d2sT[cl * 65 + rq * 16 + i] = fmaxf(s[i], 0.0f);
  __syncthreads();
  if (tid < 64) {
    const int b = tid;
    const float* ip = inputs + ((size_t)b * TT + (TT - 1)) * 42;
    float acc = df_b[br] + ip[20 + br] + ip[27] * wfs[64] + ip[27 + br + 1] * wfs[65]
              + ip[27 + br + 8] * wfs[66];
    #pragma unroll 4
    for (int j = 0; j < 64; ++j) acc += d2sT[j * 65 + b] * wfs[j];
    out[b * 7 + br] = acc;
  }
}

// ------------------------------------------------ host
extern "C" void kernel_launch(void* const* d_in, const int* in_sizes, int n_in,
                              void* d_out, int out_size, void* d_ws, size_t ws_size,
                              hipStream_t stream) {
  (void)in_sizes; (void)n_in; (void)out_size;
  const float* inputs  = (const float*)d_in[0];
  const float* eco_Wk  = (const float*)d_in[1];
  const float* eco_Wr  = (const float*)d_in[2];
  const float* eco_b   = (const float*)d_in[3];
  const float* data_Wk = (const float*)d_in[4];
  const float* data_Wr = (const float*)d_in[5];
  const float* data_b  = (const float*)d_in[6];
  const float* att_Wk  = (const float*)d_in[7];
  const float* att_Wr  = (const float*)d_in[8];
  const float* att_b   = (const float*)d_in[9];
  const float* ts_Wk   = (const float*)d_in[10];
  const float* ts_Wr   = (const float*)d_in[11];
  const float* ts_b    = (const float*)d_in[12];
  const float* d1_W    = (const float*)d_in[13];
  const float* d1_b    = (const float*)d_in[14];
  const float* d2_W    = (const float*)d_in[15];
  const float* d2_b    = (const float*)d_in[16];
  const float* df_W    = (const float*)d_in[17];
  const float* df_b    = (const float*)d_in[18];

  char* ws = (char*)d_ws;
  size_t off = 0;
  auto take = [&](size_t bytes) -> void* {
    void* p = ws + off;
    off += (bytes + 255) & ~(size_t)255;
    return p;
  };
  // fixed buffers (~27 MB)
  unsigned short* wr_swz = (unsigned short*)take((size_t)22 * 262144 * 2);
  unsigned short* wk_da  = (unsigned short*)take((size_t)14 * 262144 * 2);
  unsigned short* wk_ts  = (unsigned short*)take((size_t)7  * 262144 * 2);
  unsigned short* hbrd   = (unsigned short*)take((size_t)44 * 16384 * 2);
  float*          cstate = (float*)take((size_t)22 * 8 * 2 * 1024 * 4);
  float*          h_last = (float*)take((size_t)7 * 16384 * 4);
  float*          d1o    = (float*)take((size_t)7 * 16384 * 4);
  int*            bars   = (int*)take((size_t)44 * 16 * 4);
  if (off + 4096 > ws_size) return;

  // per-step chunk cost: xW (22 LSTMs) + hs (eco + 7 data + 7 att)
  const size_t per_step = (size_t)22 * 131072 + (size_t)15 * 32768;   // 3,375,104 B
  size_t avail = ws_size - off - 4096;
  int CH = (int)(avail / per_step);
  if (CH < 1) return;
  if (CH > TT) CH = TT;
  unsigned short* xw_eco = (unsigned short*)take((size_t)CH * 131072);
  unsigned short* xw_da  = (unsigned short*)take((size_t)14 * CH * 131072);
  unsigned short* xw_ts  = (unsigned short*)take((size_t)7  * CH * 131072);
  unsigned short* hs_eco = (unsigned short*)take((size_t)CH * 32768);
  unsigned short* hs_dat = (unsigned short*)take((size_t)7 * CH * 32768);
  unsigned short* hs_att = (unsigned short*)take((size_t)7 * CH * 32768);
  if (off > ws_size) return;

  hipMemsetAsync(hbrd, 0, (size_t)44 * 16384 * 2, stream);
  hipMemsetAsync(bars, 0, (size_t)44 * 16 * 4, stream);
  k0a_wr<<<dim3(8, 8, 22), 256, 0, stream>>>(eco_Wr, data_Wr, att_Wr, ts_Wr, wr_swz);
  k0b_wk<<<dim3(4, 8, 21), 256, 0, stream>>>(data_Wk, att_Wk, ts_Wk, wk_da, wk_ts);

  for (int t0 = 0; t0 < TT; t0 += CH) {
    int t1 = (t0 + CH < TT) ? (t0 + CH) : TT;
    int len = t1 - t0;
    k1_ecoxw<<<dim3(len, 4), 256, 0, stream>>>(inputs, eco_Wk, eco_b, xw_eco, t0);
    rec_kernel<0><<<dim3(8, 2, 1), 256, 0, stream>>>(wr_swz, xw_eco, hbrd, bars,
                                                     hs_eco, nullptr, nullptr, cstate, t0, t1);
    gemm_xw<0><<<dim3(len, 8, 14), 256, 0, stream>>>(hs_eco, nullptr, wk_da,
                                                     data_Wk, att_Wk, data_b, att_b,
                                                     inputs, xw_da, t0);
    rec_kernel<1><<<dim3(8, 2, 14), 256, 0, stream>>>(wr_swz, xw_da, hbrd, bars,
                                                      hs_dat, hs_att, nullptr, cstate, t0, t1);
    gemm_xw<1><<<dim3(len, 8, 7), 256, 0, stream>>>(hs_dat, hs_att, wk_ts,
                                                    nullptr, nullptr, ts_b, nullptr,
                                                    inputs, xw_ts, t0);
    rec_kernel<2><<<dim3(8, 2, 7), 256, 0, stream>>>(wr_swz, xw_ts, hbrd, bars,
                                                     nullptr, nullptr, h_last, cstate, t0, t1);
  }
  k7_d1<<<dim3(4, 7), 256, 0, stream>>>(h_last, d1_W, d1_b, d1o);
  k8_head<<<7, 256, 0, stream>>>(d1o, d2_W, d2_b, df_W, df_b, inputs, (float*)d_out);
}

// Round 3
// 9168.471 us; speedup vs baseline: 1.9387x; 1.9387x over previous
//
#include <hip/hip_runtime.h>

// MM_LSTM_Age_v2: 22-LSTM recurrent model on MI355X.
// Time-chunked pipeline (chunk size CH adapted to ws_size):
//   k0a/k0b weight transpose+bf16 -> per chunk: k1 eco xW -> rec<0> ->
//   gemm<0> (data/att xW) -> rec<1> -> gemm<1> (ts xW, prod fused) -> rec<2>
//   -> after last chunk: k7 dense1 -> k8 dense2+final.
// Recurrences: 8 column-WGs x 2 batch-WGs per LSTM, Wr bf16 resident in LDS.
// Cross-WG h exchange: u32-packed relaxed agent-scope atomics (cache-bypass,
// no L2 inv/wb) + s_waitcnt + relaxed flag add; consumer polls relaxed.

#define TT 365

typedef short bf16x8 __attribute__((ext_vector_type(8)));
typedef unsigned short u16x8 __attribute__((ext_vector_type(8)));
typedef float f32x4 __attribute__((ext_vector_type(4)));

__device__ __forceinline__ float b2f(unsigned short u) {
  union { unsigned u32; float f; } v; v.u32 = ((unsigned)u) << 16; return v.f;
}
__device__ __forceinline__ unsigned short f2b(float f) {
  union { float f; unsigned u32; } v; v.f = f;
  unsigned u = v.u32;
  u = u + 0x7FFFu + ((u >> 16) & 1u);   // RNE
  return (unsigned short)(u >> 16);
}
__device__ __forceinline__ float sigf(float x) { return 1.0f / (1.0f + __expf(-x)); }
__device__ __forceinline__ float tanh_(float x) { return 2.0f / (1.0f + __expf(-2.0f * x)) - 1.0f; }

// ------------------------------------------------ k0a: Wr transpose -> bf16
// wr_swz layout per (lstm,wg): [kb 8][col 128][ks 32], col = gate*32+hi
__global__ __launch_bounds__(256) void k0a_wr(const float* __restrict__ eco_Wr,
    const float* __restrict__ data_Wr, const float* __restrict__ att_Wr,
    const float* __restrict__ ts_Wr, unsigned short* __restrict__ wr_swz)
{
  __shared__ float ls[32 * 133];
  const int kb = blockIdx.x, wg = blockIdx.y, l = blockIdx.z, tid = threadIdx.x;
  const float* src;
  if (l == 0) src = eco_Wr;
  else if (l < 15) { int d = l - 1; src = ((d & 1) ? att_Wr : data_Wr) + (size_t)(d >> 1) * 262144; }
  else src = ts_Wr + (size_t)(l - 15) * 262144;
  for (int e = tid; e < 4096; e += 256) {
    int ks = e >> 7, col = e & 127;
    int gate = col >> 5, hi = col & 31;
    ls[ks * 133 + col] = src[(size_t)(kb * 32 + ks) * 1024 + gate * 256 + wg * 32 + hi];
  }
  __syncthreads();
  unsigned short* out = wr_swz + (((size_t)l * 8 + wg) * 8 + kb) * 4096;
  for (int e = tid; e < 4096; e += 256) {
    int col = e >> 5, ks = e & 31;
    out[e] = f2b(ls[ks * 133 + col]);
  }
}

// ------------------------------------------------ k0b: Wk transpose -> bf16
// wk layout per lstm: [kb 8][col 1024][ks 32] (data/att: K rows 4..259)
__global__ __launch_bounds__(256) void k0b_wk(const float* __restrict__ data_Wk,
    const float* __restrict__ att_Wk, const float* __restrict__ ts_Wk,
    unsigned short* __restrict__ wk_da, unsigned short* __restrict__ wk_ts)
{
  __shared__ float ls[32 * 261];
  const int cc = blockIdx.x, kb = blockIdx.y, d = blockIdx.z, tid = threadIdx.x;
  const float* src; unsigned short* dst; int roff;
  if (d < 14) { src = ((d & 1) ? att_Wk : data_Wk) + (size_t)(d >> 1) * 266240;
                dst = wk_da + (size_t)d * 262144; roff = 4; }
  else { src = ts_Wk + (size_t)(d - 14) * 262144;
         dst = wk_ts + (size_t)(d - 14) * 262144; roff = 0; }
  for (int e = tid; e < 8192; e += 256) {
    int ks = e >> 8, c2 = e & 255;
    ls[ks * 261 + c2] = src[(size_t)(roff + kb * 32 + ks) * 1024 + cc * 256 + c2];
  }
  __syncthreads();
  for (int e = tid; e < 8192; e += 256) {
    int col2 = e >> 5, ks = e & 31;
    dst[(size_t)kb * 32768 + (cc * 256 + col2) * 32 + ks] = f2b(ls[ks * 261 + col2]);
  }
}

// ------------------------------------------------ k1: eco xW (chunk-local out)
__global__ __launch_bounds__(256) void k1_ecoxw(const float* __restrict__ inputs,
    const float* __restrict__ eco_Wk, const float* __restrict__ eco_b,
    unsigned short* __restrict__ xw_eco, int t0)
{
  __shared__ float Asl[64 * 35];
  __shared__ float Bsl[35 * 256];
  const int tl = blockIdx.x, ct = blockIdx.y, tid = threadIdx.x;
  const int tg = t0 + tl;
  for (int i = tid; i < 64 * 35; i += 256) {
    int b = i / 35, k = i - b * 35;
    int col = (k < 20) ? k : (k + 7);          // eco input = cols [0..19, 27..41]
    Asl[i] = inputs[((size_t)b * TT + tg) * 42 + col];
  }
  for (int i = tid; i < 35 * 256; i += 256) {
    int k = i >> 8, c = i & 255;
    Bsl[i] = eco_Wk[(size_t)k * 1024 + ct * 256 + c];
  }
  __syncthreads();
  const float bias = eco_b[ct * 256 + tid];
  for (int r = 0; r < 64; ++r) {
    float s = bias;
    #pragma unroll
    for (int k = 0; k < 35; ++k) s += Asl[r * 35 + k] * Bsl[k * 256 + tid];
    xw_eco[((size_t)tl * 64 + r) * 1024 + ct * 256 + tid] = f2b(s);
  }
}

// ------------------------------------------------ recurrence
// grid (wg 8, bg 2, l). 256 threads. Per WG: 32 batch rows x 32 hidden units.
// xw/hs pointers are chunk bases (local t = t - t0); hbrd/bars use global t.
template<int STAGE>
__global__ __launch_bounds__(256, 1) void rec_kernel(
    const unsigned short* __restrict__ wr_swz_g,
    const unsigned short* __restrict__ xw_base,
    unsigned int* __restrict__ hbrd_base,     // u32-packed (2 x bf16)
    int* __restrict__ bars,
    unsigned short* __restrict__ hsA,
    unsigned short* __restrict__ hsB,
    float* __restrict__ h_last,
    float* __restrict__ cstate,
    int t0, int t1)
{
  __shared__ __align__(16) unsigned short WR[8 * 128 * 40];  // 81920 B
  __shared__ __align__(16) unsigned short Hs[8 * 32 * 40];   // 20480 B
  __shared__ float zsh[32 * 132];                            // 16896 B
  __shared__ float cst[32 * 32];                             //  4096 B

  const int tid = threadIdx.x;
  const int wg = blockIdx.x;
  const int bg = blockIdx.y;
  const int l  = blockIdx.z;
  const int len = t1 - t0;
  const int lg = (STAGE == 0) ? 0 : (STAGE == 1 ? 1 + l : 15 + l);
  const unsigned short* xw = xw_base + (size_t)l * len * 65536;
  const unsigned short* wr_g = wr_swz_g + ((size_t)lg * 8 + wg) * 32768;
  unsigned int* hbrd = hbrd_base + (size_t)(lg * 2 + bg) * 8192;   // 2 bufs x 4096 u32
  int* bar = bars + (lg * 2 + bg) * 16;
  float* cs = cstate + (((size_t)lg * 8 + wg) * 2 + bg) * 1024;
  unsigned int* hs_out32 = nullptr;
  if (STAGE == 0) hs_out32 = (unsigned int*)hsA;
  else if (STAGE == 1) hs_out32 = (unsigned int*)(((l & 1) ? hsB : hsA) + (size_t)(l >> 1) * len * 16384);
  const bool act_sig = (STAGE == 1) && (l & 1);

  // stage Wr slice into LDS (fragment-ordered in global; add pad-40)
  for (int i = tid * 8; i < 32768; i += 2048) {
    int kb = i >> 12; int rr = i & 4095; int col = rr >> 5; int ks = rr & 31;
    *(uint4*)&WR[(kb * 128 + col) * 40 + ks] = *(const uint4*)&wr_g[i];
  }
  if (t0 == 0) { for (int i = tid; i < 1024; i += 256) cst[i] = 0.0f; }
  else         { for (int i = tid; i < 1024; i += 256) cst[i] = cs[i]; }

  const int lane = tid & 63;
  const int w = tid >> 6;       // wave == gate index
  const int c = lane & 15;
  const int grp = lane >> 4;

  int xoff[16];
  #pragma unroll
  for (int rt = 0; rt < 2; ++rt)
    #pragma unroll
    for (int ct = 0; ct < 2; ++ct)
      #pragma unroll
      for (int rg = 0; rg < 4; ++rg)
        xoff[(rt * 2 + ct) * 4 + rg] =
            (bg * 32 + rt * 16 + grp * 4 + rg) * 1024 + w * 256 + wg * 32 + ct * 16 + c;

  unsigned short xva[16], xvb[16];
  #pragma unroll
  for (int i = 0; i < 16; ++i) xva[i] = xw[xoff[i]];
  __syncthreads();

  auto step = [&](int t, unsigned short (&cur)[16], unsigned short (&nxt)[16]) {
    if (t > t0) {
      if (tid == 0) {
        while (__hip_atomic_load(bar, __ATOMIC_RELAXED, __HIP_MEMORY_SCOPE_AGENT) < 8 * t) {
          __builtin_amdgcn_s_sleep(1);
        }
      }
      __syncthreads();
    }
    {  // gather h broadcast (coherent u32 atomics) -> Hs (fragment swizzle, pad 40)
      const unsigned int* hb32 = hbrd + (t & 1) * 4096;
      #pragma unroll
      for (int i = 0; i < 16; ++i) {
        int m = tid + i * 256;            // 0..4095
        int row = m >> 7;                 // 0..31
        int kp = m & 127;                 // k pair index
        int kb = kp >> 4, ksp = kp & 15;  // ks = 2*ksp
        unsigned int v = __hip_atomic_load(&hb32[m], __ATOMIC_RELAXED, __HIP_MEMORY_SCOPE_AGENT);
        *(unsigned int*)&Hs[(kb * 32 + row) * 40 + 2 * ksp] = v;
      }
    }
    __syncthreads();
    f32x4 acc[4];
    #pragma unroll
    for (int i = 0; i < 4; ++i)
      #pragma unroll
      for (int rg = 0; rg < 4; ++rg)
        acc[i][rg] = b2f(cur[i * 4 + rg]);     // acc init = xW[t] (bias folded)
    if (t + 1 < t1) {                          // prefetch xW[t+1] into regs
      const unsigned short* xw1 = xw + (size_t)(t + 1 - t0) * 65536;
      #pragma unroll
      for (int i = 0; i < 16; ++i) nxt[i] = xw1[xoff[i]];
    }
    #pragma unroll
    for (int kb = 0; kb < 8; ++kb) {
      bf16x8 a0 = *(const bf16x8*)&Hs[(kb * 32 + c) * 40 + grp * 8];
      bf16x8 a1 = *(const bf16x8*)&Hs[(kb * 32 + 16 + c) * 40 + grp * 8];
      bf16x8 b0 = *(const bf16x8*)&WR[(kb * 128 + w * 32 + c) * 40 + grp * 8];
      bf16x8 b1 = *(const bf16x8*)&WR[(kb * 128 + w * 32 + 16 + c) * 40 + grp * 8];
      acc[0] = __builtin_amdgcn_mfma_f32_16x16x32_bf16(a0, b0, acc[0], 0, 0, 0);
      acc[1] = __builtin_amdgcn_mfma_f32_16x16x32_bf16(a0, b1, acc[1], 0, 0, 0);
      acc[2] = __builtin_amdgcn_mfma_f32_16x16x32_bf16(a1, b0, acc[2], 0, 0, 0);
      acc[3] = __builtin_amdgcn_mfma_f32_16x16x32_bf16(a1, b1, acc[3], 0, 0, 0);
    }
    #pragma unroll
    for (int i = 0; i < 4; ++i) {
      int rt = i >> 1, ct = i & 1;
      #pragma unroll
      for (int rg = 0; rg < 4; ++rg) {
        int row = rt * 16 + grp * 4 + rg;
        int colL = w * 32 + ct * 16 + c;
        zsh[row * 132 + colL] = acc[i][rg];
      }
    }
    __syncthreads();
    {  // elementwise LSTM cell update: 2 hidden-unit pairs per thread
      #pragma unroll
      for (int it = 0; it < 2; ++it) {
        int m = tid + it * 256;           // 0..511
        int row = m >> 4;                 // 0..31
        int hp = m & 15;                  // unit pair
        float2 zi = *(const float2*)&zsh[row * 132 +      2 * hp];
        float2 zf = *(const float2*)&zsh[row * 132 + 32 + 2 * hp];
        float2 zg = *(const float2*)&zsh[row * 132 + 64 + 2 * hp];
        float2 zo = *(const float2*)&zsh[row * 132 + 96 + 2 * hp];
        int u0 = row * 32 + 2 * hp;
        float c0a = cst[u0], c0b = cst[u0 + 1];
        float gva = act_sig ? sigf(zg.x) : tanh_(zg.x);
        float gvb = act_sig ? sigf(zg.y) : tanh_(zg.y);
        float cna = sigf(zf.x) * c0a + sigf(zi.x) * gva;
        float cnb = sigf(zf.y) * c0b + sigf(zi.y) * gvb;
        float hva = sigf(zo.x) * (act_sig ? sigf(cna) : tanh_(cna));
        float hvb = sigf(zo.y) * (act_sig ? sigf(cnb) : tanh_(cnb));
        cst[u0] = cna; cst[u0 + 1] = cnb;
        unsigned int pv = (unsigned int)f2b(hva) | ((unsigned int)f2b(hvb) << 16);
        __hip_atomic_store(&hbrd[((t + 1) & 1) * 4096 + row * 128 + wg * 16 + hp], pv,
                           __ATOMIC_RELAXED, __HIP_MEMORY_SCOPE_AGENT);
        if (STAGE != 2) {
          hs_out32[((size_t)(t - t0) * 64 + bg * 32 + row) * 128 + wg * 16 + hp] = pv;
        } else if (t == TT - 1) {
          float* hl = h_last + (size_t)l * 16384 + (bg * 32 + row) * 256 + wg * 32 + 2 * hp;
          hl[0] = hva; hl[1] = hvb;
        }
      }
    }
    __builtin_amdgcn_s_waitcnt(0);   // drain this wave's coherent stores
    __syncthreads();                 // all waves drained
    if (tid == 0) __hip_atomic_fetch_add(bar, 1, __ATOMIC_RELAXED, __HIP_MEMORY_SCOPE_AGENT);
  };

  for (int t = t0; t < t1; t += 2) {
    step(t, xva, xvb);
    if (t + 1 < t1) step(t + 1, xvb, xva);
  }
  // persist c-state for next chunk (same unit layout as cst)
  for (int i = tid; i < 1024; i += 256) cs[i] = cst[i];
}

// ------------------------------------------------ xW GEMMs
// MODE 0: data/att xW (A = hs_eco chunk, +4 special K-rows in epilogue)
// MODE 1: ts xW (A = data_hs*att_hs fused product, chunk)
// grid (tl len, nt 8, z). out tile 64x128, K=256 in two halves.
template<int MODE>
__global__ __launch_bounds__(256, 2) void gemm_xw(
    const unsigned short* __restrict__ A1,
    const unsigned short* __restrict__ A2,
    const unsigned short* __restrict__ Bsw_base,
    const float* __restrict__ spWk_d, const float* __restrict__ spWk_a,
    const float* __restrict__ bias_d, const float* __restrict__ bias_a,
    const float* __restrict__ inputs,
    unsigned short* __restrict__ xw_out_base,
    int t0)
{
  __shared__ __align__(16) unsigned short Als[4 * 64 * 40];    // 20480 B (reused as out-stage)
  __shared__ __align__(16) unsigned short Bls[4 * 128 * 40];   // 40960 B
  __shared__ float a_sp[64 * 4];
  __shared__ float b_sp[4 * 128];
  __shared__ float bias_s[128];

  const int tid = threadIdx.x;
  const int tl = blockIdx.x, nt = blockIdx.y, z = blockIdx.z;
  const int len = gridDim.x;
  const int tg = t0 + tl;

  const unsigned short* Apt;
  const unsigned short* Apt2 = nullptr;
  const unsigned short* Bsw;
  const float* bias;
  unsigned short* xw_out;
  int br;
  if (MODE == 0) {
    br = z >> 1;
    Apt = A1;
    Bsw = Bsw_base + (size_t)z * 262144;
    bias = ((z & 1) ? bias_a : bias_d) + br * 1024;
  } else {
    br = z;
    Apt  = A1 + (size_t)z * len * 16384;
    Apt2 = A2 + (size_t)z * len * 16384;
    Bsw = Bsw_base + (size_t)z * 262144;
    bias = bias_d + z * 1024;
  }
  xw_out = xw_out_base + ((size_t)z * len + tl) * 65536;

  if (MODE == 0) {
    const float* spWk = ((z & 1) ? spWk_a : spWk_d) + (size_t)br * 266240;
    for (int i = tid; i < 4 * 128; i += 256) {
      int j = i >> 7; int cl = i & 127;
      b_sp[i] = spWk[(size_t)j * 1024 + nt * 128 + cl];
    }
    if (tid < 64) {
      const float* ip = inputs + ((size_t)tid * TT + tg) * 42;
      a_sp[tid * 4 + 0] = ip[20 + br];
      a_sp[tid * 4 + 1] = ip[27];
      a_sp[tid * 4 + 2] = ip[27 + br + 1];
      a_sp[tid * 4 + 3] = ip[27 + br + 8];
    }
  }
  if (tid < 128) bias_s[tid] = bias[nt * 128 + tid];

  const int lane = tid & 63, w = tid >> 6, c = lane & 15, grp = lane >> 4;
  f32x4 acc[8] = {};

  for (int kh = 0; kh < 2; ++kh) {
    #pragma unroll
    for (int ii = 0; ii < 4; ++ii) {       // A: 64 rows x 128 k
      int e = tid * 8 + ii * 2048;
      int row = e >> 7; int k = e & 127; int kb = k >> 5; int ks = k & 31;
      size_t g = ((size_t)tl * 64 + row) * 256 + kh * 128 + k;
      if (MODE == 0) {
        *(uint4*)&Als[(kb * 64 + row) * 40 + ks] = *(const uint4*)&Apt[g];
      } else {
        u16x8 vd = *(const u16x8*)&Apt[g];
        u16x8 va = *(const u16x8*)&Apt2[g];
        u16x8 vp;
        #pragma unroll
        for (int j = 0; j < 8; ++j) vp[j] = f2b(b2f(vd[j]) * b2f(va[j]));
        *(u16x8*)&Als[(kb * 64 + row) * 40 + ks] = vp;
      }
    }
    #pragma unroll
    for (int ii = 0; ii < 8; ++ii) {       // B: 128 cols x 128 k
      int e = tid * 8 + ii * 2048;
      int kbl = e >> 12; int rr = e & 4095; int cl = rr >> 5; int ks = rr & 31;
      size_t g = ((size_t)((kh * 4 + kbl) * 1024 + nt * 128 + cl)) * 32 + ks;
      *(uint4*)&Bls[(kbl * 128 + cl) * 40 + ks] = *(const uint4*)&Bsw[g];
    }
    __syncthreads();
    #pragma unroll
    for (int kbl = 0; kbl < 4; ++kbl) {
      bf16x8 a[4]; bf16x8 b[2];
      #pragma unroll
      for (int rt = 0; rt < 4; ++rt) a[rt] = *(const bf16x8*)&Als[(kbl * 64 + rt * 16 + c) * 40 + grp * 8];
      #pragma unroll
      for (int ct = 0; ct < 2; ++ct) b[ct] = *(const bf16x8*)&Bls[(kbl * 128 + w * 32 + ct * 16 + c) * 40 + grp * 8];
      #pragma unroll
      for (int rt = 0; rt < 4; ++rt)
        #pragma unroll
        for (int ct = 0; ct < 2; ++ct)
          acc[rt * 2 + ct] = __builtin_amdgcn_mfma_f32_16x16x32_bf16(a[rt], b[ct], acc[rt * 2 + ct], 0, 0, 0);
    }
    __syncthreads();
  }
  // epilogue -> staged bf16 tile (reuse Als), then coalesced 16B stores
  unsigned short* ostg = Als;
  #pragma unroll
  for (int i = 0; i < 8; ++i) {
    int rt = i >> 1, ct = i & 1;
    #pragma unroll
    for (int rg = 0; rg < 4; ++rg) {
      int row = rt * 16 + grp * 4 + rg;
      int colL = w * 32 + ct * 16 + c;
      float zv = acc[i][rg] + bias_s[colL];
      if (MODE == 0) {
        #pragma unroll
        for (int j = 0; j < 4; ++j) zv += a_sp[row * 4 + j] * b_sp[j * 128 + colL];
      }
      ostg[row * 128 + colL] = f2b(zv);
    }
  }
  __syncthreads();
  #pragma unroll
  for (int ii = 0; ii < 4; ++ii) {
    int e = tid * 8 + ii * 2048;
    int row = e >> 7; int cl = e & 127;
    *(uint4*)&xw_out[(size_t)row * 1024 + nt * 128 + cl] = *(const uint4*)&ostg[e];
  }
}

// ------------------------------------------------ head
__global__ __launch_bounds__(256) void k7_d1(const float* __restrict__ h_last,
    const float* __restrict__ d1_W, const float* __restrict__ d1_b, float* __restrict__ d1o)
{
  __shared__ float Asl[64 * 256];
  __shared__ float Bsl[256 * 64];
  const int nt = blockIdx.x, br = blockIdx.y, tid = threadIdx.x;
  const float* hl = h_last + (size_t)br * 16384;
  for (int i = tid; i < 16384; i += 256) Asl[i] = hl[i];
  const float* wp = d1_W + (size_t)br * 65536 + nt * 64;
  for (int i = tid; i < 16384; i += 256) {
    int k = i >> 6, cl = i & 63;
    Bsl[i] = wp[(size_t)k * 256 + cl];
  }
  __syncthreads();
  const int cl = tid & 63, rq = tid >> 6;
  float s[16];
  const float bias = d1_b[br * 256 + nt * 64 + cl];
  #pragma unroll
  for (int i = 0; i < 16; ++i) s[i] = bias;
  for (int k = 0; k < 256; ++k) {
    float bv = Bsl[k * 64 + cl];
    #pragma unroll
    for (int i = 0; i < 16; ++i) s[i] += Asl[(rq * 16 + i) * 256 + k] * bv;
  }
  #pragma unroll
  for (int i = 0; i < 16; ++i)
    d1o[(size_t)br * 16384 + (rq * 16 + i) * 256 + nt * 64 + cl] = fmaxf(s[i], 0.0f);
}

__global__ __launch_bounds__(256) void k8_head(const float* __restrict__ d1o,
    const float* __restrict__ d2_W, const float* __restrict__ d2_b,
    const float* __restrict__ df_W, const float* __restrict__ df_b,
    const float* __restrict__ inputs, float* __restrict__ out)
{
  __shared__ float Asl[64 * 256];
  __shared__ float Bsl[256 * 64];
  __shared__ float d2sT[64 * 65];
  __shared__ float wfs[68];
  const int br = blockIdx.x, tid = threadIdx.x;
  for (int i = tid; i < 16384; i += 256) Asl[i] = d1o[(size_t)br * 16384 + i];
  for (int i = tid; i < 16384; i += 256) Bsl[i] = d2_W[(size_t)br * 16384 + i];
  if (tid < 67) wfs[tid] = df_W[br * 67 + tid];
  __syncthreads();
  const int cl = tid & 63, rq = tid >> 6;
  float s[16];
  const float bias = d2_b[br * 64 + cl];
  #pragma unroll
  for (int i = 0; i < 16; ++i) s[i] = bias;
  for (int k = 0; k < 256; ++k) {
    float bv = Bsl[k * 64 + cl];
    #pragma unroll
    for (int i = 0; i < 16; ++i) s[i] += Asl[(rq * 16 + i) * 256 + k] * bv;
  }
  #pragma unroll
  for (int i = 0; i < 16; ++i) d2sT[cl * 65 + rq * 16 + i] = fmaxf(s[i], 0.0f);
  __syncthreads();
  if (tid < 64) {
    const int b = tid;
    const float* ip = inputs + ((size_t)b * TT + (TT - 1)) * 42;
    float acc = df_b[br] + ip[20 + br] + ip[27] * wfs[64] + ip[27 + br + 1] * wfs[65]
              + ip[27 + br + 8] * wfs[66];
    #pragma unroll 4
    for (int j = 0; j < 64; ++j) acc += d2sT[j * 65 + b] * wfs[j];
    out[b * 7 + br] = acc;
  }
}

// ------------------------------------------------ host
extern "C" void kernel_launch(void* const* d_in, const int* in_sizes, int n_in,
                              void* d_out, int out_size, void* d_ws, size_t ws_size,
                              hipStream_t stream) {
  (void)in_sizes; (void)n_in; (void)out_size;
  const float* inputs  = (const float*)d_in[0];
  const float* eco_Wk  = (const float*)d_in[1];
  const float* eco_Wr  = (const float*)d_in[2];
  const float* eco_b   = (const float*)d_in[3];
  const float* data_Wk = (const float*)d_in[4];
  const float* data_Wr = (const float*)d_in[5];
  const float* data_b  = (const float*)d_in[6];
  const float* att_Wk  = (const float*)d_in[7];
  const float* att_Wr  = (const float*)d_in[8];
  const float* att_b   = (const float*)d_in[9];
  const float* ts_Wk   = (const float*)d_in[10];
  const float* ts_Wr   = (const float*)d_in[11];
  const float* ts_b    = (const float*)d_in[12];
  const float* d1_W    = (const float*)d_in[13];
  const float* d1_b    = (const float*)d_in[14];
  const float* d2_W    = (const float*)d_in[15];
  const float* d2_b    = (const float*)d_in[16];
  const float* df_W    = (const float*)d_in[17];
  const float* df_b    = (const float*)d_in[18];

  char* ws = (char*)d_ws;
  size_t off = 0;
  auto take = [&](size_t bytes) -> void* {
    void* p = ws + off;
    off += (bytes + 255) & ~(size_t)255;
    return p;
  };
  // fixed buffers (~27 MB)
  unsigned short* wr_swz = (unsigned short*)take((size_t)22 * 262144 * 2);
  unsigned short* wk_da  = (unsigned short*)take((size_t)14 * 262144 * 2);
  unsigned short* wk_ts  = (unsigned short*)take((size_t)7  * 262144 * 2);
  unsigned int*   hbrd   = (unsigned int*)take((size_t)44 * 8192 * 4);
  float*          cstate = (float*)take((size_t)22 * 8 * 2 * 1024 * 4);
  float*          h_last = (float*)take((size_t)7 * 16384 * 4);
  float*          d1o    = (float*)take((size_t)7 * 16384 * 4);
  int*            bars   = (int*)take((size_t)44 * 16 * 4);
  if (off + 4096 > ws_size) return;

  // per-step chunk cost: xW (22 LSTMs) + hs (eco + 7 data + 7 att)
  const size_t per_step = (size_t)22 * 131072 + (size_t)15 * 32768;   // 3,375,104 B
  size_t avail = ws_size - off - 4096;
  int CH = (int)(avail / per_step);
  if (CH < 1) return;
  if (CH > TT) CH = TT;
  unsigned short* xw_eco = (unsigned short*)take((size_t)CH * 131072);
  unsigned short* xw_da  = (unsigned short*)take((size_t)14 * CH * 131072);
  unsigned short* xw_ts  = (unsigned short*)take((size_t)7  * CH * 131072);
  unsigned short* hs_eco = (unsigned short*)take((size_t)CH * 32768);
  unsigned short* hs_dat = (unsigned short*)take((size_t)7 * CH * 32768);
  unsigned short* hs_att = (unsigned short*)take((size_t)7 * CH * 32768);
  if (off > ws_size) return;

  hipMemsetAsync(hbrd, 0, (size_t)44 * 8192 * 4, stream);
  hipMemsetAsync(bars, 0, (size_t)44 * 16 * 4, stream);
  k0a_wr<<<dim3(8, 8, 22), 256, 0, stream>>>(eco_Wr, data_Wr, att_Wr, ts_Wr, wr_swz);
  k0b_wk<<<dim3(4, 8, 21), 256, 0, stream>>>(data_Wk, att_Wk, ts_Wk, wk_da, wk_ts);

  for (int t0 = 0; t0 < TT; t0 += CH) {
    int t1 = (t0 + CH < TT) ? (t0 + CH) : TT;
    int len = t1 - t0;
    k1_ecoxw<<<dim3(len, 4), 256, 0, stream>>>(inputs, eco_Wk, eco_b, xw_eco, t0);
    rec_kernel<0><<<dim3(8, 2, 1), 256, 0, stream>>>(wr_swz, xw_eco, hbrd, bars,
                                                     hs_eco, nullptr, nullptr, cstate, t0, t1);
    gemm_xw<0><<<dim3(len, 8, 14), 256, 0, stream>>>(hs_eco, nullptr, wk_da,
                                                     data_Wk, att_Wk, data_b, att_b,
                                                     inputs, xw_da, t0);
    rec_kernel<1><<<dim3(8, 2, 14), 256, 0, stream>>>(wr_swz, xw_da, hbrd, bars,
                                                      hs_dat, hs_att, nullptr, cstate, t0, t1);
    gemm_xw<1><<<dim3(len, 8, 7), 256, 0, stream>>>(hs_dat, hs_att, wk_ts,
                                                    nullptr, nullptr, ts_b, nullptr,
                                                    inputs, xw_ts, t0);
    rec_kernel<2><<<dim3(8, 2, 7), 256, 0, stream>>>(wr_swz, xw_ts, hbrd, bars,
                                                     nullptr, nullptr, h_last, cstate, t0, t1);
  }
  k7_d1<<<dim3(4, 7), 256, 0, stream>>>(h_last, d1_W, d1_b, d1o);
  k8_head<<<7, 256, 0, stream>>>(d1o, d2_W, d2_b, df_W, df_b, inputs, (float*)d_out);
}

// Round 4
// 5628.993 us; speedup vs baseline: 3.1577x; 1.6288x over previous
//
#include <hip/hip_runtime.h>

// MM_LSTM_Age_v2: 22-LSTM recurrent model on MI355X.
// Time-chunked pipeline (chunk size CH adapted to ws_size):
//   k0a/k0b weight transpose+bf16 -> per chunk: k1 eco xW -> rec<0> ->
//   gemm<0> (data/att xW) -> rec<1> -> gemm<1> (ts xW, prod fused) -> rec<2>
//   -> after last chunk: k7 dense1 -> k8 dense2+final.
// Recurrences: 8 column-WGs x 2 batch-WGs per LSTM, Wr bf16 resident in LDS.
// Cross-WG h exchange: TAG-CARRYING u64 relaxed agent-scope atomics
// (hi32 = h-state index, lo32 = 2 x bf16). No barrier counter: consumers
// poll tags of the 16 words they need, reloading only stale ones.

#define TT 365

typedef short bf16x8 __attribute__((ext_vector_type(8)));
typedef unsigned short u16x8 __attribute__((ext_vector_type(8)));
typedef float f32x4 __attribute__((ext_vector_type(4)));

__device__ __forceinline__ float b2f(unsigned short u) {
  union { unsigned u32; float f; } v; v.u32 = ((unsigned)u) << 16; return v.f;
}
__device__ __forceinline__ unsigned short f2b(float f) {
  union { float f; unsigned u32; } v; v.f = f;
  unsigned u = v.u32;
  u = u + 0x7FFFu + ((u >> 16) & 1u);   // RNE
  return (unsigned short)(u >> 16);
}
__device__ __forceinline__ float sigf(float x) { return 1.0f / (1.0f + __expf(-x)); }
__device__ __forceinline__ float tanh_(float x) { return 2.0f / (1.0f + __expf(-2.0f * x)) - 1.0f; }

// ------------------------------------------------ k0a: Wr transpose -> bf16
// wr_swz layout per (lstm,wg): [kb 8][col 128][ks 32], col = gate*32+hi
__global__ __launch_bounds__(256) void k0a_wr(const float* __restrict__ eco_Wr,
    const float* __restrict__ data_Wr, const float* __restrict__ att_Wr,
    const float* __restrict__ ts_Wr, unsigned short* __restrict__ wr_swz)
{
  __shared__ float ls[32 * 133];
  const int kb = blockIdx.x, wg = blockIdx.y, l = blockIdx.z, tid = threadIdx.x;
  const float* src;
  if (l == 0) src = eco_Wr;
  else if (l < 15) { int d = l - 1; src = ((d & 1) ? att_Wr : data_Wr) + (size_t)(d >> 1) * 262144; }
  else src = ts_Wr + (size_t)(l - 15) * 262144;
  for (int e = tid; e < 4096; e += 256) {
    int ks = e >> 7, col = e & 127;
    int gate = col >> 5, hi = col & 31;
    ls[ks * 133 + col] = src[(size_t)(kb * 32 + ks) * 1024 + gate * 256 + wg * 32 + hi];
  }
  __syncthreads();
  unsigned short* out = wr_swz + (((size_t)l * 8 + wg) * 8 + kb) * 4096;
  for (int e = tid; e < 4096; e += 256) {
    int col = e >> 5, ks = e & 31;
    out[e] = f2b(ls[ks * 133 + col]);
  }
}

// ------------------------------------------------ k0b: Wk transpose -> bf16
// wk layout per lstm: [kb 8][col 1024][ks 32] (data/att: K rows 4..259)
__global__ __launch_bounds__(256) void k0b_wk(const float* __restrict__ data_Wk,
    const float* __restrict__ att_Wk, const float* __restrict__ ts_Wk,
    unsigned short* __restrict__ wk_da, unsigned short* __restrict__ wk_ts)
{
  __shared__ float ls[32 * 261];
  const int cc = blockIdx.x, kb = blockIdx.y, d = blockIdx.z, tid = threadIdx.x;
  const float* src; unsigned short* dst; int roff;
  if (d < 14) { src = ((d & 1) ? att_Wk : data_Wk) + (size_t)(d >> 1) * 266240;
                dst = wk_da + (size_t)d * 262144; roff = 4; }
  else { src = ts_Wk + (size_t)(d - 14) * 262144;
         dst = wk_ts + (size_t)(d - 14) * 262144; roff = 0; }
  for (int e = tid; e < 8192; e += 256) {
    int ks = e >> 8, c2 = e & 255;
    ls[ks * 261 + c2] = src[(size_t)(roff + kb * 32 + ks) * 1024 + cc * 256 + c2];
  }
  __syncthreads();
  for (int e = tid; e < 8192; e += 256) {
    int col2 = e >> 5, ks = e & 31;
    dst[(size_t)kb * 32768 + (cc * 256 + col2) * 32 + ks] = f2b(ls[ks * 261 + col2]);
  }
}

// ------------------------------------------------ k1: eco xW (chunk-local out)
__global__ __launch_bounds__(256) void k1_ecoxw(const float* __restrict__ inputs,
    const float* __restrict__ eco_Wk, const float* __restrict__ eco_b,
    unsigned short* __restrict__ xw_eco, int t0)
{
  __shared__ float Asl[64 * 35];
  __shared__ float Bsl[35 * 256];
  const int tl = blockIdx.x, ct = blockIdx.y, tid = threadIdx.x;
  const int tg = t0 + tl;
  for (int i = tid; i < 64 * 35; i += 256) {
    int b = i / 35, k = i - b * 35;
    int col = (k < 20) ? k : (k + 7);          // eco input = cols [0..19, 27..41]
    Asl[i] = inputs[((size_t)b * TT + tg) * 42 + col];
  }
  for (int i = tid; i < 35 * 256; i += 256) {
    int k = i >> 8, c = i & 255;
    Bsl[i] = eco_Wk[(size_t)k * 1024 + ct * 256 + c];
  }
  __syncthreads();
  const float bias = eco_b[ct * 256 + tid];
  for (int r = 0; r < 64; ++r) {
    float s = bias;
    #pragma unroll
    for (int k = 0; k < 35; ++k) s += Asl[r * 35 + k] * Bsl[k * 256 + tid];
    xw_eco[((size_t)tl * 64 + r) * 1024 + ct * 256 + tid] = f2b(s);
  }
}

// ------------------------------------------------ recurrence
// grid (wg 8, bg 2, l). 256 threads. Per WG: 32 batch rows x 32 hidden units.
// xw/hs pointers are chunk bases (local t = t - t0); hbrd uses global tags.
template<int STAGE>
__global__ __launch_bounds__(256, 1) void rec_kernel(
    const unsigned short* __restrict__ wr_swz_g,
    const unsigned short* __restrict__ xw_base,
    unsigned long long* __restrict__ hbrd_base,   // {tag(hi32), 2xbf16(lo32)}
    unsigned short* __restrict__ hsA,
    unsigned short* __restrict__ hsB,
    float* __restrict__ h_last,
    float* __restrict__ cstate,
    int t0, int t1)
{
  __shared__ __align__(16) unsigned short WR[8 * 128 * 40];  // 81920 B
  __shared__ __align__(16) unsigned short Hs[8 * 32 * 40];   // 20480 B
  __shared__ float zsh[32 * 132];                            // 16896 B
  __shared__ float cst[32 * 32];                             //  4096 B

  const int tid = threadIdx.x;
  const int wg = blockIdx.x;
  const int bg = blockIdx.y;
  const int l  = blockIdx.z;
  const int len = t1 - t0;
  const int lg = (STAGE == 0) ? 0 : (STAGE == 1 ? 1 + l : 15 + l);
  const unsigned short* xw = xw_base + (size_t)l * len * 65536;
  const unsigned short* wr_g = wr_swz_g + ((size_t)lg * 8 + wg) * 32768;
  unsigned long long* hbrd = hbrd_base + (size_t)(lg * 2 + bg) * 8192;  // 2 slots x 4096
  float* cs = cstate + (((size_t)lg * 8 + wg) * 2 + bg) * 1024;
  unsigned int* hs_out32 = nullptr;
  if (STAGE == 0) hs_out32 = (unsigned int*)hsA;
  else if (STAGE == 1) hs_out32 = (unsigned int*)(((l & 1) ? hsB : hsA) + (size_t)(l >> 1) * len * 16384);
  const bool act_sig = (STAGE == 1) && (l & 1);

  // stage Wr slice into LDS (fragment-ordered in global; add pad-40)
  for (int i = tid * 8; i < 32768; i += 2048) {
    int kb = i >> 12; int rr = i & 4095; int col = rr >> 5; int ks = rr & 31;
    *(uint4*)&WR[(kb * 128 + col) * 40 + ks] = *(const uint4*)&wr_g[i];
  }
  if (t0 == 0) { for (int i = tid; i < 1024; i += 256) cst[i] = 0.0f; }
  else         { for (int i = tid; i < 1024; i += 256) cst[i] = cs[i]; }

  const int lane = tid & 63;
  const int w = tid >> 6;       // wave == gate index
  const int c = lane & 15;
  const int grp = lane >> 4;

  int xoff[16];
  #pragma unroll
  for (int rt = 0; rt < 2; ++rt)
    #pragma unroll
    for (int ct = 0; ct < 2; ++ct)
      #pragma unroll
      for (int rg = 0; rg < 4; ++rg)
        xoff[(rt * 2 + ct) * 4 + rg] =
            (bg * 32 + rt * 16 + grp * 4 + rg) * 1024 + w * 256 + wg * 32 + ct * 16 + c;

  unsigned short xva[16], xvb[16];
  #pragma unroll
  for (int i = 0; i < 16; ++i) xva[i] = xw[xoff[i]];
  __syncthreads();

  // gather Hs-element destination precompute: m = tid + i*256
  auto step = [&](int t, unsigned short (&cur)[16], unsigned short (&nxt)[16]) {
    {  // tag-polled gather of h state t -> Hs (fragment swizzle, pad 40)
      const unsigned long long* hb = hbrd + (size_t)(t & 1) * 4096;
      unsigned long long v[16];
      #pragma unroll
      for (int i = 0; i < 16; ++i)
        v[i] = __hip_atomic_load(&hb[tid + i * 256], __ATOMIC_RELAXED, __HIP_MEMORY_SCOPE_AGENT);
      const unsigned tagv = (unsigned)t;
      int tries = 0;
      while (true) {
        unsigned pending = 0u;
        #pragma unroll
        for (int i = 0; i < 16; ++i)
          pending |= ((unsigned)(v[i] >> 32) != tagv) ? (1u << i) : 0u;
        if (pending == 0u) break;
        if (++tries > 8) __builtin_amdgcn_s_sleep(1);
        #pragma unroll
        for (int i = 0; i < 16; ++i)
          if (pending & (1u << i))
            v[i] = __hip_atomic_load(&hb[tid + i * 256], __ATOMIC_RELAXED, __HIP_MEMORY_SCOPE_AGENT);
      }
      #pragma unroll
      for (int i = 0; i < 16; ++i) {
        int m = tid + i * 256;            // 0..4095
        int row = m >> 7;                 // 0..31
        int kp = m & 127;                 // k pair index
        int kb = kp >> 4, ksp = kp & 15;  // ks = 2*ksp
        *(unsigned int*)&Hs[(kb * 32 + row) * 40 + 2 * ksp] = (unsigned int)v[i];
      }
    }
    __syncthreads();                      // Hs ready; also fences prior cell update
    f32x4 acc[4];
    #pragma unroll
    for (int i = 0; i < 4; ++i)
      #pragma unroll
      for (int rg = 0; rg < 4; ++rg)
        acc[i][rg] = b2f(cur[i * 4 + rg]);     // acc init = xW[t] (bias folded)
    if (t + 1 < t1) {                          // prefetch xW[t+1] into regs
      const unsigned short* xw1 = xw + (size_t)(t + 1 - t0) * 65536;
      #pragma unroll
      for (int i = 0; i < 16; ++i) nxt[i] = xw1[xoff[i]];
    }
    #pragma unroll
    for (int kb = 0; kb < 8; ++kb) {
      bf16x8 a0 = *(const bf16x8*)&Hs[(kb * 32 + c) * 40 + grp * 8];
      bf16x8 a1 = *(const bf16x8*)&Hs[(kb * 32 + 16 + c) * 40 + grp * 8];
      bf16x8 b0 = *(const bf16x8*)&WR[(kb * 128 + w * 32 + c) * 40 + grp * 8];
      bf16x8 b1 = *(const bf16x8*)&WR[(kb * 128 + w * 32 + 16 + c) * 40 + grp * 8];
      acc[0] = __builtin_amdgcn_mfma_f32_16x16x32_bf16(a0, b0, acc[0], 0, 0, 0);
      acc[1] = __builtin_amdgcn_mfma_f32_16x16x32_bf16(a0, b1, acc[1], 0, 0, 0);
      acc[2] = __builtin_amdgcn_mfma_f32_16x16x32_bf16(a1, b0, acc[2], 0, 0, 0);
      acc[3] = __builtin_amdgcn_mfma_f32_16x16x32_bf16(a1, b1, acc[3], 0, 0, 0);
    }
    #pragma unroll
    for (int i = 0; i < 4; ++i) {
      int rt = i >> 1, ct = i & 1;
      #pragma unroll
      for (int rg = 0; rg < 4; ++rg) {
        int row = rt * 16 + grp * 4 + rg;
        int colL = w * 32 + ct * 16 + c;
        zsh[row * 132 + colL] = acc[i][rg];
      }
    }
    __syncthreads();                      // zsh ready
    {  // elementwise LSTM cell update: 2 hidden-unit pairs per thread
      const unsigned long long tagp = ((unsigned long long)(unsigned)(t + 1)) << 32;
      #pragma unroll
      for (int it = 0; it < 2; ++it) {
        int m = tid + it * 256;           // 0..511
        int row = m >> 4;                 // 0..31
        int hp = m & 15;                  // unit pair
        float2 zi = *(const float2*)&zsh[row * 132 +      2 * hp];
        float2 zf = *(const float2*)&zsh[row * 132 + 32 + 2 * hp];
        float2 zg = *(const float2*)&zsh[row * 132 + 64 + 2 * hp];
        float2 zo = *(const float2*)&zsh[row * 132 + 96 + 2 * hp];
        int u0 = row * 32 + 2 * hp;
        float c0a = cst[u0], c0b = cst[u0 + 1];
        float gva = act_sig ? sigf(zg.x) : tanh_(zg.x);
        float gvb = act_sig ? sigf(zg.y) : tanh_(zg.y);
        float cna = sigf(zf.x) * c0a + sigf(zi.x) * gva;
        float cnb = sigf(zf.y) * c0b + sigf(zi.y) * gvb;
        float hva = sigf(zo.x) * (act_sig ? sigf(cna) : tanh_(cna));
        float hvb = sigf(zo.y) * (act_sig ? sigf(cnb) : tanh_(cnb));
        cst[u0] = cna; cst[u0 + 1] = cnb;
        unsigned int pv = (unsigned int)f2b(hva) | ((unsigned int)f2b(hvb) << 16);
        __hip_atomic_store(&hbrd[(size_t)((t + 1) & 1) * 4096 + row * 128 + wg * 16 + hp],
                           tagp | pv, __ATOMIC_RELAXED, __HIP_MEMORY_SCOPE_AGENT);
        if (STAGE != 2) {
          hs_out32[((size_t)(t - t0) * 64 + bg * 32 + row) * 128 + wg * 16 + hp] = pv;
        } else if (t == TT - 1) {
          float* hl = h_last + (size_t)l * 16384 + (bg * 32 + row) * 256 + wg * 32 + 2 * hp;
          hl[0] = hva; hl[1] = hvb;
        }
      }
    }
  };

  for (int t = t0; t < t1; t += 2) {
    step(t, xva, xvb);
    if (t + 1 < t1) step(t + 1, xvb, xva);
  }
  // persist c-state for next chunk (same unit layout as cst)
  __syncthreads();
  for (int i = tid; i < 1024; i += 256) cs[i] = cst[i];
}

// ------------------------------------------------ xW GEMMs
// MODE 0: data/att xW (A = hs_eco chunk, +4 special K-rows in epilogue)
// MODE 1: ts xW (A = data_hs*att_hs fused product, chunk)
// grid (tl len, nt 8, z). out tile 64x128, K=256 in two halves.
template<int MODE>
__global__ __launch_bounds__(256, 2) void gemm_xw(
    const unsigned short* __restrict__ A1,
    const unsigned short* __restrict__ A2,
    const unsigned short* __restrict__ Bsw_base,
    const float* __restrict__ spWk_d, const float* __restrict__ spWk_a,
    const float* __restrict__ bias_d, const float* __restrict__ bias_a,
    const float* __restrict__ inputs,
    unsigned short* __restrict__ xw_out_base,
    int t0)
{
  __shared__ __align__(16) unsigned short Als[4 * 64 * 40];    // 20480 B (reused as out-stage)
  __shared__ __align__(16) unsigned short Bls[4 * 128 * 40];   // 40960 B
  __shared__ float a_sp[64 * 4];
  __shared__ float b_sp[4 * 128];
  __shared__ float bias_s[128];

  const int tid = threadIdx.x;
  const int tl = blockIdx.x, nt = blockIdx.y, z = blockIdx.z;
  const int len = gridDim.x;
  const int tg = t0 + tl;

  const unsigned short* Apt;
  const unsigned short* Apt2 = nullptr;
  const unsigned short* Bsw;
  const float* bias;
  unsigned short* xw_out;
  int br;
  if (MODE == 0) {
    br = z >> 1;
    Apt = A1;
    Bsw = Bsw_base + (size_t)z * 262144;
    bias = ((z & 1) ? bias_a : bias_d) + br * 1024;
  } else {
    br = z;
    Apt  = A1 + (size_t)z * len * 16384;
    Apt2 = A2 + (size_t)z * len * 16384;
    Bsw = Bsw_base + (size_t)z * 262144;
    bias = bias_d + z * 1024;
  }
  xw_out = xw_out_base + ((size_t)z * len + tl) * 65536;

  if (MODE == 0) {
    const float* spWk = ((z & 1) ? spWk_a : spWk_d) + (size_t)br * 266240;
    for (int i = tid; i < 4 * 128; i += 256) {
      int j = i >> 7; int cl = i & 127;
      b_sp[i] = spWk[(size_t)j * 1024 + nt * 128 + cl];
    }
    if (tid < 64) {
      const float* ip = inputs + ((size_t)tid * TT + tg) * 42;
      a_sp[tid * 4 + 0] = ip[20 + br];
      a_sp[tid * 4 + 1] = ip[27];
      a_sp[tid * 4 + 2] = ip[27 + br + 1];
      a_sp[tid * 4 + 3] = ip[27 + br + 8];
    }
  }
  if (tid < 128) bias_s[tid] = bias[nt * 128 + tid];

  const int lane = tid & 63, w = tid >> 6, c = lane & 15, grp = lane >> 4;
  f32x4 acc[8] = {};

  for (int kh = 0; kh < 2; ++kh) {
    #pragma unroll
    for (int ii = 0; ii < 4; ++ii) {       // A: 64 rows x 128 k
      int e = tid * 8 + ii * 2048;
      int row = e >> 7; int k = e & 127; int kb = k >> 5; int ks = k & 31;
      size_t g = ((size_t)tl * 64 + row) * 256 + kh * 128 + k;
      if (MODE == 0) {
        *(uint4*)&Als[(kb * 64 + row) * 40 + ks] = *(const uint4*)&Apt[g];
      } else {
        u16x8 vd = *(const u16x8*)&Apt[g];
        u16x8 va = *(const u16x8*)&Apt2[g];
        u16x8 vp;
        #pragma unroll
        for (int j = 0; j < 8; ++j) vp[j] = f2b(b2f(vd[j]) * b2f(va[j]));
        *(u16x8*)&Als[(kb * 64 + row) * 40 + ks] = vp;
      }
    }
    #pragma unroll
    for (int ii = 0; ii < 8; ++ii) {       // B: 128 cols x 128 k
      int e = tid * 8 + ii * 2048;
      int kbl = e >> 12; int rr = e & 4095; int cl = rr >> 5; int ks = rr & 31;
      size_t g = ((size_t)((kh * 4 + kbl) * 1024 + nt * 128 + cl)) * 32 + ks;
      *(uint4*)&Bls[(kbl * 128 + cl) * 40 + ks] = *(const uint4*)&Bsw[g];
    }
    __syncthreads();
    #pragma unroll
    for (int kbl = 0; kbl < 4; ++kbl) {
      bf16x8 a[4]; bf16x8 b[2];
      #pragma unroll
      for (int rt = 0; rt < 4; ++rt) a[rt] = *(const bf16x8*)&Als[(kbl * 64 + rt * 16 + c) * 40 + grp * 8];
      #pragma unroll
      for (int ct = 0; ct < 2; ++ct) b[ct] = *(const bf16x8*)&Bls[(kbl * 128 + w * 32 + ct * 16 + c) * 40 + grp * 8];
      #pragma unroll
      for (int rt = 0; rt < 4; ++rt)
        #pragma unroll
        for (int ct = 0; ct < 2; ++ct)
          acc[rt * 2 + ct] = __builtin_amdgcn_mfma_f32_16x16x32_bf16(a[rt], b[ct], acc[rt * 2 + ct], 0, 0, 0);
    }
    __syncthreads();
  }
  // epilogue -> staged bf16 tile (reuse Als), then coalesced 16B stores
  unsigned short* ostg = Als;
  #pragma unroll
  for (int i = 0; i < 8; ++i) {
    int rt = i >> 1, ct = i & 1;
    #pragma unroll
    for (int rg = 0; rg < 4; ++rg) {
      int row = rt * 16 + grp * 4 + rg;
      int colL = w * 32 + ct * 16 + c;
      float zv = acc[i][rg] + bias_s[colL];
      if (MODE == 0) {
        #pragma unroll
        for (int j = 0; j < 4; ++j) zv += a_sp[row * 4 + j] * b_sp[j * 128 + colL];
      }
      ostg[row * 128 + colL] = f2b(zv);
    }
  }
  __syncthreads();
  #pragma unroll
  for (int ii = 0; ii < 4; ++ii) {
    int e = tid * 8 + ii * 2048;
    int row = e >> 7; int cl = e & 127;
    *(uint4*)&xw_out[(size_t)row * 1024 + nt * 128 + cl] = *(const uint4*)&ostg[e];
  }
}

// ------------------------------------------------ head
__global__ __launch_bounds__(256) void k7_d1(const float* __restrict__ h_last,
    const float* __restrict__ d1_W, const float* __restrict__ d1_b, float* __restrict__ d1o)
{
  __shared__ float Asl[64 * 256];
  __shared__ float Bsl[256 * 64];
  const int nt = blockIdx.x, br = blockIdx.y, tid = threadIdx.x;
  const float* hl = h_last + (size_t)br * 16384;
  for (int i = tid; i < 16384; i += 256) Asl[i] = hl[i];
  const float* wp = d1_W + (size_t)br * 65536 + nt * 64;
  for (int i = tid; i < 16384; i += 256) {
    int k = i >> 6, cl = i & 63;
    Bsl[i] = wp[(size_t)k * 256 + cl];
  }
  __syncthreads();
  const int cl = tid & 63, rq = tid >> 6;
  float s[16];
  const float bias = d1_b[br * 256 + nt * 64 + cl];
  #pragma unroll
  for (int i = 0; i < 16; ++i) s[i] = bias;
  for (int k = 0; k < 256; ++k) {
    float bv = Bsl[k * 64 + cl];
    #pragma unroll
    for (int i = 0; i < 16; ++i) s[i] += Asl[(rq * 16 + i) * 256 + k] * bv;
  }
  #pragma unroll
  for (int i = 0; i < 16; ++i)
    d1o[(size_t)br * 16384 + (rq * 16 + i) * 256 + nt * 64 + cl] = fmaxf(s[i], 0.0f);
}

__global__ __launch_bounds__(256) void k8_head(const float* __restrict__ d1o,
    const float* __restrict__ d2_W, const float* __restrict__ d2_b,
    const float* __restrict__ df_W, const float* __restrict__ df_b,
    const float* __restrict__ inputs, float* __restrict__ out)
{
  __shared__ float Asl[64 * 256];
  __shared__ float Bsl[256 * 64];
  __shared__ float d2sT[64 * 65];
  __shared__ float wfs[68];
  const int br = blockIdx.x, tid = threadIdx.x;
  for (int i = tid; i < 16384; i += 256) Asl[i] = d1o[(size_t)br * 16384 + i];
  for (int i = tid; i < 16384; i += 256) Bsl[i] = d2_W[(size_t)br * 16384 + i];
  if (tid < 67) wfs[tid] = df_W[br * 67 + tid];
  __syncthreads();
  const int cl = tid & 63, rq = tid >> 6;
  float s[16];
  const float bias = d2_b[br * 64 + cl];
  #pragma unroll
  for (int i = 0; i < 16; ++i) s[i] = bias;
  for (int k = 0; k < 256; ++k) {
    float bv = Bsl[k * 64 + cl];
    #pragma unroll
    for (int i = 0; i < 16; ++i) s[i] += Asl[(rq * 16 + i) * 256 + k] * bv;
  }
  #pragma unroll
  for (int i = 0; i < 16; ++i) d2sT[cl * 65 + rq * 16 + i] = fmaxf(s[i], 0.0f);
  __syncthreads();
  if (tid < 64) {
    const int b = tid;
    const float* ip = inputs + ((size_t)b * TT + (TT - 1)) * 42;
    float acc = df_b[br] + ip[20 + br] + ip[27] * wfs[64] + ip[27 + br + 1] * wfs[65]
              + ip[27 + br + 8] * wfs[66];
    #pragma unroll 4
    for (int j = 0; j < 64; ++j) acc += d2sT[j * 65 + b] * wfs[j];
    out[b * 7 + br] = acc;
  }
}

// ------------------------------------------------ host
extern "C" void kernel_launch(void* const* d_in, const int* in_sizes, int n_in,
                              void* d_out, int out_size, void* d_ws, size_t ws_size,
                              hipStream_t stream) {
  (void)in_sizes; (void)n_in; (void)out_size;
  const float* inputs  = (const float*)d_in[0];
  const float* eco_Wk  = (const float*)d_in[1];
  const float* eco_Wr  = (const float*)d_in[2];
  const float* eco_b   = (const float*)d_in[3];
  const float* data_Wk = (const float*)d_in[4];
  const float* data_Wr = (const float*)d_in[5];
  const float* data_b  = (const float*)d_in[6];
  const float* att_Wk  = (const float*)d_in[7];
  const float* att_Wr  = (const float*)d_in[8];
  const float* att_b   = (const float*)d_in[9];
  const float* ts_Wk   = (const float*)d_in[10];
  const float* ts_Wr   = (const float*)d_in[11];
  const float* ts_b    = (const float*)d_in[12];
  const float* d1_W    = (const float*)d_in[13];
  const float* d1_b    = (const float*)d_in[14];
  const float* d2_W    = (const float*)d_in[15];
  const float* d2_b    = (const float*)d_in[16];
  const float* df_W    = (const float*)d_in[17];
  const float* df_b    = (const float*)d_in[18];

  char* ws = (char*)d_ws;
  size_t off = 0;
  auto take = [&](size_t bytes) -> void* {
    void* p = ws + off;
    off += (bytes + 255) & ~(size_t)255;
    return p;
  };
  // fixed buffers (~28 MB)
  unsigned short* wr_swz = (unsigned short*)take((size_t)22 * 262144 * 2);
  unsigned short* wk_da  = (unsigned short*)take((size_t)14 * 262144 * 2);
  unsigned short* wk_ts  = (unsigned short*)take((size_t)7  * 262144 * 2);
  unsigned long long* hbrd = (unsigned long long*)take((size_t)44 * 8192 * 8);
  float*          cstate = (float*)take((size_t)22 * 8 * 2 * 1024 * 4);
  float*          h_last = (float*)take((size_t)7 * 16384 * 4);
  float*          d1o    = (float*)take((size_t)7 * 16384 * 4);
  if (off + 4096 > ws_size) return;

  // per-step chunk cost: xW (22 LSTMs) + hs (eco + 7 data + 7 att)
  const size_t per_step = (size_t)22 * 131072 + (size_t)15 * 32768;   // 3,375,104 B
  size_t avail = ws_size - off - 4096;
  int CH = (int)(avail / per_step);
  if (CH < 1) return;
  if (CH > TT) CH = TT;
  unsigned short* xw_eco = (unsigned short*)take((size_t)CH * 131072);
  unsigned short* xw_da  = (unsigned short*)take((size_t)14 * CH * 131072);
  unsigned short* xw_ts  = (unsigned short*)take((size_t)7  * CH * 131072);
  unsigned short* hs_eco = (unsigned short*)take((size_t)CH * 32768);
  unsigned short* hs_dat = (unsigned short*)take((size_t)7 * CH * 32768);
  unsigned short* hs_att = (unsigned short*)take((size_t)7 * CH * 32768);
  if (off > ws_size) return;

  hipMemsetAsync(hbrd, 0, (size_t)44 * 8192 * 8, stream);   // tag 0 == h-state 0 (zeros)
  k0a_wr<<<dim3(8, 8, 22), 256, 0, stream>>>(eco_Wr, data_Wr, att_Wr, ts_Wr, wr_swz);
  k0b_wk<<<dim3(4, 8, 21), 256, 0, stream>>>(data_Wk, att_Wk, ts_Wk, wk_da, wk_ts);

  for (int t0 = 0; t0 < TT; t0 += CH) {
    int t1 = (t0 + CH < TT) ? (t0 + CH) : TT;
    int len = t1 - t0;
    k1_ecoxw<<<dim3(len, 4), 256, 0, stream>>>(inputs, eco_Wk, eco_b, xw_eco, t0);
    rec_kernel<0><<<dim3(8, 2, 1), 256, 0, stream>>>(wr_swz, xw_eco, hbrd,
                                                     hs_eco, nullptr, nullptr, cstate, t0, t1);
    gemm_xw<0><<<dim3(len, 8, 14), 256, 0, stream>>>(hs_eco, nullptr, wk_da,
                                                     data_Wk, att_Wk, data_b, att_b,
                                                     inputs, xw_da, t0);
    rec_kernel<1><<<dim3(8, 2, 14), 256, 0, stream>>>(wr_swz, xw_da, hbrd,
                                                      hs_dat, hs_att, nullptr, cstate, t0, t1);
    gemm_xw<1><<<dim3(len, 8, 7), 256, 0, stream>>>(hs_dat, hs_att, wk_ts,
                                                    nullptr, nullptr, ts_b, nullptr,
                                                    inputs, xw_ts, t0);
    rec_kernel<2><<<dim3(8, 2, 7), 256, 0, stream>>>(wr_swz, xw_ts, hbrd,
                                                     nullptr, nullptr, h_last, cstate, t0, t1);
  }
  k7_d1<<<dim3(4, 7), 256, 0, stream>>>(h_last, d1_W, d1_b, d1o);
  k8_head<<<7, 256, 0, stream>>>(d1o, d2_W, d2_b, df_W, df_b, inputs, (float*)d_out);
}

// Round 5
// 5134.242 us; speedup vs baseline: 3.4620x; 1.0964x over previous
//
#include <hip/hip_runtime.h>

// MM_LSTM_Age_v2 on MI355X — fused systolic pipeline.
// k0a/k0b: weight transpose->bf16.  k1: eco xW (full T).
// K_A (240 WGs, co-resident): rec0(16) -> gemm_da(112) -> rec1(112) staggered
//   pipeline via tag-embedded u64 agent-scope atomics in rings.
// K_B (168 WGs): gemm_ts(56) -> rec2(112) same scheme.
// k7/k8: dense head.

#define TT 365
#define RE 4   // hE (eco h) ring slots
#define RH 2   // rec1 h ring slots
#define RX 4   // xw ring slots

typedef short bf16x8 __attribute__((ext_vector_type(8)));
typedef unsigned short u16x8 __attribute__((ext_vector_type(8)));
typedef float f32x4 __attribute__((ext_vector_type(4)));

__device__ __forceinline__ float b2f(unsigned short u) {
  union { unsigned u32; float f; } v; v.u32 = ((unsigned)u) << 16; return v.f;
}
__device__ __forceinline__ unsigned short f2b(float f) {
  union { float f; unsigned u32; } v; v.f = f;
  unsigned u = v.u32;
  u = u + 0x7FFFu + ((u >> 16) & 1u);   // RNE
  return (unsigned short)(u >> 16);
}
__device__ __forceinline__ float sigf(float x) { return 1.0f / (1.0f + __expf(-x)); }
__device__ __forceinline__ float tanh_(float x) { return 2.0f / (1.0f + __expf(-2.0f * x)) - 1.0f; }

__device__ __forceinline__ unsigned long long ld64(const unsigned long long* p) {
  return __hip_atomic_load(p, __ATOMIC_RELAXED, __HIP_MEMORY_SCOPE_AGENT);
}
__device__ __forceinline__ void st64(unsigned long long* p, unsigned long long v) {
  __hip_atomic_store(p, v, __ATOMIC_RELAXED, __HIP_MEMORY_SCOPE_AGENT);
}
__device__ __forceinline__ unsigned ld32(const unsigned* p) {
  return __hip_atomic_load(p, __ATOMIC_RELAXED, __HIP_MEMORY_SCOPE_AGENT);
}
__device__ __forceinline__ void st32(unsigned* p, unsigned v) {
  __hip_atomic_store(p, v, __ATOMIC_RELAXED, __HIP_MEMORY_SCOPE_AGENT);
}

// ------------------------------------------------ k0a: Wr transpose -> bf16
// wr_swz per (lstm,wg): [kb 8][col 128][ks 32], col = gate*32+hi
__global__ __launch_bounds__(256) void k0a_wr(const float* __restrict__ eco_Wr,
    const float* __restrict__ data_Wr, const float* __restrict__ att_Wr,
    const float* __restrict__ ts_Wr, unsigned short* __restrict__ wr_swz)
{
  __shared__ float ls[32 * 133];
  const int kb = blockIdx.x, wg = blockIdx.y, l = blockIdx.z, tid = threadIdx.x;
  const float* src;
  if (l == 0) src = eco_Wr;
  else if (l < 15) { int d = l - 1; src = ((d & 1) ? att_Wr : data_Wr) + (size_t)(d >> 1) * 262144; }
  else src = ts_Wr + (size_t)(l - 15) * 262144;
  for (int e = tid; e < 4096; e += 256) {
    int ks = e >> 7, col = e & 127;
    int gate = col >> 5, hi = col & 31;
    ls[ks * 133 + col] = src[(size_t)(kb * 32 + ks) * 1024 + gate * 256 + wg * 32 + hi];
  }
  __syncthreads();
  unsigned short* out = wr_swz + (((size_t)l * 8 + wg) * 8 + kb) * 4096;
  for (int e = tid; e < 4096; e += 256) {
    int col = e >> 5, ks = e & 31;
    out[e] = f2b(ls[ks * 133 + col]);
  }
}

// ------------------------------------------------ k0b: Wk transpose -> bf16
__global__ __launch_bounds__(256) void k0b_wk(const float* __restrict__ data_Wk,
    const float* __restrict__ att_Wk, const float* __restrict__ ts_Wk,
    unsigned short* __restrict__ wk_da, unsigned short* __restrict__ wk_ts)
{
  __shared__ float ls[32 * 261];
  const int cc = blockIdx.x, kb = blockIdx.y, d = blockIdx.z, tid = threadIdx.x;
  const float* src; unsigned short* dst; int roff;
  if (d < 14) { src = ((d & 1) ? att_Wk : data_Wk) + (size_t)(d >> 1) * 266240;
                dst = wk_da + (size_t)d * 262144; roff = 4; }
  else { src = ts_Wk + (size_t)(d - 14) * 262144;
         dst = wk_ts + (size_t)(d - 14) * 262144; roff = 0; }
  for (int e = tid; e < 8192; e += 256) {
    int ks = e >> 8, c2 = e & 255;
    ls[ks * 261 + c2] = src[(size_t)(roff + kb * 32 + ks) * 1024 + cc * 256 + c2];
  }
  __syncthreads();
  for (int e = tid; e < 8192; e += 256) {
    int col2 = e >> 5, ks = e & 31;
    dst[(size_t)kb * 32768 + (cc * 256 + col2) * 32 + ks] = f2b(ls[ks * 261 + col2]);
  }
}

// ------------------------------------------------ k1: eco xW full T
__global__ __launch_bounds__(256) void k1_ecoxw(const float* __restrict__ inputs,
    const float* __restrict__ eco_Wk, const float* __restrict__ eco_b,
    unsigned short* __restrict__ xw_eco)
{
  __shared__ float Asl[64 * 35];
  __shared__ float Bsl[35 * 256];
  const int tg = blockIdx.x, ct = blockIdx.y, tid = threadIdx.x;
  for (int i = tid; i < 64 * 35; i += 256) {
    int b = i / 35, k = i - b * 35;
    int col = (k < 20) ? k : (k + 7);
    Asl[i] = inputs[((size_t)b * TT + tg) * 42 + col];
  }
  for (int i = tid; i < 35 * 256; i += 256) {
    int k = i >> 8, c = i & 255;
    Bsl[i] = eco_Wk[(size_t)k * 1024 + ct * 256 + c];
  }
  __syncthreads();
  const float bias = eco_b[ct * 256 + tid];
  for (int r = 0; r < 64; ++r) {
    float s = bias;
    #pragma unroll
    for (int k = 0; k < 35; ++k) s += Asl[r * 35 + k] * Bsl[k * 256 + tid];
    xw_eco[((size_t)tg * 64 + r) * 1024 + ct * 256 + tid] = f2b(s);
  }
}

// ================================================ K_A: rec0 + gemm_da + rec1
__global__ __launch_bounds__(256, 1) void kA(
    const unsigned short* __restrict__ wr_swz,
    const unsigned short* __restrict__ wk_da,
    const unsigned short* __restrict__ xw_eco,
    const float* __restrict__ inputs,
    const float* __restrict__ data_Wk, const float* __restrict__ att_Wk,
    const float* __restrict__ data_b, const float* __restrict__ att_b,
    unsigned long long* __restrict__ hE,
    unsigned long long* __restrict__ hD,
    unsigned long long* __restrict__ xwA,
    unsigned* __restrict__ progX, unsigned* __restrict__ prog1,
    unsigned short* __restrict__ hsD, unsigned short* __restrict__ hsA_)
{
  __shared__ __align__(16) unsigned char smem[157696];
  const int tid = threadIdx.x;
  const int widx = blockIdx.x;
  const int lane = tid & 63, w = tid >> 6, c = lane & 15, grp = lane >> 4;

  if (widx < 16) {
    // -------- rec0: eco LSTM, 32-batch x 32-hid per WG
    unsigned short* WR = (unsigned short*)smem;             // 81920
    unsigned short* Hs = (unsigned short*)(smem + 81920);   // 20480
    float* zsh = (float*)(smem + 102400);                   // 16896
    float* cst = (float*)(smem + 119296);                   // 4096
    const int wg = widx >> 1, bg = widx & 1;
    const unsigned short* wr_g = wr_swz + (size_t)wg * 32768;
    for (int i = tid * 8; i < 32768; i += 2048) {
      int kb = i >> 12; int rr = i & 4095; int col = rr >> 5; int ks = rr & 31;
      *(uint4*)&WR[(kb * 128 + col) * 40 + ks] = *(const uint4*)&wr_g[i];
    }
    for (int i = tid; i < 1024; i += 256) cst[i] = 0.0f;

    int xoff[16];
    #pragma unroll
    for (int rt = 0; rt < 2; ++rt)
      #pragma unroll
      for (int ct = 0; ct < 2; ++ct)
        #pragma unroll
        for (int rg = 0; rg < 4; ++rg)
          xoff[(rt * 2 + ct) * 4 + rg] =
              (bg * 32 + rt * 16 + grp * 4 + rg) * 1024 + w * 256 + wg * 32 + ct * 16 + c;
    unsigned short xva[16], xvb[16];
    #pragma unroll
    for (int i = 0; i < 16; ++i) xva[i] = xw_eco[xoff[i]];
    __syncthreads();

    for (int t = 0; t < TT; ++t) {
      unsigned short* cur = (t & 1) ? xvb : xva;
      unsigned short* nxt = (t & 1) ? xva : xvb;
      int s = t + 1;
      if (s > RE && tid < 112) {           // ring-overwrite guard on gemm_da progress
        while ((int)ld32(&progX[tid]) < s - RE) __builtin_amdgcn_s_sleep(2);
      }
      { // gather eco h(t) from hE slot t%RE (rows of this bg)
        const unsigned long long* hb = hE + (size_t)(t % RE) * 8192 + (size_t)bg * 32 * 128;
        unsigned long long v[16];
        #pragma unroll
        for (int i = 0; i < 16; ++i) v[i] = ld64(&hb[tid + i * 256]);
        const unsigned tagv = (unsigned)t;
        int tries = 0;
        while (true) {
          unsigned pend = 0u;
          #pragma unroll
          for (int i = 0; i < 16; ++i)
            pend |= ((unsigned)(v[i] >> 32) != tagv) ? (1u << i) : 0u;
          if (!pend) break;
          if (++tries > 8) __builtin_amdgcn_s_sleep(1);
          #pragma unroll
          for (int i = 0; i < 16; ++i)
            if (pend & (1u << i)) v[i] = ld64(&hb[tid + i * 256]);
        }
        #pragma unroll
        for (int i = 0; i < 16; ++i) {
          int m = tid + i * 256;
          int rl = m >> 7, cp = m & 127;
          *(unsigned int*)&Hs[((cp >> 4) * 32 + rl) * 40 + 2 * (cp & 15)] = (unsigned int)v[i];
        }
      }
      __syncthreads();
      f32x4 acc[4];
      #pragma unroll
      for (int i = 0; i < 4; ++i)
        #pragma unroll
        for (int rg = 0; rg < 4; ++rg) acc[i][rg] = b2f(cur[i * 4 + rg]);
      if (t + 1 < TT) {
        const unsigned short* xw1 = xw_eco + (size_t)(t + 1) * 65536;
        #pragma unroll
        for (int i = 0; i < 16; ++i) nxt[i] = xw1[xoff[i]];
      }
      #pragma unroll
      for (int kb = 0; kb < 8; ++kb) {
        bf16x8 a0 = *(const bf16x8*)&Hs[(kb * 32 + c) * 40 + grp * 8];
        bf16x8 a1 = *(const bf16x8*)&Hs[(kb * 32 + 16 + c) * 40 + grp * 8];
        bf16x8 b0 = *(const bf16x8*)&WR[(kb * 128 + w * 32 + c) * 40 + grp * 8];
        bf16x8 b1 = *(const bf16x8*)&WR[(kb * 128 + w * 32 + 16 + c) * 40 + grp * 8];
        acc[0] = __builtin_amdgcn_mfma_f32_16x16x32_bf16(a0, b0, acc[0], 0, 0, 0);
        acc[1] = __builtin_amdgcn_mfma_f32_16x16x32_bf16(a0, b1, acc[1], 0, 0, 0);
        acc[2] = __builtin_amdgcn_mfma_f32_16x16x32_bf16(a1, b0, acc[2], 0, 0, 0);
        acc[3] = __builtin_amdgcn_mfma_f32_16x16x32_bf16(a1, b1, acc[3], 0, 0, 0);
      }
      #pragma unroll
      for (int i = 0; i < 4; ++i) {
        int rt = i >> 1, ct = i & 1;
        #pragma unroll
        for (int rg = 0; rg < 4; ++rg)
          zsh[(rt * 16 + grp * 4 + rg) * 132 + w * 32 + ct * 16 + c] = acc[i][rg];
      }
      __syncthreads();
      { // cell update + publish to hE slot (t+1)%RE
        const unsigned long long tg = ((unsigned long long)(unsigned)(t + 1)) << 32;
        unsigned long long* ho = hE + (size_t)((t + 1) % RE) * 8192;
        #pragma unroll
        for (int it = 0; it < 2; ++it) {
          int m = tid + it * 256;
          int row = m >> 4, hp = m & 15;
          float2 zi = *(const float2*)&zsh[row * 132 + 2 * hp];
          float2 zf = *(const float2*)&zsh[row * 132 + 32 + 2 * hp];
          float2 zg = *(const float2*)&zsh[row * 132 + 64 + 2 * hp];
          float2 zo = *(const float2*)&zsh[row * 132 + 96 + 2 * hp];
          int u0 = row * 32 + 2 * hp;
          float cna = sigf(zf.x) * cst[u0] + sigf(zi.x) * tanh_(zg.x);
          float cnb = sigf(zf.y) * cst[u0 + 1] + sigf(zi.y) * tanh_(zg.y);
          float hva = sigf(zo.x) * tanh_(cna);
          float hvb = sigf(zo.y) * tanh_(cnb);
          cst[u0] = cna; cst[u0 + 1] = cnb;
          unsigned int pv = (unsigned)f2b(hva) | ((unsigned)f2b(hvb) << 16);
          st64(&ho[(bg * 32 + row) * 128 + wg * 16 + hp], tg | pv);
        }
      }
      __syncthreads();
    }
  } else if (widx < 128) {
    // -------- gemm_da: xw for data/att LSTM l1, 128-col slice nt
    unsigned short* Bls = (unsigned short*)smem;             // 81920
    unsigned short* Als = (unsigned short*)(smem + 81920);   // 40960 (reused as ostg)
    float* b_sp = (float*)(smem + 122880);                   // 2048
    float* bias_s = (float*)(smem + 124928);                 // 512
    float* a_sp = (float*)(smem + 125440);                   // 1024
    const int z = widx - 16, l1 = z >> 3, nt = z & 7, br = l1 >> 1, kind = l1 & 1;
    const unsigned short* wk = wk_da + (size_t)l1 * 262144;
    for (int it = 0; it < 16; ++it) {
      int e = tid * 8 + it * 2048;
      int kb = e >> 12; int rr = e & 4095; int col = rr >> 5; int ks = rr & 31;
      *(uint4*)&Bls[(kb * 128 + col) * 40 + ks] =
          *(const uint4*)&wk[(size_t)kb * 32768 + (nt * 128 + col) * 32 + ks];
    }
    const float* spWk = (kind ? att_Wk : data_Wk) + (size_t)br * 266240;
    for (int i = tid; i < 512; i += 256) {
      int j = i >> 7, cl = i & 127;
      b_sp[i] = spWk[(size_t)j * 1024 + nt * 128 + cl];
    }
    if (tid < 128) bias_s[tid] = (kind ? att_b : data_b)[br * 1024 + nt * 128 + tid];
    unsigned long long* ring = xwA + (size_t)l1 * RX * 32768;
    __syncthreads();

    for (int t = 0; t < TT; ++t) {
      if (tid < 64) {
        const float* ip = inputs + ((size_t)tid * TT + t) * 42;
        a_sp[tid * 4 + 0] = ip[20 + br];
        a_sp[tid * 4 + 1] = ip[27];
        a_sp[tid * 4 + 2] = ip[27 + br + 1];
        a_sp[tid * 4 + 3] = ip[27 + br + 8];
      }
      if (t >= RX && tid < 8) {          // ring guard on rec1 progress
        while ((int)ld32(&prog1[l1 * 8 + tid]) < t - RX + 1) __builtin_amdgcn_s_sleep(2);
      }
      { // gather eco h state t+1
        const unsigned long long* hb = hE + (size_t)((t + 1) % RE) * 8192;
        unsigned long long v[32];
        #pragma unroll
        for (int i = 0; i < 32; ++i) v[i] = ld64(&hb[tid + i * 256]);
        const unsigned tagv = (unsigned)(t + 1);
        int tries = 0;
        while (true) {
          unsigned pend = 0u;
          #pragma unroll
          for (int i = 0; i < 32; ++i)
            pend |= ((unsigned)(v[i] >> 32) != tagv) ? (1u << i) : 0u;
          if (!pend) break;
          if (++tries > 8) __builtin_amdgcn_s_sleep(1);
          #pragma unroll
          for (int i = 0; i < 32; ++i)
            if (pend & (1u << i)) v[i] = ld64(&hb[tid + i * 256]);
        }
        #pragma unroll
        for (int i = 0; i < 32; ++i) {
          int m = tid + i * 256;
          int row = m >> 7, cp = m & 127;
          *(unsigned int*)&Als[((cp >> 4) * 64 + row) * 40 + 2 * (cp & 15)] = (unsigned int)v[i];
        }
      }
      __syncthreads();
      f32x4 acc[8] = {};
      #pragma unroll
      for (int kb = 0; kb < 8; ++kb) {
        bf16x8 a[4]; bf16x8 b[2];
        #pragma unroll
        for (int rt = 0; rt < 4; ++rt) a[rt] = *(const bf16x8*)&Als[(kb * 64 + rt * 16 + c) * 40 + grp * 8];
        #pragma unroll
        for (int ct = 0; ct < 2; ++ct) b[ct] = *(const bf16x8*)&Bls[(kb * 128 + w * 32 + ct * 16 + c) * 40 + grp * 8];
        #pragma unroll
        for (int rt = 0; rt < 4; ++rt)
          #pragma unroll
          for (int ct = 0; ct < 2; ++ct)
            acc[rt * 2 + ct] = __builtin_amdgcn_mfma_f32_16x16x32_bf16(a[rt], b[ct], acc[rt * 2 + ct], 0, 0, 0);
      }
      __syncthreads();
      unsigned short* ostg = Als;
      #pragma unroll
      for (int i = 0; i < 8; ++i) {
        int rt = i >> 1, ct = i & 1;
        #pragma unroll
        for (int rg = 0; rg < 4; ++rg) {
          int row = rt * 16 + grp * 4 + rg;
          int colL = w * 32 + ct * 16 + c;
          float zv = acc[i][rg] + bias_s[colL]
                   + a_sp[row * 4 + 0] * b_sp[colL]       + a_sp[row * 4 + 1] * b_sp[128 + colL]
                   + a_sp[row * 4 + 2] * b_sp[256 + colL] + a_sp[row * 4 + 3] * b_sp[384 + colL];
          ostg[row * 128 + colL] = f2b(zv);
        }
      }
      __syncthreads();
      unsigned long long* slot = ring + (size_t)(t % RX) * 32768;
      const unsigned long long tg = ((unsigned long long)(unsigned)(t + 1)) << 32;
      #pragma unroll
      for (int i = 0; i < 16; ++i) {
        int m = tid + i * 256;
        int row = m >> 6, cpl = m & 63;
        unsigned int pv = (unsigned)ostg[row * 128 + cpl * 2] |
                          ((unsigned)ostg[row * 128 + cpl * 2 + 1] << 16);
        st64(&slot[row * 512 + nt * 64 + cpl], tg | pv);
      }
      __syncthreads();
      if (tid == 0) st32(&progX[z], (unsigned)(t + 1));
    }
  } else {
    // -------- rec1: data/att LSTM l1, 64-batch x 32-hid per WG
    unsigned short* WR = (unsigned short*)smem;             // 81920
    unsigned short* Hs = (unsigned short*)(smem + 81920);   // 40960
    float* zsh = (float*)(smem + 122880);                   // 33792
    const int q = widx - 128, l1 = q >> 3, colwg = q & 7, br = l1 >> 1;
    const bool act_sig = (l1 & 1);
    const unsigned short* wr_g = wr_swz + ((size_t)(1 + l1) * 8 + colwg) * 32768;
    for (int i = tid * 8; i < 32768; i += 2048) {
      int kb = i >> 12; int rr = i & 4095; int col = rr >> 5; int ks = rr & 31;
      *(uint4*)&WR[(kb * 128 + col) * 40 + ks] = *(const uint4*)&wr_g[i];
    }
    float creg[8];
    #pragma unroll
    for (int j = 0; j < 8; ++j) creg[j] = 0.0f;
    int ixw[32];
    #pragma unroll
    for (int rt = 0; rt < 4; ++rt)
      #pragma unroll
      for (int ct = 0; ct < 2; ++ct)
        #pragma unroll
        for (int rg = 0; rg < 4; ++rg) {
          int row = rt * 16 + grp * 4 + rg;
          int col = w * 256 + colwg * 32 + ct * 16 + c;
          ixw[(rt * 2 + ct) * 4 + rg] = row * 512 + (col >> 1);
        }
    const int half = c & 1;
    unsigned long long* hring = hD + (size_t)l1 * RH * 8192;
    unsigned long long* xring = xwA + (size_t)l1 * RX * 32768;
    unsigned short* hs_out = (act_sig ? hsA_ : hsD) + (size_t)br * TT * 16384;
    const int urow = tid >> 2, usub = tid & 3;
    __syncthreads();

    for (int t = 0; t < TT; ++t) {
      unsigned long long vx[32];
      { // poll xw(t) state t+1
        const unsigned long long* slot = xring + (size_t)(t % RX) * 32768;
        #pragma unroll
        for (int i = 0; i < 32; ++i) vx[i] = ld64(&slot[ixw[i]]);
        const unsigned tagv = (unsigned)(t + 1);
        int tries = 0;
        while (true) {
          unsigned pend = 0u;
          #pragma unroll
          for (int i = 0; i < 32; ++i)
            pend |= ((unsigned)(vx[i] >> 32) != tagv) ? (1u << i) : 0u;
          if (!pend) break;
          if (++tries > 8) __builtin_amdgcn_s_sleep(1);
          #pragma unroll
          for (int i = 0; i < 32; ++i)
            if (pend & (1u << i)) vx[i] = ld64(&slot[ixw[i]]);
        }
      }
      { // gather own-lstm h state t
        const unsigned long long* hb = hring + (size_t)(t % RH) * 8192;
        unsigned long long v[32];
        #pragma unroll
        for (int i = 0; i < 32; ++i) v[i] = ld64(&hb[tid + i * 256]);
        const unsigned tagv = (unsigned)t;
        int tries = 0;
        while (true) {
          unsigned pend = 0u;
          #pragma unroll
          for (int i = 0; i < 32; ++i)
            pend |= ((unsigned)(v[i] >> 32) != tagv) ? (1u << i) : 0u;
          if (!pend) break;
          if (++tries > 8) __builtin_amdgcn_s_sleep(1);
          #pragma unroll
          for (int i = 0; i < 32; ++i)
            if (pend & (1u << i)) v[i] = ld64(&hb[tid + i * 256]);
        }
        #pragma unroll
        for (int i = 0; i < 32; ++i) {
          int m = tid + i * 256;
          int row = m >> 7, cp = m & 127;
          *(unsigned int*)&Hs[((cp >> 4) * 64 + row) * 40 + 2 * (cp & 15)] = (unsigned int)v[i];
        }
      }
      __syncthreads();
      f32x4 acc[8];
      #pragma unroll
      for (int i = 0; i < 8; ++i)
        #pragma unroll
        for (int rg = 0; rg < 4; ++rg) {
          unsigned int lo = (unsigned int)vx[i * 4 + rg];
          acc[i][rg] = b2f(half ? (unsigned short)(lo >> 16) : (unsigned short)lo);
        }
      #pragma unroll
      for (int kb = 0; kb < 8; ++kb) {
        bf16x8 a[4]; bf16x8 b[2];
        #pragma unroll
        for (int rt = 0; rt < 4; ++rt) a[rt] = *(const bf16x8*)&Hs[(kb * 64 + rt * 16 + c) * 40 + grp * 8];
        #pragma unroll
        for (int ct = 0; ct < 2; ++ct) b[ct] = *(const bf16x8*)&WR[(kb * 128 + w * 32 + ct * 16 + c) * 40 + grp * 8];
        #pragma unroll
        for (int rt = 0; rt < 4; ++rt)
          #pragma unroll
          for (int ct = 0; ct < 2; ++ct)
            acc[rt * 2 + ct] = __builtin_amdgcn_mfma_f32_16x16x32_bf16(a[rt], b[ct], acc[rt * 2 + ct], 0, 0, 0);
      }
      #pragma unroll
      for (int i = 0; i < 8; ++i) {
        int rt = i >> 1, ct = i & 1;
        #pragma unroll
        for (int rg = 0; rg < 4; ++rg)
          zsh[(rt * 16 + grp * 4 + rg) * 132 + w * 32 + ct * 16 + c] = acc[i][rg];
      }
      __syncthreads();
      { // cell update (8 units/thread), publish h + plain hs
        unsigned short hbf[8];
        #pragma unroll
        for (int j = 0; j < 8; ++j) {
          int hid = usub * 8 + j;
          float zi = zsh[urow * 132 + hid];
          float zf = zsh[urow * 132 + 32 + hid];
          float zg = zsh[urow * 132 + 64 + hid];
          float zo = zsh[urow * 132 + 96 + hid];
          float gv = act_sig ? sigf(zg) : tanh_(zg);
          float cn = sigf(zf) * creg[j] + sigf(zi) * gv;
          float hv = sigf(zo) * (act_sig ? sigf(cn) : tanh_(cn));
          creg[j] = cn;
          hbf[j] = f2b(hv);
        }
        unsigned int pv[4];
        #pragma unroll
        for (int p = 0; p < 4; ++p)
          pv[p] = (unsigned)hbf[2 * p] | ((unsigned)hbf[2 * p + 1] << 16);
        unsigned long long* ho = hring + (size_t)((t + 1) % RH) * 8192;
        const unsigned long long tg = ((unsigned long long)(unsigned)(t + 1)) << 32;
        #pragma unroll
        for (int p = 0; p < 4; ++p)
          st64(&ho[urow * 128 + colwg * 16 + usub * 4 + p], tg | pv[p]);
        *(uint4*)&hs_out[((size_t)t * 64 + urow) * 256 + colwg * 32 + usub * 8] =
            make_uint4(pv[0], pv[1], pv[2], pv[3]);
      }
      __syncthreads();
      if (tid == 0) st32(&prog1[l1 * 8 + colwg], (unsigned)(t + 1));
    }
  }
}

// ================================================ K_B: gemm_ts + rec2
__global__ __launch_bounds__(256, 1) void kB(
    const unsigned short* __restrict__ wr_swz,
    const unsigned short* __restrict__ wk_ts,
    const float* __restrict__ ts_b,
    const unsigned short* __restrict__ hsD, const unsigned short* __restrict__ hsA_,
    unsigned long long* __restrict__ hb2,
    unsigned long long* __restrict__ xwB,
    unsigned* __restrict__ prog2,
    float* __restrict__ h_last)
{
  __shared__ __align__(16) unsigned char smem[126976];
  const int tid = threadIdx.x;
  const int widx = blockIdx.x;
  const int lane = tid & 63, w = tid >> 6, c = lane & 15, grp = lane >> 4;

  if (widx < 56) {
    // -------- gemm_ts: xw for ts LSTM d, slice nt; A = hs_dat*hs_att
    unsigned short* Bls = (unsigned short*)smem;             // 81920
    unsigned short* Als = (unsigned short*)(smem + 81920);   // 40960
    float* bias_s = (float*)(smem + 122880);                 // 512
    const int d = widx >> 3, nt = widx & 7;
    const unsigned short* wk = wk_ts + (size_t)d * 262144;
    for (int it = 0; it < 16; ++it) {
      int e = tid * 8 + it * 2048;
      int kb = e >> 12; int rr = e & 4095; int col = rr >> 5; int ks = rr & 31;
      *(uint4*)&Bls[(kb * 128 + col) * 40 + ks] =
          *(const uint4*)&wk[(size_t)kb * 32768 + (nt * 128 + col) * 32 + ks];
    }
    if (tid < 128) bias_s[tid] = ts_b[d * 1024 + nt * 128 + tid];
    const unsigned short* pd = hsD + (size_t)d * TT * 16384;
    const unsigned short* pa = hsA_ + (size_t)d * TT * 16384;
    unsigned long long* ring = xwB + (size_t)d * RX * 32768;
    __syncthreads();

    for (int t = 0; t < TT; ++t) {
      if (t >= RX && tid < 16) {
        while ((int)ld32(&prog2[d * 16 + tid]) < t - RX + 1) __builtin_amdgcn_s_sleep(2);
      }
      #pragma unroll
      for (int ii = 0; ii < 8; ++ii) {
        int e = tid * 8 + ii * 2048;
        int row = e >> 8, k = e & 255, kb = k >> 5, ks = k & 31;
        size_t g = ((size_t)t * 64 + row) * 256 + k;
        u16x8 vd = *(const u16x8*)&pd[g];
        u16x8 va = *(const u16x8*)&pa[g];
        u16x8 vp;
        #pragma unroll
        for (int j = 0; j < 8; ++j) vp[j] = f2b(b2f(vd[j]) * b2f(va[j]));
        *(u16x8*)&Als[(kb * 64 + row) * 40 + ks] = vp;
      }
      __syncthreads();
      f32x4 acc[8] = {};
      #pragma unroll
      for (int kb = 0; kb < 8; ++kb) {
        bf16x8 a[4]; bf16x8 b[2];
        #pragma unroll
        for (int rt = 0; rt < 4; ++rt) a[rt] = *(const bf16x8*)&Als[(kb * 64 + rt * 16 + c) * 40 + grp * 8];
        #pragma unroll
        for (int ct = 0; ct < 2; ++ct) b[ct] = *(const bf16x8*)&Bls[(kb * 128 + w * 32 + ct * 16 + c) * 40 + grp * 8];
        #pragma unroll
        for (int rt = 0; rt < 4; ++rt)
          #pragma unroll
          for (int ct = 0; ct < 2; ++ct)
            acc[rt * 2 + ct] = __builtin_amdgcn_mfma_f32_16x16x32_bf16(a[rt], b[ct], acc[rt * 2 + ct], 0, 0, 0);
      }
      __syncthreads();
      unsigned short* ostg = Als;
      #pragma unroll
      for (int i = 0; i < 8; ++i) {
        int rt = i >> 1, ct = i & 1;
        #pragma unroll
        for (int rg = 0; rg < 4; ++rg) {
          int row = rt * 16 + grp * 4 + rg;
          int colL = w * 32 + ct * 16 + c;
          ostg[row * 128 + colL] = f2b(acc[i][rg] + bias_s[colL]);
        }
      }
      __syncthreads();
      unsigned long long* slot = ring + (size_t)(t % RX) * 32768;
      const unsigned long long tg = ((unsigned long long)(unsigned)(t + 1)) << 32;
      #pragma unroll
      for (int i = 0; i < 16; ++i) {
        int m = tid + i * 256;
        int row = m >> 6, cpl = m & 63;
        unsigned int pv = (unsigned)ostg[row * 128 + cpl * 2] |
                          ((unsigned)ostg[row * 128 + cpl * 2 + 1] << 16);
        st64(&slot[row * 512 + nt * 64 + cpl], tg | pv);
      }
      __syncthreads();
    }
  } else {
    // -------- rec2: ts LSTM d, 32-batch x 32-hid per WG
    unsigned short* WR = (unsigned short*)smem;             // 81920
    unsigned short* Hs = (unsigned short*)(smem + 81920);   // 20480
    float* zsh = (float*)(smem + 102400);                   // 16896
    float* cst = (float*)(smem + 119296);                   // 4096
    const int r = widx - 56, d = r >> 4, sub = r & 15, colwg = sub >> 1, bg = sub & 1;
    const unsigned short* wr_g = wr_swz + ((size_t)(15 + d) * 8 + colwg) * 32768;
    for (int i = tid * 8; i < 32768; i += 2048) {
      int kb = i >> 12; int rr = i & 4095; int col = rr >> 5; int ks = rr & 31;
      *(uint4*)&WR[(kb * 128 + col) * 40 + ks] = *(const uint4*)&wr_g[i];
    }
    for (int i = tid; i < 1024; i += 256) cst[i] = 0.0f;
    int ixw[16];
    #pragma unroll
    for (int rt = 0; rt < 2; ++rt)
      #pragma unroll
      for (int ct = 0; ct < 2; ++ct)
        #pragma unroll
        for (int rg = 0; rg < 4; ++rg) {
          int row = bg * 32 + rt * 16 + grp * 4 + rg;
          int col = w * 256 + colwg * 32 + ct * 16 + c;
          ixw[(rt * 2 + ct) * 4 + rg] = row * 512 + (col >> 1);
        }
    const int half = c & 1;
    unsigned long long* hbrd = hb2 + (size_t)(d * 2 + bg) * 8192;
    unsigned long long* ring = xwB + (size_t)d * RX * 32768;
    __syncthreads();

    for (int t = 0; t < TT; ++t) {
      unsigned long long vx[16];
      { // poll xw(t)
        const unsigned long long* slot = ring + (size_t)(t % RX) * 32768;
        #pragma unroll
        for (int i = 0; i < 16; ++i) vx[i] = ld64(&slot[ixw[i]]);
        const unsigned tagv = (unsigned)(t + 1);
        int tries = 0;
        while (true) {
          unsigned pend = 0u;
          #pragma unroll
          for (int i = 0; i < 16; ++i)
            pend |= ((unsigned)(vx[i] >> 32) != tagv) ? (1u << i) : 0u;
          if (!pend) break;
          if (++tries > 8) __builtin_amdgcn_s_sleep(1);
          #pragma unroll
          for (int i = 0; i < 16; ++i)
            if (pend & (1u << i)) vx[i] = ld64(&slot[ixw[i]]);
        }
      }
      { // gather own h(t)
        const unsigned long long* hb = hbrd + (size_t)(t & 1) * 4096;
        unsigned long long v[16];
        #pragma unroll
        for (int i = 0; i < 16; ++i) v[i] = ld64(&hb[tid + i * 256]);
        const unsigned tagv = (unsigned)t;
        int tries = 0;
        while (true) {
          unsigned pend = 0u;
          #pragma unroll
          for (int i = 0; i < 16; ++i)
            pend |= ((unsigned)(v[i] >> 32) != tagv) ? (1u << i) : 0u;
          if (!pend) break;
          if (++tries > 8) __builtin_amdgcn_s_sleep(1);
          #pragma unroll
          for (int i = 0; i < 16; ++i)
            if (pend & (1u << i)) v[i] = ld64(&hb[tid + i * 256]);
        }
        #pragma unroll
        for (int i = 0; i < 16; ++i) {
          int m = tid + i * 256;
          int row = m >> 7, cp = m & 127;
          *(unsigned int*)&Hs[((cp >> 4) * 32 + row) * 40 + 2 * (cp & 15)] = (unsigned int)v[i];
        }
      }
      __syncthreads();
      f32x4 acc[4];
      #pragma unroll
      for (int i = 0; i < 4; ++i)
        #pragma unroll
        for (int rg = 0; rg < 4; ++rg) {
          unsigned int lo = (unsigned int)vx[i * 4 + rg];
          acc[i][rg] = b2f(half ? (unsigned short)(lo >> 16) : (unsigned short)lo);
        }
      #pragma unroll
      for (int kb = 0; kb < 8; ++kb) {
        bf16x8 a0 = *(const bf16x8*)&Hs[(kb * 32 + c) * 40 + grp * 8];
        bf16x8 a1 = *(const bf16x8*)&Hs[(kb * 32 + 16 + c) * 40 + grp * 8];
        bf16x8 b0 = *(const bf16x8*)&WR[(kb * 128 + w * 32 + c) * 40 + grp * 8];
        bf16x8 b1 = *(const bf16x8*)&WR[(kb * 128 + w * 32 + 16 + c) * 40 + grp * 8];
        acc[0] = __builtin_amdgcn_mfma_f32_16x16x32_bf16(a0, b0, acc[0], 0, 0, 0);
        acc[1] = __builtin_amdgcn_mfma_f32_16x16x32_bf16(a0, b1, acc[1], 0, 0, 0);
        acc[2] = __builtin_amdgcn_mfma_f32_16x16x32_bf16(a1, b0, acc[2], 0, 0, 0);
        acc[3] = __builtin_amdgcn_mfma_f32_16x16x32_bf16(a1, b1, acc[3], 0, 0, 0);
      }
      #pragma unroll
      for (int i = 0; i < 4; ++i) {
        int rt = i >> 1, ct = i & 1;
        #pragma unroll
        for (int rg = 0; rg < 4; ++rg)
          zsh[(rt * 16 + grp * 4 + rg) * 132 + w * 32 + ct * 16 + c] = acc[i][rg];
      }
      __syncthreads();
      { // cell update + publish h
        const unsigned long long tg = ((unsigned long long)(unsigned)(t + 1)) << 32;
        unsigned long long* ho = hbrd + (size_t)((t + 1) & 1) * 4096;
        #pragma unroll
        for (int it = 0; it < 2; ++it) {
          int m = tid + it * 256;
          int row = m >> 4, hp = m & 15;
          float2 zi = *(const float2*)&zsh[row * 132 + 2 * hp];
          float2 zf = *(const float2*)&zsh[row * 132 + 32 + 2 * hp];
          float2 zg = *(const float2*)&zsh[row * 132 + 64 + 2 * hp];
          float2 zo = *(const float2*)&zsh[row * 132 + 96 + 2 * hp];
          int u0 = row * 32 + 2 * hp;
          float cna = sigf(zf.x) * cst[u0] + sigf(zi.x) * tanh_(zg.x);
          float cnb = sigf(zf.y) * cst[u0 + 1] + sigf(zi.y) * tanh_(zg.y);
          float hva = sigf(zo.x) * tanh_(cna);
          float hvb = sigf(zo.y) * tanh_(cnb);
          cst[u0] = cna; cst[u0 + 1] = cnb;
          unsigned int pv = (unsigned)f2b(hva) | ((unsigned)f2b(hvb) << 16);
          st64(&ho[row * 128 + colwg * 16 + hp], tg | pv);
          if (t == TT - 1) {
            float* hl = h_last + (size_t)d * 16384 + (bg * 32 + row) * 256 + colwg * 32 + 2 * hp;
            hl[0] = hva; hl[1] = hvb;
          }
        }
      }
      __syncthreads();
      if (tid == 0) st32(&prog2[d * 16 + sub], (unsigned)(t + 1));
    }
  }
}

// ------------------------------------------------ head
__global__ __launch_bounds__(256) void k7_d1(const float* __restrict__ h_last,
    const float* __restrict__ d1_W, const float* __restrict__ d1_b, float* __restrict__ d1o)
{
  __shared__ float Asl[64 * 256];
  __shared__ float Bsl[256 * 64];
  const int nt = blockIdx.x, br = blockIdx.y, tid = threadIdx.x;
  const float* hl = h_last + (size_t)br * 16384;
  for (int i = tid; i < 16384; i += 256) Asl[i] = hl[i];
  const float* wp = d1_W + (size_t)br * 65536 + nt * 64;
  for (int i = tid; i < 16384; i += 256) {
    int k = i >> 6, cl = i & 63;
    Bsl[i] = wp[(size_t)k * 256 + cl];
  }
  __syncthreads();
  const int cl = tid & 63, rq = tid >> 6;
  float s[16];
  const float bias = d1_b[br * 256 + nt * 64 + cl];
  #pragma unroll
  for (int i = 0; i < 16; ++i) s[i] = bias;
  for (int k = 0; k < 256; ++k) {
    float bv = Bsl[k * 64 + cl];
    #pragma unroll
    for (int i = 0; i < 16; ++i) s[i] += Asl[(rq * 16 + i) * 256 + k] * bv;
  }
  #pragma unroll
  for (int i = 0; i < 16; ++i)
    d1o[(size_t)br * 16384 + (rq * 16 + i) * 256 + nt * 64 + cl] = fmaxf(s[i], 0.0f);
}

__global__ __launch_bounds__(256) void k8_head(const float* __restrict__ d1o,
    const float* __restrict__ d2_W, const float* __restrict__ d2_b,
    const float* __restrict__ df_W, const float* __restrict__ df_b,
    const float* __restrict__ inputs, float* __restrict__ out)
{
  __shared__ float Asl[64 * 256];
  __shared__ float Bsl[256 * 64];
  __shared__ float d2sT[64 * 65];
  __shared__ float wfs[68];
  const int br = blockIdx.x, tid = threadIdx.x;
  for (int i = tid; i < 16384; i += 256) Asl[i] = d1o[(size_t)br * 16384 + i];
  for (int i = tid; i < 16384; i += 256) Bsl[i] = d2_W[(size_t)br * 16384 + i];
  if (tid < 67) wfs[tid] = df_W[br * 67 + tid];
  __syncthreads();
  const int cl = tid & 63, rq = tid >> 6;
  float s[16];
  const float bias = d2_b[br * 64 + cl];
  #pragma unroll
  for (int i = 0; i < 16; ++i) s[i] = bias;
  for (int k = 0; k < 256; ++k) {
    float bv = Bsl[k * 64 + cl];
    #pragma unroll
    for (int i = 0; i < 16; ++i) s[i] += Asl[(rq * 16 + i) * 256 + k] * bv;
  }
  #pragma unroll
  for (int i = 0; i < 16; ++i) d2sT[cl * 65 + rq * 16 + i] = fmaxf(s[i], 0.0f);
  __syncthreads();
  if (tid < 64) {
    const int b = tid;
    const float* ip = inputs + ((size_t)b * TT + (TT - 1)) * 42;
    float acc = df_b[br] + ip[20 + br] + ip[27] * wfs[64] + ip[27 + br + 1] * wfs[65]
              + ip[27 + br + 8] * wfs[66];
    #pragma unroll 4
    for (int j = 0; j < 64; ++j) acc += d2sT[j * 65 + b] * wfs[j];
    out[b * 7 + br] = acc;
  }
}

// ------------------------------------------------ host
extern "C" void kernel_launch(void* const* d_in, const int* in_sizes, int n_in,
                              void* d_out, int out_size, void* d_ws, size_t ws_size,
                              hipStream_t stream) {
  (void)in_sizes; (void)n_in; (void)out_size;
  const float* inputs  = (const float*)d_in[0];
  const float* eco_Wk  = (const float*)d_in[1];
  const float* eco_Wr  = (const float*)d_in[2];
  const float* eco_b   = (const float*)d_in[3];
  const float* data_Wk = (const float*)d_in[4];
  const float* data_Wr = (const float*)d_in[5];
  const float* data_b  = (const float*)d_in[6];
  const float* att_Wk  = (const float*)d_in[7];
  const float* att_Wr  = (const float*)d_in[8];
  const float* att_b   = (const float*)d_in[9];
  const float* ts_Wk   = (const float*)d_in[10];
  const float* ts_Wr   = (const float*)d_in[11];
  const float* ts_b    = (const float*)d_in[12];
  const float* d1_W    = (const float*)d_in[13];
  const float* d1_b    = (const float*)d_in[14];
  const float* d2_W    = (const float*)d_in[15];
  const float* d2_b    = (const float*)d_in[16];
  const float* df_W    = (const float*)d_in[17];
  const float* df_b    = (const float*)d_in[18];

  char* ws = (char*)d_ws;
  size_t off = 0;
  auto take = [&](size_t bytes) -> void* {
    void* p = ws + off;
    off += (bytes + 255) & ~(size_t)255;
    return p;
  };
  unsigned short* wr_swz = (unsigned short*)take((size_t)22 * 262144 * 2);
  unsigned short* wk_da  = (unsigned short*)take((size_t)14 * 262144 * 2);
  unsigned short* wk_ts  = (unsigned short*)take((size_t)7  * 262144 * 2);
  unsigned short* xw_eco = (unsigned short*)take((size_t)TT * 65536 * 2);
  unsigned short* hsD    = (unsigned short*)take((size_t)7 * TT * 16384 * 2);
  unsigned short* hsA_   = (unsigned short*)take((size_t)7 * TT * 16384 * 2);
  float*          h_last = (float*)take((size_t)7 * 16384 * 4);
  float*          d1o    = (float*)take((size_t)7 * 16384 * 4);
  // --- sync region (contiguous, memset each launch) ---
  size_t sync_begin = off;
  unsigned long long* hE  = (unsigned long long*)take((size_t)RE * 8192 * 8);
  unsigned long long* hD  = (unsigned long long*)take((size_t)14 * RH * 8192 * 8);
  unsigned long long* xwA = (unsigned long long*)take((size_t)14 * RX * 32768 * 8);
  unsigned long long* hb2 = (unsigned long long*)take((size_t)7 * 2 * 8192 * 8);
  unsigned long long* xwB = (unsigned long long*)take((size_t)7 * RX * 32768 * 8);
  unsigned* progX = (unsigned*)take(112 * 4);
  unsigned* prog1 = (unsigned*)take(112 * 4);
  unsigned* prog2 = (unsigned*)take(112 * 4);
  size_t sync_bytes = off - sync_begin;
  if (off > ws_size) return;   // fail loudly (output stays zero)

  hipMemsetAsync(ws + sync_begin, 0, sync_bytes, stream);
  k0a_wr<<<dim3(8, 8, 22), 256, 0, stream>>>(eco_Wr, data_Wr, att_Wr, ts_Wr, wr_swz);
  k0b_wk<<<dim3(4, 8, 21), 256, 0, stream>>>(data_Wk, att_Wk, ts_Wk, wk_da, wk_ts);
  k1_ecoxw<<<dim3(TT, 4), 256, 0, stream>>>(inputs, eco_Wk, eco_b, xw_eco);
  kA<<<240, 256, 0, stream>>>(wr_swz, wk_da, xw_eco, inputs,
                              data_Wk, att_Wk, data_b, att_b,
                              hE, hD, xwA, progX, prog1, hsD, hsA_);
  kB<<<168, 256, 0, stream>>>(wr_swz, wk_ts, ts_b, hsD, hsA_,
                              hb2, xwB, prog2, h_last);
  k7_d1<<<dim3(4, 7), 256, 0, stream>>>(h_last, d1_W, d1_b, d1o);
  k8_head<<<7, 256, 0, stream>>>(d1o, d2_W, d2_b, df_W, df_b, inputs, (float*)d_out);
}

// Round 6
// 4875.747 us; speedup vs baseline: 3.6455x; 1.0530x over previous
//
#include <hip/hip_runtime.h>

// MM_LSTM_Age_v2 on MI355X — fused systolic pipeline, low-fabric-traffic rev.
// k0a/k0b: weight transpose->bf16.  k1: eco xW (full T).
// kA (128 WGs co-resident): rec0(16) + rec1(112, xW fused w/ Wk in VGPRs).
//   h exchange: 4x bf16 packed in u64, relaxed agent atomics; per-producer
//   flag words (payload stores -> s_waitcnt -> barrier -> flag store).
// kB (112 WGs): rec2 with ts-xW fused (A = hsD*hsA from plain cached reads).
// k7/k8: dense head.

#define TT 365
#define RE 4   // eco h ring slots

typedef short bf16x8 __attribute__((ext_vector_type(8)));
typedef unsigned short u16x8 __attribute__((ext_vector_type(8)));
typedef float f32x4 __attribute__((ext_vector_type(4)));

__device__ __forceinline__ float b2f(unsigned short u) {
  union { unsigned u32; float f; } v; v.u32 = ((unsigned)u) << 16; return v.f;
}
__device__ __forceinline__ unsigned short f2b(float f) {
  union { float f; unsigned u32; } v; v.f = f;
  unsigned u = v.u32;
  u = u + 0x7FFFu + ((u >> 16) & 1u);   // RNE
  return (unsigned short)(u >> 16);
}
__device__ __forceinline__ float sigf(float x) { return 1.0f / (1.0f + __expf(-x)); }
__device__ __forceinline__ float tanh_(float x) { return 2.0f / (1.0f + __expf(-2.0f * x)) - 1.0f; }

__device__ __forceinline__ unsigned long long ld64(const unsigned long long* p) {
  return __hip_atomic_load(p, __ATOMIC_RELAXED, __HIP_MEMORY_SCOPE_AGENT);
}
__device__ __forceinline__ void st64(unsigned long long* p, unsigned long long v) {
  __hip_atomic_store(p, v, __ATOMIC_RELAXED, __HIP_MEMORY_SCOPE_AGENT);
}
__device__ __forceinline__ unsigned ld32(const unsigned* p) {
  return __hip_atomic_load(p, __ATOMIC_RELAXED, __HIP_MEMORY_SCOPE_AGENT);
}
__device__ __forceinline__ void st32(unsigned* p, unsigned v) {
  __hip_atomic_store(p, v, __ATOMIC_RELAXED, __HIP_MEMORY_SCOPE_AGENT);
}
__device__ __forceinline__ unsigned long long pack4(float a, float b, float c, float d) {
  return (unsigned long long)f2b(a) | ((unsigned long long)f2b(b) << 16)
       | ((unsigned long long)f2b(c) << 32) | ((unsigned long long)f2b(d) << 48);
}

// ------------------------------------------------ k0a: Wr transpose -> bf16
// wr_swz per (lstm,wg): [kb 8][col 128][ks 32], col = gate*32+hi
__global__ __launch_bounds__(256) void k0a_wr(const float* __restrict__ eco_Wr,
    const float* __restrict__ data_Wr, const float* __restrict__ att_Wr,
    const float* __restrict__ ts_Wr, unsigned short* __restrict__ wr_swz)
{
  __shared__ float ls[32 * 133];
  const int kb = blockIdx.x, wg = blockIdx.y, l = blockIdx.z, tid = threadIdx.x;
  const float* src;
  if (l == 0) src = eco_Wr;
  else if (l < 15) { int d = l - 1; src = ((d & 1) ? att_Wr : data_Wr) + (size_t)(d >> 1) * 262144; }
  else src = ts_Wr + (size_t)(l - 15) * 262144;
  for (int e = tid; e < 4096; e += 256) {
    int ks = e >> 7, col = e & 127;
    int gate = col >> 5, hi = col & 31;
    ls[ks * 133 + col] = src[(size_t)(kb * 32 + ks) * 1024 + gate * 256 + wg * 32 + hi];
  }
  __syncthreads();
  unsigned short* out = wr_swz + (((size_t)l * 8 + wg) * 8 + kb) * 4096;
  for (int e = tid; e < 4096; e += 256) {
    int col = e >> 5, ks = e & 31;
    out[e] = f2b(ls[ks * 133 + col]);
  }
}

// ------------------------------------------------ k0b: Wk transpose -> bf16
// wk layout per lstm: [kb 8][col 1024][ks 32] (data/att use K rows 4..259)
__global__ __launch_bounds__(256) void k0b_wk(const float* __restrict__ data_Wk,
    const float* __restrict__ att_Wk, const float* __restrict__ ts_Wk,
    unsigned short* __restrict__ wk_da, unsigned short* __restrict__ wk_ts)
{
  __shared__ float ls[32 * 261];
  const int cc = blockIdx.x, kb = blockIdx.y, d = blockIdx.z, tid = threadIdx.x;
  const float* src; unsigned short* dst; int roff;
  if (d < 14) { src = ((d & 1) ? att_Wk : data_Wk) + (size_t)(d >> 1) * 266240;
                dst = wk_da + (size_t)d * 262144; roff = 4; }
  else { src = ts_Wk + (size_t)(d - 14) * 262144;
         dst = wk_ts + (size_t)(d - 14) * 262144; roff = 0; }
  for (int e = tid; e < 8192; e += 256) {
    int ks = e >> 8, c2 = e & 255;
    ls[ks * 261 + c2] = src[(size_t)(roff + kb * 32 + ks) * 1024 + cc * 256 + c2];
  }
  __syncthreads();
  for (int e = tid; e < 8192; e += 256) {
    int col2 = e >> 5, ks = e & 31;
    dst[(size_t)kb * 32768 + (cc * 256 + col2) * 32 + ks] = f2b(ls[ks * 261 + col2]);
  }
}

// ------------------------------------------------ k1: eco xW full T
__global__ __launch_bounds__(256) void k1_ecoxw(const float* __restrict__ inputs,
    const float* __restrict__ eco_Wk, const float* __restrict__ eco_b,
    unsigned short* __restrict__ xw_eco)
{
  __shared__ float Asl[64 * 35];
  __shared__ float Bsl[35 * 256];
  const int tg = blockIdx.x, ct = blockIdx.y, tid = threadIdx.x;
  for (int i = tid; i < 64 * 35; i += 256) {
    int b = i / 35, k = i - b * 35;
    int col = (k < 20) ? k : (k + 7);
    Asl[i] = inputs[((size_t)b * TT + tg) * 42 + col];
  }
  for (int i = tid; i < 35 * 256; i += 256) {
    int k = i >> 8, c = i & 255;
    Bsl[i] = eco_Wk[(size_t)k * 1024 + ct * 256 + c];
  }
  __syncthreads();
  const float bias = eco_b[ct * 256 + tid];
  for (int r = 0; r < 64; ++r) {
    float s = bias;
    #pragma unroll
    for (int k = 0; k < 35; ++k) s += Asl[r * 35 + k] * Bsl[k * 256 + tid];
    xw_eco[((size_t)tg * 64 + r) * 1024 + ct * 256 + tid] = f2b(s);
  }
}

// ================================================ kA: rec0(16) + rec1(112)
// hE: u64[RE][64 row][64 hq] (hq = hid/4).  hD per l1: u64[2][64][64].
// hEf[16] (wg*2+bg), hDf[112] (l1*8+colwg): value = completed steps.
__global__ __launch_bounds__(256, 1) void kA(
    const unsigned short* __restrict__ wr_swz,
    const unsigned short* __restrict__ wk_da,
    const unsigned short* __restrict__ xw_eco,
    const float* __restrict__ inputs,
    const float* __restrict__ data_Wk, const float* __restrict__ att_Wk,
    const float* __restrict__ data_b, const float* __restrict__ att_b,
    unsigned long long* __restrict__ hE,
    unsigned long long* __restrict__ hD,
    unsigned* __restrict__ hEf, unsigned* __restrict__ hDf,
    unsigned short* __restrict__ hsD, unsigned short* __restrict__ hsA_)
{
  __shared__ __align__(16) unsigned char smem[160256];
  const int tid = threadIdx.x;
  const int widx = blockIdx.x;
  const int lane = tid & 63, w = tid >> 6, c = lane & 15, grp = lane >> 4;

  if (widx < 16) {
    // ---------------- rec0: eco LSTM, 32 batch x 32 hid per WG
    unsigned short* WR = (unsigned short*)smem;             // 81920
    unsigned short* Hs = (unsigned short*)(smem + 81920);   // 8x32x40 = 20480
    float* zsh = (float*)(smem + 102400);                   // 32x132 = 16896
    float* cst = (float*)(smem + 119296);                   // 4096
    const int wg = widx >> 1, bg = widx & 1;
    const unsigned short* wr_g = wr_swz + (size_t)wg * 32768;
    for (int i = tid * 8; i < 32768; i += 2048) {
      int kb = i >> 12; int rr = i & 4095; int col = rr >> 5; int ks = rr & 31;
      *(uint4*)&WR[(kb * 128 + col) * 40 + ks] = *(const uint4*)&wr_g[i];
    }
    for (int i = tid; i < 1024; i += 256) cst[i] = 0.0f;

    int xoff[16];
    #pragma unroll
    for (int rt = 0; rt < 2; ++rt)
      #pragma unroll
      for (int ct = 0; ct < 2; ++ct)
        #pragma unroll
        for (int rg = 0; rg < 4; ++rg)
          xoff[(rt * 2 + ct) * 4 + rg] =
              (bg * 32 + rt * 16 + grp * 4 + rg) * 1024 + w * 256 + wg * 32 + ct * 16 + c;
    unsigned short xv[16], xn[16];
    #pragma unroll
    for (int i = 0; i < 16; ++i) xv[i] = xw_eco[xoff[i]];
    __syncthreads();

    for (int t = 0; t < TT; ++t) {
      // poll: own state t written (all 16 rec0 flags), ring guard vs rec1
      if (tid < 16) {
        while (ld32(&hEf[tid]) < (unsigned)t) __builtin_amdgcn_s_sleep(1);
      } else if (tid < 128 && t + 1 > RE) {
        while ((int)ld32(&hDf[tid - 16]) < t + 1 - RE) __builtin_amdgcn_s_sleep(2);
      }
      __syncthreads();
      { // gather own state t (rows of this bg)
        const unsigned long long* hb = hE + (size_t)(t % RE) * 4096;
        unsigned long long v[8];
        #pragma unroll
        for (int i = 0; i < 8; ++i) {
          int m = tid + i * 256;
          v[i] = ld64(&hb[(bg * 32 + (m >> 6)) * 64 + (m & 63)]);
        }
        #pragma unroll
        for (int i = 0; i < 8; ++i) {
          int m = tid + i * 256, row = m >> 6, hq = m & 63;
          *(unsigned long long*)&Hs[((hq >> 3) * 32 + row) * 40 + (hq & 7) * 4] = v[i];
        }
      }
      __syncthreads();
      f32x4 acc[4];
      #pragma unroll
      for (int i = 0; i < 4; ++i)
        #pragma unroll
        for (int rg = 0; rg < 4; ++rg) acc[i][rg] = b2f(xv[i * 4 + rg]);
      if (t + 1 < TT) {
        const unsigned short* xw1 = xw_eco + (size_t)(t + 1) * 65536;
        #pragma unroll
        for (int i = 0; i < 16; ++i) xn[i] = xw1[xoff[i]];
      }
      #pragma unroll
      for (int kb = 0; kb < 8; ++kb) {
        bf16x8 a0 = *(const bf16x8*)&Hs[(kb * 32 + c) * 40 + grp * 8];
        bf16x8 a1 = *(const bf16x8*)&Hs[(kb * 32 + 16 + c) * 40 + grp * 8];
        bf16x8 b0 = *(const bf16x8*)&WR[(kb * 128 + w * 32 + c) * 40 + grp * 8];
        bf16x8 b1 = *(const bf16x8*)&WR[(kb * 128 + w * 32 + 16 + c) * 40 + grp * 8];
        acc[0] = __builtin_amdgcn_mfma_f32_16x16x32_bf16(a0, b0, acc[0], 0, 0, 0);
        acc[1] = __builtin_amdgcn_mfma_f32_16x16x32_bf16(a0, b1, acc[1], 0, 0, 0);
        acc[2] = __builtin_amdgcn_mfma_f32_16x16x32_bf16(a1, b0, acc[2], 0, 0, 0);
        acc[3] = __builtin_amdgcn_mfma_f32_16x16x32_bf16(a1, b1, acc[3], 0, 0, 0);
      }
      #pragma unroll
      for (int i = 0; i < 4; ++i) {
        int rt = i >> 1, ct = i & 1;
        #pragma unroll
        for (int rg = 0; rg < 4; ++rg)
          zsh[(rt * 16 + grp * 4 + rg) * 132 + w * 32 + ct * 16 + c] = acc[i][rg];
      }
      __syncthreads();
      { // cell update: 1 row x 4 hid per thread, publish 4-packed
        int row = tid >> 3, hq8 = tid & 7;
        float4 zi = *(const float4*)&zsh[row * 132 +      hq8 * 4];
        float4 zf = *(const float4*)&zsh[row * 132 + 32 + hq8 * 4];
        float4 zg = *(const float4*)&zsh[row * 132 + 64 + hq8 * 4];
        float4 zo = *(const float4*)&zsh[row * 132 + 96 + hq8 * 4];
        float4 c0 = *(const float4*)&cst[row * 32 + hq8 * 4];
        float cn0 = sigf(zf.x) * c0.x + sigf(zi.x) * tanh_(zg.x);
        float cn1 = sigf(zf.y) * c0.y + sigf(zi.y) * tanh_(zg.y);
        float cn2 = sigf(zf.z) * c0.z + sigf(zi.z) * tanh_(zg.z);
        float cn3 = sigf(zf.w) * c0.w + sigf(zi.w) * tanh_(zg.w);
        float hv0 = sigf(zo.x) * tanh_(cn0);
        float hv1 = sigf(zo.y) * tanh_(cn1);
        float hv2 = sigf(zo.z) * tanh_(cn2);
        float hv3 = sigf(zo.w) * tanh_(cn3);
        *(float4*)&cst[row * 32 + hq8 * 4] = make_float4(cn0, cn1, cn2, cn3);
        st64(&hE[(size_t)((t + 1) % RE) * 4096 + (bg * 32 + row) * 64 + wg * 8 + hq8],
             pack4(hv0, hv1, hv2, hv3));
      }
      __builtin_amdgcn_s_waitcnt(0);
      __syncthreads();
      if (tid == 0) st32(&hEf[widx], (unsigned)(t + 1));
      #pragma unroll
      for (int i = 0; i < 16; ++i) xv[i] = xn[i];
    }
  } else {
    // ---------------- rec1: data/att LSTM l1, 64 batch x 32 hid, xW fused
    unsigned short* WR = (unsigned short*)smem;             // 81920
    unsigned short* Hs = (unsigned short*)(smem + 81920);   // 8x64x40 = 40960
    float* zsh = (float*)(smem + 122880);                   // 64x132 = 33792
    float* a_sp = (float*)(smem + 156672);                  // 1024
    float* b_sp = (float*)(smem + 157696);                  // 2048
    float* bias_s = (float*)(smem + 159744);                // 512
    const int q = widx - 16, l1 = q >> 3, colwg = q & 7, br = l1 >> 1;
    const bool act_sig = (l1 & 1);
    const unsigned short* wr_g = wr_swz + ((size_t)(1 + l1) * 8 + colwg) * 32768;
    for (int i = tid * 8; i < 32768; i += 2048) {
      int kb = i >> 12; int rr = i & 4095; int col = rr >> 5; int ks = rr & 31;
      *(uint4*)&WR[(kb * 128 + col) * 40 + ks] = *(const uint4*)&wr_g[i];
    }
    // Wk slice in VGPRs (16 B-fragments)
    bf16x8 wkf[16];
    const unsigned short* wk = wk_da + (size_t)l1 * 262144;
    #pragma unroll
    for (int kb = 0; kb < 8; ++kb)
      #pragma unroll
      for (int ct = 0; ct < 2; ++ct) {
        int col = w * 256 + colwg * 32 + ct * 16 + c;
        wkf[kb * 2 + ct] = *(const bf16x8*)&wk[kb * 32768 + col * 32 + grp * 8];
      }
    const float* spWk = (act_sig ? att_Wk : data_Wk) + (size_t)br * 266240;
    for (int i = tid; i < 512; i += 256) {
      int j = i >> 7, colL = i & 127;
      int gcol = (colL >> 5) * 256 + colwg * 32 + (colL & 31);
      b_sp[i] = spWk[(size_t)j * 1024 + gcol];
    }
    if (tid < 128) {
      int gcol = (tid >> 5) * 256 + colwg * 32 + (tid & 31);
      bias_s[tid] = (act_sig ? att_b : data_b)[br * 1024 + gcol];
    }
    float creg[8];
    #pragma unroll
    for (int j = 0; j < 8; ++j) creg[j] = 0.0f;
    unsigned long long* hDl = hD + (size_t)l1 * 8192;
    unsigned short* hs_out = (act_sig ? hsA_ : hsD) + (size_t)br * TT * 16384;
    __syncthreads();

    for (int t = 0; t < TT; ++t) {
      if (tid < 16) {
        while (ld32(&hEf[tid]) < (unsigned)(t + 1)) __builtin_amdgcn_s_sleep(1);
      } else if (tid >= 32 && tid < 40) {
        while (ld32(&hDf[l1 * 8 + (tid - 32)]) < (unsigned)t) __builtin_amdgcn_s_sleep(1);
      }
      __syncthreads();
      if (tid < 64) {
        const float* ip = inputs + ((size_t)tid * TT + t) * 42;
        a_sp[tid * 4 + 0] = ip[20 + br];
        a_sp[tid * 4 + 1] = ip[27];
        a_sp[tid * 4 + 2] = ip[27 + br + 1];
        a_sp[tid * 4 + 3] = ip[27 + br + 8];
      }
      // issue both gathers, then unpack hE first
      const unsigned long long* he = hE + (size_t)((t + 1) % RE) * 4096;
      const unsigned long long* ho = hDl + (size_t)(t & 1) * 4096;
      unsigned long long ve[16], vh[16];
      #pragma unroll
      for (int i = 0; i < 16; ++i) ve[i] = ld64(&he[tid + i * 256]);
      #pragma unroll
      for (int i = 0; i < 16; ++i) vh[i] = ld64(&ho[tid + i * 256]);
      #pragma unroll
      for (int i = 0; i < 16; ++i) {
        int m = tid + i * 256, row = m >> 6, hq = m & 63;
        *(unsigned long long*)&Hs[((hq >> 3) * 64 + row) * 40 + (hq & 7) * 4] = ve[i];
      }
      __syncthreads();
      // xW MFMA (A = eco h, B = Wk regs)
      f32x4 acc[8] = {};
      #pragma unroll
      for (int kb = 0; kb < 8; ++kb) {
        bf16x8 a[4];
        #pragma unroll
        for (int rt = 0; rt < 4; ++rt)
          a[rt] = *(const bf16x8*)&Hs[(kb * 64 + rt * 16 + c) * 40 + grp * 8];
        #pragma unroll
        for (int rt = 0; rt < 4; ++rt)
          #pragma unroll
          for (int ct = 0; ct < 2; ++ct)
            acc[rt * 2 + ct] = __builtin_amdgcn_mfma_f32_16x16x32_bf16(a[rt], wkf[kb * 2 + ct], acc[rt * 2 + ct], 0, 0, 0);
      }
      #pragma unroll
      for (int i = 0; i < 8; ++i) {
        int rt = i >> 1, ct2 = i & 1;
        #pragma unroll
        for (int rg = 0; rg < 4; ++rg) {
          int row = rt * 16 + grp * 4 + rg;
          int colL = w * 32 + ct2 * 16 + c;
          acc[i][rg] += bias_s[colL]
                      + a_sp[row * 4 + 0] * b_sp[colL]       + a_sp[row * 4 + 1] * b_sp[128 + colL]
                      + a_sp[row * 4 + 2] * b_sp[256 + colL] + a_sp[row * 4 + 3] * b_sp[384 + colL];
        }
      }
      __syncthreads();                 // done reading Hs (eco h)
      #pragma unroll
      for (int i = 0; i < 16; ++i) {
        int m = tid + i * 256, row = m >> 6, hq = m & 63;
        *(unsigned long long*)&Hs[((hq >> 3) * 64 + row) * 40 + (hq & 7) * 4] = vh[i];
      }
      __syncthreads();
      // recurrent MFMA (A = own h, B = Wr LDS)
      #pragma unroll
      for (int kb = 0; kb < 8; ++kb) {
        bf16x8 a[4]; bf16x8 b[2];
        #pragma unroll
        for (int rt = 0; rt < 4; ++rt)
          a[rt] = *(const bf16x8*)&Hs[(kb * 64 + rt * 16 + c) * 40 + grp * 8];
        #pragma unroll
        for (int ct = 0; ct < 2; ++ct)
          b[ct] = *(const bf16x8*)&WR[(kb * 128 + w * 32 + ct * 16 + c) * 40 + grp * 8];
        #pragma unroll
        for (int rt = 0; rt < 4; ++rt)
          #pragma unroll
          for (int ct = 0; ct < 2; ++ct)
            acc[rt * 2 + ct] = __builtin_amdgcn_mfma_f32_16x16x32_bf16(a[rt], b[ct], acc[rt * 2 + ct], 0, 0, 0);
      }
      #pragma unroll
      for (int i = 0; i < 8; ++i) {
        int rt = i >> 1, ct2 = i & 1;
        #pragma unroll
        for (int rg = 0; rg < 4; ++rg)
          zsh[(rt * 16 + grp * 4 + rg) * 132 + w * 32 + ct2 * 16 + c] = acc[i][rg];
      }
      __syncthreads();
      { // cell update: 2 items x 4 hid, publish 4-packed + plain hs
        unsigned long long* hon = hDl + (size_t)((t + 1) & 1) * 4096;
        #pragma unroll
        for (int it = 0; it < 2; ++it) {
          int m = tid + it * 256, row = m >> 3, hq8 = m & 7;
          float4 zi = *(const float4*)&zsh[row * 132 +      hq8 * 4];
          float4 zf = *(const float4*)&zsh[row * 132 + 32 + hq8 * 4];
          float4 zg = *(const float4*)&zsh[row * 132 + 64 + hq8 * 4];
          float4 zo = *(const float4*)&zsh[row * 132 + 96 + hq8 * 4];
          float g0 = act_sig ? sigf(zg.x) : tanh_(zg.x);
          float g1 = act_sig ? sigf(zg.y) : tanh_(zg.y);
          float g2 = act_sig ? sigf(zg.z) : tanh_(zg.z);
          float g3 = act_sig ? sigf(zg.w) : tanh_(zg.w);
          float cn0 = sigf(zf.x) * creg[it * 4 + 0] + sigf(zi.x) * g0;
          float cn1 = sigf(zf.y) * creg[it * 4 + 1] + sigf(zi.y) * g1;
          float cn2 = sigf(zf.z) * creg[it * 4 + 2] + sigf(zi.z) * g2;
          float cn3 = sigf(zf.w) * creg[it * 4 + 3] + sigf(zi.w) * g3;
          float hv0 = sigf(zo.x) * (act_sig ? sigf(cn0) : tanh_(cn0));
          float hv1 = sigf(zo.y) * (act_sig ? sigf(cn1) : tanh_(cn1));
          float hv2 = sigf(zo.z) * (act_sig ? sigf(cn2) : tanh_(cn2));
          float hv3 = sigf(zo.w) * (act_sig ? sigf(cn3) : tanh_(cn3));
          creg[it * 4 + 0] = cn0; creg[it * 4 + 1] = cn1;
          creg[it * 4 + 2] = cn2; creg[it * 4 + 3] = cn3;
          unsigned long long pv = pack4(hv0, hv1, hv2, hv3);
          st64(&hon[row * 64 + colwg * 8 + hq8], pv);
          *(unsigned long long*)&hs_out[((size_t)t * 64 + row) * 256 + colwg * 32 + hq8 * 4] = pv;
        }
      }
      __builtin_amdgcn_s_waitcnt(0);
      __syncthreads();
      if (tid == 0) st32(&hDf[q], (unsigned)(t + 1));
    }
  }
}

// ================================================ kB: rec2 (ts) w/ xW fused
// h2 per d: u64[2][64][64]; h2f[112] (d*16+sub).
__global__ __launch_bounds__(256, 1) void kB(
    const unsigned short* __restrict__ wr_swz,
    const unsigned short* __restrict__ wk_ts,
    const float* __restrict__ ts_b,
    const unsigned short* __restrict__ hsD, const unsigned short* __restrict__ hsA_,
    unsigned long long* __restrict__ h2,
    unsigned* __restrict__ h2f,
    float* __restrict__ h_last)
{
  __shared__ __align__(16) unsigned char smem[123904];
  const int tid = threadIdx.x;
  const int widx = blockIdx.x;
  const int lane = tid & 63, w = tid >> 6, c = lane & 15, grp = lane >> 4;
  unsigned short* WR = (unsigned short*)smem;             // 81920
  unsigned short* Hs = (unsigned short*)(smem + 81920);   // 8x32x40 = 20480
  float* zsh = (float*)(smem + 102400);                   // 32x132 = 16896
  float* bias_s = (float*)(smem + 119296);                // 512

  const int d = widx >> 4, sub = widx & 15, colwg = sub >> 1, bg = sub & 1;
  const unsigned short* wr_g = wr_swz + ((size_t)(15 + d) * 8 + colwg) * 32768;
  for (int i = tid * 8; i < 32768; i += 2048) {
    int kb = i >> 12; int rr = i & 4095; int col = rr >> 5; int ks = rr & 31;
    *(uint4*)&WR[(kb * 128 + col) * 40 + ks] = *(const uint4*)&wr_g[i];
  }
  bf16x8 wkf[16];
  const unsigned short* wk = wk_ts + (size_t)d * 262144;
  #pragma unroll
  for (int kb = 0; kb < 8; ++kb)
    #pragma unroll
    for (int ct = 0; ct < 2; ++ct) {
      int col = w * 256 + colwg * 32 + ct * 16 + c;
      wkf[kb * 2 + ct] = *(const bf16x8*)&wk[kb * 32768 + col * 32 + grp * 8];
    }
  if (tid < 128) {
    int gcol = (tid >> 5) * 256 + colwg * 32 + (tid & 31);
    bias_s[tid] = ts_b[d * 1024 + gcol];
  }
  float creg[4] = {0.0f, 0.0f, 0.0f, 0.0f};
  const unsigned short* pd = hsD + (size_t)d * TT * 16384;
  const unsigned short* pa = hsA_ + (size_t)d * TT * 16384;
  unsigned long long* h2d = h2 + (size_t)d * 8192;
  __syncthreads();

  for (int t = 0; t < TT; ++t) {
    if (tid < 16) {
      while (ld32(&h2f[d * 16 + tid]) < (unsigned)t) __builtin_amdgcn_s_sleep(1);
    }
    __syncthreads();
    // own-h gather (issue early) + product A staging from plain arrays
    unsigned long long vh[8];
    const unsigned long long* ho = h2d + (size_t)(t & 1) * 4096;
    #pragma unroll
    for (int i = 0; i < 8; ++i) {
      int m = tid + i * 256;
      vh[i] = ld64(&ho[(bg * 32 + (m >> 6)) * 64 + (m & 63)]);
    }
    #pragma unroll
    for (int ii = 0; ii < 4; ++ii) {
      int e = tid * 8 + ii * 2048;
      int row32 = e >> 8, k = e & 255;
      size_t g = ((size_t)t * 64 + bg * 32 + row32) * 256 + k;
      u16x8 vd = *(const u16x8*)&pd[g];
      u16x8 va = *(const u16x8*)&pa[g];
      u16x8 vp;
      #pragma unroll
      for (int j = 0; j < 8; ++j) vp[j] = f2b(b2f(vd[j]) * b2f(va[j]));
      *(u16x8*)&Hs[((k >> 5) * 32 + row32) * 40 + (k & 31)] = vp;
    }
    __syncthreads();
    f32x4 acc[4] = {};
    #pragma unroll
    for (int kb = 0; kb < 8; ++kb) {
      bf16x8 a0 = *(const bf16x8*)&Hs[(kb * 32 + c) * 40 + grp * 8];
      bf16x8 a1 = *(const bf16x8*)&Hs[(kb * 32 + 16 + c) * 40 + grp * 8];
      acc[0] = __builtin_amdgcn_mfma_f32_16x16x32_bf16(a0, wkf[kb * 2 + 0], acc[0], 0, 0, 0);
      acc[1] = __builtin_amdgcn_mfma_f32_16x16x32_bf16(a0, wkf[kb * 2 + 1], acc[1], 0, 0, 0);
      acc[2] = __builtin_amdgcn_mfma_f32_16x16x32_bf16(a1, wkf[kb * 2 + 0], acc[2], 0, 0, 0);
      acc[3] = __builtin_amdgcn_mfma_f32_16x16x32_bf16(a1, wkf[kb * 2 + 1], acc[3], 0, 0, 0);
    }
    #pragma unroll
    for (int i = 0; i < 4; ++i) {
      int ct2 = i & 1;
      #pragma unroll
      for (int rg = 0; rg < 4; ++rg)
        acc[i][rg] += bias_s[w * 32 + ct2 * 16 + c];
    }
    __syncthreads();
    #pragma unroll
    for (int i = 0; i < 8; ++i) {
      int m = tid + i * 256, row = m >> 6, hq = m & 63;
      *(unsigned long long*)&Hs[((hq >> 3) * 32 + row) * 40 + (hq & 7) * 4] = vh[i];
    }
    __syncthreads();
    #pragma unroll
    for (int kb = 0; kb < 8; ++kb) {
      bf16x8 a0 = *(const bf16x8*)&Hs[(kb * 32 + c) * 40 + grp * 8];
      bf16x8 a1 = *(const bf16x8*)&Hs[(kb * 32 + 16 + c) * 40 + grp * 8];
      bf16x8 b0 = *(const bf16x8*)&WR[(kb * 128 + w * 32 + c) * 40 + grp * 8];
      bf16x8 b1 = *(const bf16x8*)&WR[(kb * 128 + w * 32 + 16 + c) * 40 + grp * 8];
      acc[0] = __builtin_amdgcn_mfma_f32_16x16x32_bf16(a0, b0, acc[0], 0, 0, 0);
      acc[1] = __builtin_amdgcn_mfma_f32_16x16x32_bf16(a0, b1, acc[1], 0, 0, 0);
      acc[2] = __builtin_amdgcn_mfma_f32_16x16x32_bf16(a1, b0, acc[2], 0, 0, 0);
      acc[3] = __builtin_amdgcn_mfma_f32_16x16x32_bf16(a1, b1, acc[3], 0, 0, 0);
    }
    #pragma unroll
    for (int i = 0; i < 4; ++i) {
      int rt = i >> 1, ct2 = i & 1;
      #pragma unroll
      for (int rg = 0; rg < 4; ++rg)
        zsh[(rt * 16 + grp * 4 + rg) * 132 + w * 32 + ct2 * 16 + c] = acc[i][rg];
    }
    __syncthreads();
    { // cell: 1 row x 4 hid per thread
      int row32 = tid >> 3, hq8 = tid & 7;
      float4 zi = *(const float4*)&zsh[row32 * 132 +      hq8 * 4];
      float4 zf = *(const float4*)&zsh[row32 * 132 + 32 + hq8 * 4];
      float4 zg = *(const float4*)&zsh[row32 * 132 + 64 + hq8 * 4];
      float4 zo = *(const float4*)&zsh[row32 * 132 + 96 + hq8 * 4];
      float cn0 = sigf(zf.x) * creg[0] + sigf(zi.x) * tanh_(zg.x);
      float cn1 = sigf(zf.y) * creg[1] + sigf(zi.y) * tanh_(zg.y);
      float cn2 = sigf(zf.z) * creg[2] + sigf(zi.z) * tanh_(zg.z);
      float cn3 = sigf(zf.w) * creg[3] + sigf(zi.w) * tanh_(zg.w);
      float hv0 = sigf(zo.x) * tanh_(cn0);
      float hv1 = sigf(zo.y) * tanh_(cn1);
      float hv2 = sigf(zo.z) * tanh_(cn2);
      float hv3 = sigf(zo.w) * tanh_(cn3);
      creg[0] = cn0; creg[1] = cn1; creg[2] = cn2; creg[3] = cn3;
      st64(&h2d[(size_t)((t + 1) & 1) * 4096 + (bg * 32 + row32) * 64 + colwg * 8 + hq8],
           pack4(hv0, hv1, hv2, hv3));
      if (t == TT - 1) {
        *(float4*)&h_last[(size_t)d * 16384 + (bg * 32 + row32) * 256 + colwg * 32 + hq8 * 4]
            = make_float4(hv0, hv1, hv2, hv3);
      }
    }
    __builtin_amdgcn_s_waitcnt(0);
    __syncthreads();
    if (tid == 0) st32(&h2f[d * 16 + sub], (unsigned)(t + 1));
  }
}

// ------------------------------------------------ head
__global__ __launch_bounds__(256) void k7_d1(const float* __restrict__ h_last,
    const float* __restrict__ d1_W, const float* __restrict__ d1_b, float* __restrict__ d1o)
{
  __shared__ float Asl[64 * 256];
  __shared__ float Bsl[256 * 64];
  const int nt = blockIdx.x, br = blockIdx.y, tid = threadIdx.x;
  const float* hl = h_last + (size_t)br * 16384;
  for (int i = tid; i < 16384; i += 256) Asl[i] = hl[i];
  const float* wp = d1_W + (size_t)br * 65536 + nt * 64;
  for (int i = tid; i < 16384; i += 256) {
    int k = i >> 6, cl = i & 63;
    Bsl[i] = wp[(size_t)k * 256 + cl];
  }
  __syncthreads();
  const int cl = tid & 63, rq = tid >> 6;
  float s[16];
  const float bias = d1_b[br * 256 + nt * 64 + cl];
  #pragma unroll
  for (int i = 0; i < 16; ++i) s[i] = bias;
  for (int k = 0; k < 256; ++k) {
    float bv = Bsl[k * 64 + cl];
    #pragma unroll
    for (int i = 0; i < 16; ++i) s[i] += Asl[(rq * 16 + i) * 256 + k] * bv;
  }
  #pragma unroll
  for (int i = 0; i < 16; ++i)
    d1o[(size_t)br * 16384 + (rq * 16 + i) * 256 + nt * 64 + cl] = fmaxf(s[i], 0.0f);
}

__global__ __launch_bounds__(256) void k8_head(const float* __restrict__ d1o,
    const float* __restrict__ d2_W, const float* __restrict__ d2_b,
    const float* __restrict__ df_W, const float* __restrict__ df_b,
    const float* __restrict__ inputs, float* __restrict__ out)
{
  __shared__ float Asl[64 * 256];
  __shared__ float Bsl[256 * 64];
  __shared__ float d2sT[64 * 65];
  __shared__ float wfs[68];
  const int br = blockIdx.x, tid = threadIdx.x;
  for (int i = tid; i < 16384; i += 256) Asl[i] = d1o[(size_t)br * 16384 + i];
  for (int i = tid; i < 16384; i += 256) Bsl[i] = d2_W[(size_t)br * 16384 + i];
  if (tid < 67) wfs[tid] = df_W[br * 67 + tid];
  __syncthreads();
  const int cl = tid & 63, rq = tid >> 6;
  float s[16];
  const float bias = d2_b[br * 64 + cl];
  #pragma unroll
  for (int i = 0; i < 16; ++i) s[i] = bias;
  for (int k = 0; k < 256; ++k) {
    float bv = Bsl[k * 64 + cl];
    #pragma unroll
    for (int i = 0; i < 16; ++i) s[i] += Asl[(rq * 16 + i) * 256 + k] * bv;
  }
  #pragma unroll
  for (int i = 0; i < 16; ++i) d2sT[cl * 65 + rq * 16 + i] = fmaxf(s[i], 0.0f);
  __syncthreads();
  if (tid < 64) {
    const int b = tid;
    const float* ip = inputs + ((size_t)b * TT + (TT - 1)) * 42;
    float acc = df_b[br] + ip[20 + br] + ip[27] * wfs[64] + ip[27 + br + 1] * wfs[65]
              + ip[27 + br + 8] * wfs[66];
    #pragma unroll 4
    for (int j = 0; j < 64; ++j) acc += d2sT[j * 65 + b] * wfs[j];
    out[b * 7 + br] = acc;
  }
}

// ------------------------------------------------ host
extern "C" void kernel_launch(void* const* d_in, const int* in_sizes, int n_in,
                              void* d_out, int out_size, void* d_ws, size_t ws_size,
                              hipStream_t stream) {
  (void)in_sizes; (void)n_in; (void)out_size;
  const float* inputs  = (const float*)d_in[0];
  const float* eco_Wk  = (const float*)d_in[1];
  const float* eco_Wr  = (const float*)d_in[2];
  const float* eco_b   = (const float*)d_in[3];
  const float* data_Wk = (const float*)d_in[4];
  const float* data_Wr = (const float*)d_in[5];
  const float* data_b  = (const float*)d_in[6];
  const float* att_Wk  = (const float*)d_in[7];
  const float* att_Wr  = (const float*)d_in[8];
  const float* att_b   = (const float*)d_in[9];
  const float* ts_Wk   = (const float*)d_in[10];
  const float* ts_Wr   = (const float*)d_in[11];
  const float* ts_b    = (const float*)d_in[12];
  const float* d1_W    = (const float*)d_in[13];
  const float* d1_b    = (const float*)d_in[14];
  const float* d2_W    = (const float*)d_in[15];
  const float* d2_b    = (const float*)d_in[16];
  const float* df_W    = (const float*)d_in[17];
  const float* df_b    = (const float*)d_in[18];

  char* ws = (char*)d_ws;
  size_t off = 0;
  auto take = [&](size_t bytes) -> void* {
    void* p = ws + off;
    off += (bytes + 255) & ~(size_t)255;
    return p;
  };
  unsigned short* wr_swz = (unsigned short*)take((size_t)22 * 262144 * 2);
  unsigned short* wk_da  = (unsigned short*)take((size_t)14 * 262144 * 2);
  unsigned short* wk_ts  = (unsigned short*)take((size_t)7  * 262144 * 2);
  unsigned short* xw_eco = (unsigned short*)take((size_t)TT * 65536 * 2);
  unsigned short* hsD    = (unsigned short*)take((size_t)7 * TT * 16384 * 2);
  unsigned short* hsA_   = (unsigned short*)take((size_t)7 * TT * 16384 * 2);
  float*          h_last = (float*)take((size_t)7 * 16384 * 4);
  float*          d1o    = (float*)take((size_t)7 * 16384 * 4);
  // --- sync region (contiguous, memset each launch) ---
  size_t sync_begin = off;
  unsigned long long* hE = (unsigned long long*)take((size_t)RE * 4096 * 8);
  unsigned long long* hD = (unsigned long long*)take((size_t)14 * 8192 * 8);
  unsigned long long* h2 = (unsigned long long*)take((size_t)7 * 8192 * 8);
  unsigned* hEf = (unsigned*)take(16 * 4);
  unsigned* hDf = (unsigned*)take(112 * 4);
  unsigned* h2f = (unsigned*)take(112 * 4);
  size_t sync_bytes = off - sync_begin;
  if (off > ws_size) return;   // fail loudly (output stays zero)

  hipMemsetAsync(ws + sync_begin, 0, sync_bytes, stream);
  k0a_wr<<<dim3(8, 8, 22), 256, 0, stream>>>(eco_Wr, data_Wr, att_Wr, ts_Wr, wr_swz);
  k0b_wk<<<dim3(4, 8, 21), 256, 0, stream>>>(data_Wk, att_Wk, ts_Wk, wk_da, wk_ts);
  k1_ecoxw<<<dim3(TT, 4), 256, 0, stream>>>(inputs, eco_Wk, eco_b, xw_eco);
  kA<<<128, 256, 0, stream>>>(wr_swz, wk_da, xw_eco, inputs,
                              data_Wk, att_Wk, data_b, att_b,
                              hE, hD, hEf, hDf, hsD, hsA_);
  kB<<<112, 256, 0, stream>>>(wr_swz, wk_ts, ts_b, hsD, hsA_, h2, h2f, h_last);
  k7_d1<<<dim3(4, 7), 256, 0, stream>>>(h_last, d1_W, d1_b, d1o);
  k8_head<<<7, 256, 0, stream>>>(d1o, d2_W, d2_b, df_W, df_b, inputs, (float*)d_out);
}

// Round 7
// 3923.675 us; speedup vs baseline: 4.5301x; 1.2426x over previous
//
#include <hip/hip_runtime.h>

// MM_LSTM_Age_v2 on MI355X — single fused systolic pipeline.
// k0a/k0b: weight transpose->bf16.  k1: eco xW (full T).
// kP (240 WGs, 1 block/CU, co-resident): rec0(16) + rec1(112, xW fused with
//   Wk in VGPRs) + rec2(112, ts-xW fused, A = hsD*hsA from tagged rings).
//   ALL cross-WG h/hs exchange: tag-embedded u64 {state(hi32), 2xbf16(lo32)}
//   relaxed agent atomics — single round trip, consumers repoll stale words.
//   Flags (hDf/h2f) only as lagged ring-overwrite guards (distance 4).
// k7/k8: dense head.

#define TT 365
#define RE 4   // eco h ring slots
#define RS 4   // hs (data/att -> ts) ring slots

typedef short bf16x8 __attribute__((ext_vector_type(8)));
typedef float f32x4 __attribute__((ext_vector_type(4)));

__device__ __forceinline__ float b2f(unsigned short u) {
  union { unsigned u32; float f; } v; v.u32 = ((unsigned)u) << 16; return v.f;
}
__device__ __forceinline__ unsigned short f2b(float f) {
  union { float f; unsigned u32; } v; v.f = f;
  unsigned u = v.u32;
  u = u + 0x7FFFu + ((u >> 16) & 1u);   // RNE
  return (unsigned short)(u >> 16);
}
__device__ __forceinline__ float sigf(float x) { return 1.0f / (1.0f + __expf(-x)); }
__device__ __forceinline__ float tanh_(float x) { return 2.0f / (1.0f + __expf(-2.0f * x)) - 1.0f; }

__device__ __forceinline__ unsigned long long ld64(const unsigned long long* p) {
  return __hip_atomic_load(p, __ATOMIC_RELAXED, __HIP_MEMORY_SCOPE_AGENT);
}
__device__ __forceinline__ void st64(unsigned long long* p, unsigned long long v) {
  __hip_atomic_store(p, v, __ATOMIC_RELAXED, __HIP_MEMORY_SCOPE_AGENT);
}
__device__ __forceinline__ unsigned ld32(const unsigned* p) {
  return __hip_atomic_load(p, __ATOMIC_RELAXED, __HIP_MEMORY_SCOPE_AGENT);
}
__device__ __forceinline__ void st32(unsigned* p, unsigned v) {
  __hip_atomic_store(p, v, __ATOMIC_RELAXED, __HIP_MEMORY_SCOPE_AGENT);
}
__device__ __forceinline__ unsigned long long tag2(unsigned tag, float a, float b) {
  return ((unsigned long long)tag << 32) | (unsigned)f2b(a) | ((unsigned)f2b(b) << 16);
}

// ------------------------------------------------ k0a: Wr transpose -> bf16
// wr_swz per (lstm,wg): [kb 8][col 128][ks 32], col = gate*32+hi
__global__ __launch_bounds__(256) void k0a_wr(const float* __restrict__ eco_Wr,
    const float* __restrict__ data_Wr, const float* __restrict__ att_Wr,
    const float* __restrict__ ts_Wr, unsigned short* __restrict__ wr_swz)
{
  __shared__ float ls[32 * 133];
  const int kb = blockIdx.x, wg = blockIdx.y, l = blockIdx.z, tid = threadIdx.x;
  const float* src;
  if (l == 0) src = eco_Wr;
  else if (l < 15) { int d = l - 1; src = ((d & 1) ? att_Wr : data_Wr) + (size_t)(d >> 1) * 262144; }
  else src = ts_Wr + (size_t)(l - 15) * 262144;
  for (int e = tid; e < 4096; e += 256) {
    int ks = e >> 7, col = e & 127;
    int gate = col >> 5, hi = col & 31;
    ls[ks * 133 + col] = src[(size_t)(kb * 32 + ks) * 1024 + gate * 256 + wg * 32 + hi];
  }
  __syncthreads();
  unsigned short* out = wr_swz + (((size_t)l * 8 + wg) * 8 + kb) * 4096;
  for (int e = tid; e < 4096; e += 256) {
    int col = e >> 5, ks = e & 31;
    out[e] = f2b(ls[ks * 133 + col]);
  }
}

// ------------------------------------------------ k0b: Wk transpose -> bf16
// wk layout per lstm: [kb 8][col 1024][ks 32] (data/att use K rows 4..259)
__global__ __launch_bounds__(256) void k0b_wk(const float* __restrict__ data_Wk,
    const float* __restrict__ att_Wk, const float* __restrict__ ts_Wk,
    unsigned short* __restrict__ wk_da, unsigned short* __restrict__ wk_ts)
{
  __shared__ float ls[32 * 261];
  const int cc = blockIdx.x, kb = blockIdx.y, d = blockIdx.z, tid = threadIdx.x;
  const float* src; unsigned short* dst; int roff;
  if (d < 14) { src = ((d & 1) ? att_Wk : data_Wk) + (size_t)(d >> 1) * 266240;
                dst = wk_da + (size_t)d * 262144; roff = 4; }
  else { src = ts_Wk + (size_t)(d - 14) * 262144;
         dst = wk_ts + (size_t)(d - 14) * 262144; roff = 0; }
  for (int e = tid; e < 8192; e += 256) {
    int ks = e >> 8, c2 = e & 255;
    ls[ks * 261 + c2] = src[(size_t)(roff + kb * 32 + ks) * 1024 + cc * 256 + c2];
  }
  __syncthreads();
  for (int e = tid; e < 8192; e += 256) {
    int col2 = e >> 5, ks = e & 31;
    dst[(size_t)kb * 32768 + (cc * 256 + col2) * 32 + ks] = f2b(ls[ks * 261 + col2]);
  }
}

// ------------------------------------------------ k1: eco xW full T
__global__ __launch_bounds__(256) void k1_ecoxw(const float* __restrict__ inputs,
    const float* __restrict__ eco_Wk, const float* __restrict__ eco_b,
    unsigned short* __restrict__ xw_eco)
{
  __shared__ float Asl[64 * 35];
  __shared__ float Bsl[35 * 256];
  const int tg = blockIdx.x, ct = blockIdx.y, tid = threadIdx.x;
  for (int i = tid; i < 64 * 35; i += 256) {
    int b = i / 35, k = i - b * 35;
    int col = (k < 20) ? k : (k + 7);
    Asl[i] = inputs[((size_t)b * TT + tg) * 42 + col];
  }
  for (int i = tid; i < 35 * 256; i += 256) {
    int k = i >> 8, c = i & 255;
    Bsl[i] = eco_Wk[(size_t)k * 1024 + ct * 256 + c];
  }
  __syncthreads();
  const float bias = eco_b[ct * 256 + tid];
  for (int r = 0; r < 64; ++r) {
    float s = bias;
    #pragma unroll
    for (int k = 0; k < 35; ++k) s += Asl[r * 35 + k] * Bsl[k * 256 + tid];
    xw_eco[((size_t)tg * 64 + r) * 1024 + ct * 256 + tid] = f2b(s);
  }
}

// ================================================ kP: full systolic pipeline
// hE:  u64[RE][64 row][128 kp]              (eco h, tag = state)
// hD:  per l1 u64[2][64][128]               (data/att own h)
// hsD/hsA: per br u64[RS][64][128]          (hs streams to ts, tag = t+1)
// h2:  per d u64[2][64][128]                (ts own h)
// hDf[112] (l1*8+colwg), h2f[112] (d*16+sub): lagged progress guards.
__global__ __launch_bounds__(256, 1) void kP(
    const unsigned short* __restrict__ wr_swz,
    const unsigned short* __restrict__ wk_da,
    const unsigned short* __restrict__ wk_ts,
    const unsigned short* __restrict__ xw_eco,
    const float* __restrict__ inputs,
    const float* __restrict__ data_Wk, const float* __restrict__ att_Wk,
    const float* __restrict__ data_b, const float* __restrict__ att_b,
    const float* __restrict__ ts_b,
    unsigned long long* __restrict__ hE,
    unsigned long long* __restrict__ hD,
    unsigned long long* __restrict__ hsD,
    unsigned long long* __restrict__ hsA,
    unsigned long long* __restrict__ h2,
    unsigned* __restrict__ hDf, unsigned* __restrict__ h2f,
    float* __restrict__ h_last)
{
  __shared__ __align__(16) unsigned char smem[160256];
  const int tid = threadIdx.x;
  const int widx = blockIdx.x;
  const int lane = tid & 63, w = tid >> 6, c = lane & 15, grp = lane >> 4;

  if (widx < 16) {
    // ================= rec0: eco LSTM, 32 batch x 32 hid per WG
    unsigned short* WR = (unsigned short*)smem;             // 81920
    unsigned short* Hs = (unsigned short*)(smem + 81920);   // 20480
    float* zsh = (float*)(smem + 102400);                   // 16896
    float* cst = (float*)(smem + 119296);                   // 4096
    const int wg = widx >> 1, bg = widx & 1;
    const unsigned short* wr_g = wr_swz + (size_t)wg * 32768;
    for (int i = tid * 8; i < 32768; i += 2048) {
      int kb = i >> 12; int rr = i & 4095; int col = rr >> 5; int ks = rr & 31;
      *(uint4*)&WR[(kb * 128 + col) * 40 + ks] = *(const uint4*)&wr_g[i];
    }
    for (int i = tid; i < 1024; i += 256) cst[i] = 0.0f;

    int xoff[16];
    #pragma unroll
    for (int rt = 0; rt < 2; ++rt)
      #pragma unroll
      for (int ct = 0; ct < 2; ++ct)
        #pragma unroll
        for (int rg = 0; rg < 4; ++rg)
          xoff[(rt * 2 + ct) * 4 + rg] =
              (bg * 32 + rt * 16 + grp * 4 + rg) * 1024 + w * 256 + wg * 32 + ct * 16 + c;
    unsigned short xv[16], xn[16];
    #pragma unroll
    for (int i = 0; i < 16; ++i) xv[i] = xw_eco[xoff[i]];
    __syncthreads();

    for (int t = 0; t < TT; ++t) {
      // lagged ring guard: rec1 must have consumed the slot we overwrite
      if (t + 1 > RE && tid < 112) {
        while ((int)ld32(&hDf[tid]) < t + 1 - RE) __builtin_amdgcn_s_sleep(2);
      }
      { // tag-polled gather of own state t
        const unsigned long long* hb = hE + (size_t)(t % RE) * 8192;
        unsigned long long v[16];
        #pragma unroll
        for (int i = 0; i < 16; ++i) {
          int m = tid + i * 256;
          v[i] = ld64(&hb[(bg * 32 + (m >> 7)) * 128 + (m & 127)]);
        }
        const unsigned tagv = (unsigned)t;
        int tries = 0;
        while (true) {
          unsigned pend = 0u;
          #pragma unroll
          for (int i = 0; i < 16; ++i)
            pend |= ((unsigned)(v[i] >> 32) != tagv) ? (1u << i) : 0u;
          if (!pend) break;
          if (++tries > 8) __builtin_amdgcn_s_sleep(1);
          #pragma unroll
          for (int i = 0; i < 16; ++i)
            if (pend & (1u << i)) {
              int m = tid + i * 256;
              v[i] = ld64(&hb[(bg * 32 + (m >> 7)) * 128 + (m & 127)]);
            }
        }
        #pragma unroll
        for (int i = 0; i < 16; ++i) {
          int m = tid + i * 256, row = m >> 7, kp = m & 127;
          *(unsigned int*)&Hs[((kp >> 4) * 32 + row) * 40 + 2 * (kp & 15)] = (unsigned int)v[i];
        }
      }
      __syncthreads();
      f32x4 acc[4];
      #pragma unroll
      for (int i = 0; i < 4; ++i)
        #pragma unroll
        for (int rg = 0; rg < 4; ++rg) acc[i][rg] = b2f(xv[i * 4 + rg]);
      if (t + 1 < TT) {
        const unsigned short* xw1 = xw_eco + (size_t)(t + 1) * 65536;
        #pragma unroll
        for (int i = 0; i < 16; ++i) xn[i] = xw1[xoff[i]];
      }
      #pragma unroll
      for (int kb = 0; kb < 8; ++kb) {
        bf16x8 a0 = *(const bf16x8*)&Hs[(kb * 32 + c) * 40 + grp * 8];
        bf16x8 a1 = *(const bf16x8*)&Hs[(kb * 32 + 16 + c) * 40 + grp * 8];
        bf16x8 b0 = *(const bf16x8*)&WR[(kb * 128 + w * 32 + c) * 40 + grp * 8];
        bf16x8 b1 = *(const bf16x8*)&WR[(kb * 128 + w * 32 + 16 + c) * 40 + grp * 8];
        acc[0] = __builtin_amdgcn_mfma_f32_16x16x32_bf16(a0, b0, acc[0], 0, 0, 0);
        acc[1] = __builtin_amdgcn_mfma_f32_16x16x32_bf16(a0, b1, acc[1], 0, 0, 0);
        acc[2] = __builtin_amdgcn_mfma_f32_16x16x32_bf16(a1, b0, acc[2], 0, 0, 0);
        acc[3] = __builtin_amdgcn_mfma_f32_16x16x32_bf16(a1, b1, acc[3], 0, 0, 0);
      }
      #pragma unroll
      for (int i = 0; i < 4; ++i) {
        int rt = i >> 1, ct = i & 1;
        #pragma unroll
        for (int rg = 0; rg < 4; ++rg)
          zsh[(rt * 16 + grp * 4 + rg) * 132 + w * 32 + ct * 16 + c] = acc[i][rg];
      }
      __syncthreads();
      { // cell update: 1 row x 4 hid, publish tagged pairs
        int row = tid >> 3, hq8 = tid & 7;
        float4 zi = *(const float4*)&zsh[row * 132 +      hq8 * 4];
        float4 zf = *(const float4*)&zsh[row * 132 + 32 + hq8 * 4];
        float4 zg = *(const float4*)&zsh[row * 132 + 64 + hq8 * 4];
        float4 zo = *(const float4*)&zsh[row * 132 + 96 + hq8 * 4];
        float4 c0 = *(const float4*)&cst[row * 32 + hq8 * 4];
        float cn0 = sigf(zf.x) * c0.x + sigf(zi.x) * tanh_(zg.x);
        float cn1 = sigf(zf.y) * c0.y + sigf(zi.y) * tanh_(zg.y);
        float cn2 = sigf(zf.z) * c0.z + sigf(zi.z) * tanh_(zg.z);
        float cn3 = sigf(zf.w) * c0.w + sigf(zi.w) * tanh_(zg.w);
        float hv0 = sigf(zo.x) * tanh_(cn0);
        float hv1 = sigf(zo.y) * tanh_(cn1);
        float hv2 = sigf(zo.z) * tanh_(cn2);
        float hv3 = sigf(zo.w) * tanh_(cn3);
        *(float4*)&cst[row * 32 + hq8 * 4] = make_float4(cn0, cn1, cn2, cn3);
        unsigned long long* ho = hE + (size_t)((t + 1) % RE) * 8192
                               + (bg * 32 + row) * 128 + wg * 16 + hq8 * 2;
        st64(&ho[0], tag2(t + 1, hv0, hv1));
        st64(&ho[1], tag2(t + 1, hv2, hv3));
      }
      __syncthreads();
      #pragma unroll
      for (int i = 0; i < 16; ++i) xv[i] = xn[i];
    }
  } else if (widx < 128) {
    // ================= rec1: data/att LSTM l1, 64 batch x 32 hid, xW fused
    unsigned short* WR = (unsigned short*)smem;             // 81920
    unsigned short* Hs = (unsigned short*)(smem + 81920);   // 40960
    float* zsh = (float*)(smem + 122880);                   // 33792
    float* a_sp = (float*)(smem + 156672);                  // 1024
    float* b_sp = (float*)(smem + 157696);                  // 2048
    float* bias_s = (float*)(smem + 159744);                // 512
    const int q = widx - 16, l1 = q >> 3, colwg = q & 7, br = l1 >> 1;
    const bool act_sig = (l1 & 1);
    const unsigned short* wr_g = wr_swz + ((size_t)(1 + l1) * 8 + colwg) * 32768;
    for (int i = tid * 8; i < 32768; i += 2048) {
      int kb = i >> 12; int rr = i & 4095; int col = rr >> 5; int ks = rr & 31;
      *(uint4*)&WR[(kb * 128 + col) * 40 + ks] = *(const uint4*)&wr_g[i];
    }
    bf16x8 wkf[16];
    const unsigned short* wk = wk_da + (size_t)l1 * 262144;
    #pragma unroll
    for (int kb = 0; kb < 8; ++kb)
      #pragma unroll
      for (int ct = 0; ct < 2; ++ct) {
        int col = w * 256 + colwg * 32 + ct * 16 + c;
        wkf[kb * 2 + ct] = *(const bf16x8*)&wk[kb * 32768 + col * 32 + grp * 8];
      }
    const float* spWk = (act_sig ? att_Wk : data_Wk) + (size_t)br * 266240;
    for (int i = tid; i < 512; i += 256) {
      int j = i >> 7, colL = i & 127;
      int gcol = (colL >> 5) * 256 + colwg * 32 + (colL & 31);
      b_sp[i] = spWk[(size_t)j * 1024 + gcol];
    }
    if (tid < 128) {
      int gcol = (tid >> 5) * 256 + colwg * 32 + (tid & 31);
      bias_s[tid] = (act_sig ? att_b : data_b)[br * 1024 + gcol];
    }
    float creg[8];
    #pragma unroll
    for (int j = 0; j < 8; ++j) creg[j] = 0.0f;
    unsigned long long* hDl = hD + (size_t)l1 * 2 * 8192;
    unsigned long long* ring = (act_sig ? hsA : hsD) + (size_t)br * RS * 8192;
    __syncthreads();

    for (int t = 0; t < TT; ++t) {
      // lagged ring guard: rec2 must have consumed the hs slot we overwrite
      if (t + 1 > RS && tid < 16) {
        while ((int)ld32(&h2f[br * 16 + tid]) < t + 1 - RS) __builtin_amdgcn_s_sleep(2);
      }
      if (tid < 64) {
        const float* ip = inputs + ((size_t)tid * TT + t) * 42;
        a_sp[tid * 4 + 0] = ip[20 + br];
        a_sp[tid * 4 + 1] = ip[27];
        a_sp[tid * 4 + 2] = ip[27 + br + 1];
        a_sp[tid * 4 + 3] = ip[27 + br + 8];
      }
      // issue both gathers
      const unsigned long long* he = hE + (size_t)((t + 1) % RE) * 8192;
      const unsigned long long* ho = hDl + (size_t)(t & 1) * 8192;
      unsigned long long ve[32], vh[32];
      #pragma unroll
      for (int i = 0; i < 32; ++i) ve[i] = ld64(&he[tid + i * 256]);
      #pragma unroll
      for (int i = 0; i < 32; ++i) vh[i] = ld64(&ho[tid + i * 256]);
      { // poll eco h tags == t+1
        const unsigned tagv = (unsigned)(t + 1);
        int tries = 0;
        while (true) {
          unsigned long long pend = 0ull;
          #pragma unroll
          for (int i = 0; i < 32; ++i)
            pend |= ((unsigned)(ve[i] >> 32) != tagv) ? (1ull << i) : 0ull;
          if (!pend) break;
          if (++tries > 8) __builtin_amdgcn_s_sleep(1);
          #pragma unroll
          for (int i = 0; i < 32; ++i)
            if (pend & (1ull << i)) ve[i] = ld64(&he[tid + i * 256]);
        }
      }
      #pragma unroll
      for (int i = 0; i < 32; ++i) {
        int m = tid + i * 256, row = m >> 7, kp = m & 127;
        *(unsigned int*)&Hs[((kp >> 4) * 64 + row) * 40 + 2 * (kp & 15)] = (unsigned int)ve[i];
      }
      __syncthreads();
      // xW MFMA (A = eco h, B = Wk regs)
      f32x4 acc[8] = {};
      #pragma unroll
      for (int kb = 0; kb < 8; ++kb) {
        bf16x8 a[4];
        #pragma unroll
        for (int rt = 0; rt < 4; ++rt)
          a[rt] = *(const bf16x8*)&Hs[(kb * 64 + rt * 16 + c) * 40 + grp * 8];
        #pragma unroll
        for (int rt = 0; rt < 4; ++rt)
          #pragma unroll
          for (int ct = 0; ct < 2; ++ct)
            acc[rt * 2 + ct] = __builtin_amdgcn_mfma_f32_16x16x32_bf16(a[rt], wkf[kb * 2 + ct], acc[rt * 2 + ct], 0, 0, 0);
      }
      #pragma unroll
      for (int i = 0; i < 8; ++i) {
        int rt = i >> 1, ct2 = i & 1;
        #pragma unroll
        for (int rg = 0; rg < 4; ++rg) {
          int row = rt * 16 + grp * 4 + rg;
          int colL = w * 32 + ct2 * 16 + c;
          acc[i][rg] += bias_s[colL]
                      + a_sp[row * 4 + 0] * b_sp[colL]       + a_sp[row * 4 + 1] * b_sp[128 + colL]
                      + a_sp[row * 4 + 2] * b_sp[256 + colL] + a_sp[row * 4 + 3] * b_sp[384 + colL];
        }
      }
      { // poll own h tags == t (usually instant)
        const unsigned tagv = (unsigned)t;
        int tries = 0;
        while (true) {
          unsigned long long pend = 0ull;
          #pragma unroll
          for (int i = 0; i < 32; ++i)
            pend |= ((unsigned)(vh[i] >> 32) != tagv) ? (1ull << i) : 0ull;
          if (!pend) break;
          if (++tries > 8) __builtin_amdgcn_s_sleep(1);
          #pragma unroll
          for (int i = 0; i < 32; ++i)
            if (pend & (1ull << i)) vh[i] = ld64(&ho[tid + i * 256]);
        }
      }
      __syncthreads();                 // everyone done reading Hs (eco h)
      #pragma unroll
      for (int i = 0; i < 32; ++i) {
        int m = tid + i * 256, row = m >> 7, kp = m & 127;
        *(unsigned int*)&Hs[((kp >> 4) * 64 + row) * 40 + 2 * (kp & 15)] = (unsigned int)vh[i];
      }
      __syncthreads();
      // recurrent MFMA (A = own h, B = Wr LDS)
      #pragma unroll
      for (int kb = 0; kb < 8; ++kb) {
        bf16x8 a[4]; bf16x8 b[2];
        #pragma unroll
        for (int rt = 0; rt < 4; ++rt)
          a[rt] = *(const bf16x8*)&Hs[(kb * 64 + rt * 16 + c) * 40 + grp * 8];
        #pragma unroll
        for (int ct = 0; ct < 2; ++ct)
          b[ct] = *(const bf16x8*)&WR[(kb * 128 + w * 32 + ct * 16 + c) * 40 + grp * 8];
        #pragma unroll
        for (int rt = 0; rt < 4; ++rt)
          #pragma unroll
          for (int ct = 0; ct < 2; ++ct)
            acc[rt * 2 + ct] = __builtin_amdgcn_mfma_f32_16x16x32_bf16(a[rt], b[ct], acc[rt * 2 + ct], 0, 0, 0);
      }
      #pragma unroll
      for (int i = 0; i < 8; ++i) {
        int rt = i >> 1, ct2 = i & 1;
        #pragma unroll
        for (int rg = 0; rg < 4; ++rg)
          zsh[(rt * 16 + grp * 4 + rg) * 132 + w * 32 + ct2 * 16 + c] = acc[i][rg];
      }
      __syncthreads();
      { // cell: 2 items x 4 hid; publish own h (2-slot) + hs ring (tag t+1)
        unsigned long long* hon = hDl + (size_t)((t + 1) & 1) * 8192;
        unsigned long long* rs = ring + (size_t)(t % RS) * 8192;
        #pragma unroll
        for (int it = 0; it < 2; ++it) {
          int m = tid + it * 256, row = m >> 3, hq8 = m & 7;
          float4 zi = *(const float4*)&zsh[row * 132 +      hq8 * 4];
          float4 zf = *(const float4*)&zsh[row * 132 + 32 + hq8 * 4];
          float4 zg = *(const float4*)&zsh[row * 132 + 64 + hq8 * 4];
          float4 zo = *(const float4*)&zsh[row * 132 + 96 + hq8 * 4];
          float g0 = act_sig ? sigf(zg.x) : tanh_(zg.x);
          float g1 = act_sig ? sigf(zg.y) : tanh_(zg.y);
          float g2 = act_sig ? sigf(zg.z) : tanh_(zg.z);
          float g3 = act_sig ? sigf(zg.w) : tanh_(zg.w);
          float cn0 = sigf(zf.x) * creg[it * 4 + 0] + sigf(zi.x) * g0;
          float cn1 = sigf(zf.y) * creg[it * 4 + 1] + sigf(zi.y) * g1;
          float cn2 = sigf(zf.z) * creg[it * 4 + 2] + sigf(zi.z) * g2;
          float cn3 = sigf(zf.w) * creg[it * 4 + 3] + sigf(zi.w) * g3;
          float hv0 = sigf(zo.x) * (act_sig ? sigf(cn0) : tanh_(cn0));
          float hv1 = sigf(zo.y) * (act_sig ? sigf(cn1) : tanh_(cn1));
          float hv2 = sigf(zo.z) * (act_sig ? sigf(cn2) : tanh_(cn2));
          float hv3 = sigf(zo.w) * (act_sig ? sigf(cn3) : tanh_(cn3));
          creg[it * 4 + 0] = cn0; creg[it * 4 + 1] = cn1;
          creg[it * 4 + 2] = cn2; creg[it * 4 + 3] = cn3;
          int kp = colwg * 16 + hq8 * 2;
          unsigned long long w0 = tag2(t + 1, hv0, hv1);
          unsigned long long w1 = tag2(t + 1, hv2, hv3);
          st64(&hon[row * 128 + kp], w0);
          st64(&hon[row * 128 + kp + 1], w1);
          st64(&rs[row * 128 + kp], w0);
          st64(&rs[row * 128 + kp + 1], w1);
        }
      }
      __builtin_amdgcn_s_waitcnt(0);
      __syncthreads();
      if (tid == 0) st32(&hDf[q], (unsigned)(t + 1));   // lagged guard only
    }
  } else {
    // ================= rec2: ts LSTM d, 32 batch x 32 hid, xW fused
    unsigned short* WR = (unsigned short*)smem;             // 81920
    unsigned short* Hs = (unsigned short*)(smem + 81920);   // 20480
    float* zsh = (float*)(smem + 102400);                   // 16896
    float* bias_s = (float*)(smem + 119296);                // 512
    const int r = widx - 128, d = r >> 4, sub = r & 15, colwg = sub >> 1, bg = sub & 1;
    const unsigned short* wr_g = wr_swz + ((size_t)(15 + d) * 8 + colwg) * 32768;
    for (int i = tid * 8; i < 32768; i += 2048) {
      int kb = i >> 12; int rr = i & 4095; int col = rr >> 5; int ks = rr & 31;
      *(uint4*)&WR[(kb * 128 + col) * 40 + ks] = *(const uint4*)&wr_g[i];
    }
    bf16x8 wkf[16];
    const unsigned short* wk = wk_ts + (size_t)d * 262144;
    #pragma unroll
    for (int kb = 0; kb < 8; ++kb)
      #pragma unroll
      for (int ct = 0; ct < 2; ++ct) {
        int col = w * 256 + colwg * 32 + ct * 16 + c;
        wkf[kb * 2 + ct] = *(const bf16x8*)&wk[kb * 32768 + col * 32 + grp * 8];
      }
    if (tid < 128) {
      int gcol = (tid >> 5) * 256 + colwg * 32 + (tid & 31);
      bias_s[tid] = ts_b[d * 1024 + gcol];
    }
    float creg[4] = {0.0f, 0.0f, 0.0f, 0.0f};
    const unsigned long long* rD = hsD + (size_t)d * RS * 8192;
    const unsigned long long* rA = hsA + (size_t)d * RS * 8192;
    unsigned long long* h2d = h2 + (size_t)d * 2 * 8192;
    __syncthreads();

    for (int t = 0; t < TT; ++t) {
      const unsigned long long* sd = rD + (size_t)(t % RS) * 8192;
      const unsigned long long* sa = rA + (size_t)(t % RS) * 8192;
      const unsigned long long* ho = h2d + (size_t)(t & 1) * 8192;
      unsigned long long vd[16], va[16], vh[16];
      int idx16[16];
      #pragma unroll
      for (int i = 0; i < 16; ++i) {
        int m = tid + i * 256;
        idx16[i] = (bg * 32 + (m >> 7)) * 128 + (m & 127);
      }
      #pragma unroll
      for (int i = 0; i < 16; ++i) vd[i] = ld64(&sd[idx16[i]]);
      #pragma unroll
      for (int i = 0; i < 16; ++i) va[i] = ld64(&sa[idx16[i]]);
      #pragma unroll
      for (int i = 0; i < 16; ++i) vh[i] = ld64(&ho[idx16[i]]);
      { // poll hs tags == t+1 (both rings)
        const unsigned tagv = (unsigned)(t + 1);
        int tries = 0;
        while (true) {
          unsigned pend = 0u;
          #pragma unroll
          for (int i = 0; i < 16; ++i) {
            pend |= ((unsigned)(vd[i] >> 32) != tagv) ? (1u << i) : 0u;
            pend |= ((unsigned)(va[i] >> 32) != tagv) ? (0x10000u << i) : 0u;
          }
          if (!pend) break;
          if (++tries > 8) __builtin_amdgcn_s_sleep(1);
          #pragma unroll
          for (int i = 0; i < 16; ++i) {
            if (pend & (1u << i)) vd[i] = ld64(&sd[idx16[i]]);
            if (pend & (0x10000u << i)) va[i] = ld64(&sa[idx16[i]]);
          }
        }
      }
      #pragma unroll
      for (int i = 0; i < 16; ++i) {  // product -> Hs
        int m = tid + i * 256, row = m >> 7, kp = m & 127;
        unsigned dl = (unsigned)vd[i], al = (unsigned)va[i];
        float p0 = b2f((unsigned short)dl) * b2f((unsigned short)al);
        float p1 = b2f((unsigned short)(dl >> 16)) * b2f((unsigned short)(al >> 16));
        unsigned pv = (unsigned)f2b(p0) | ((unsigned)f2b(p1) << 16);
        *(unsigned int*)&Hs[((kp >> 4) * 32 + row) * 40 + 2 * (kp & 15)] = pv;
      }
      __syncthreads();
      f32x4 acc[4] = {};
      #pragma unroll
      for (int kb = 0; kb < 8; ++kb) {
        bf16x8 a0 = *(const bf16x8*)&Hs[(kb * 32 + c) * 40 + grp * 8];
        bf16x8 a1 = *(const bf16x8*)&Hs[(kb * 32 + 16 + c) * 40 + grp * 8];
        acc[0] = __builtin_amdgcn_mfma_f32_16x16x32_bf16(a0, wkf[kb * 2 + 0], acc[0], 0, 0, 0);
        acc[1] = __builtin_amdgcn_mfma_f32_16x16x32_bf16(a0, wkf[kb * 2 + 1], acc[1], 0, 0, 0);
        acc[2] = __builtin_amdgcn_mfma_f32_16x16x32_bf16(a1, wkf[kb * 2 + 0], acc[2], 0, 0, 0);
        acc[3] = __builtin_amdgcn_mfma_f32_16x16x32_bf16(a1, wkf[kb * 2 + 1], acc[3], 0, 0, 0);
      }
      #pragma unroll
      for (int i = 0; i < 4; ++i) {
        int ct2 = i & 1;
        #pragma unroll
        for (int rg = 0; rg < 4; ++rg)
          acc[i][rg] += bias_s[w * 32 + ct2 * 16 + c];
      }
      { // poll own h tags == t (instant)
        const unsigned tagv = (unsigned)t;
        int tries = 0;
        while (true) {
          unsigned pend = 0u;
          #pragma unroll
          for (int i = 0; i < 16; ++i)
            pend |= ((unsigned)(vh[i] >> 32) != tagv) ? (1u << i) : 0u;
          if (!pend) break;
          if (++tries > 8) __builtin_amdgcn_s_sleep(1);
          #pragma unroll
          for (int i = 0; i < 16; ++i)
            if (pend & (1u << i)) vh[i] = ld64(&ho[idx16[i]]);
        }
      }
      __syncthreads();
      #pragma unroll
      for (int i = 0; i < 16; ++i) {
        int m = tid + i * 256, row = m >> 7, kp = m & 127;
        *(unsigned int*)&Hs[((kp >> 4) * 32 + row) * 40 + 2 * (kp & 15)] = (unsigned int)vh[i];
      }
      __syncthreads();
      #pragma unroll
      for (int kb = 0; kb < 8; ++kb) {
        bf16x8 a0 = *(const bf16x8*)&Hs[(kb * 32 + c) * 40 + grp * 8];
        bf16x8 a1 = *(const bf16x8*)&Hs[(kb * 32 + 16 + c) * 40 + grp * 8];
        bf16x8 b0 = *(const bf16x8*)&WR[(kb * 128 + w * 32 + c) * 40 + grp * 8];
        bf16x8 b1 = *(const bf16x8*)&WR[(kb * 128 + w * 32 + 16 + c) * 40 + grp * 8];
        acc[0] = __builtin_amdgcn_mfma_f32_16x16x32_bf16(a0, b0, acc[0], 0, 0, 0);
        acc[1] = __builtin_amdgcn_mfma_f32_16x16x32_bf16(a0, b1, acc[1], 0, 0, 0);
        acc[2] = __builtin_amdgcn_mfma_f32_16x16x32_bf16(a1, b0, acc[2], 0, 0, 0);
        acc[3] = __builtin_amdgcn_mfma_f32_16x16x32_bf16(a1, b1, acc[3], 0, 0, 0);
      }
      #pragma unroll
      for (int i = 0; i < 4; ++i) {
        int rt = i >> 1, ct2 = i & 1;
        #pragma unroll
        for (int rg = 0; rg < 4; ++rg)
          zsh[(rt * 16 + grp * 4 + rg) * 132 + w * 32 + ct2 * 16 + c] = acc[i][rg];
      }
      __syncthreads();
      { // cell: 1 row x 4 hid; publish h2 (2-slot)
        int row = tid >> 3, hq8 = tid & 7;
        float4 zi = *(const float4*)&zsh[row * 132 +      hq8 * 4];
        float4 zf = *(const float4*)&zsh[row * 132 + 32 + hq8 * 4];
        float4 zg = *(const float4*)&zsh[row * 132 + 64 + hq8 * 4];
        float4 zo = *(const float4*)&zsh[row * 132 + 96 + hq8 * 4];
        float cn0 = sigf(zf.x) * creg[0] + sigf(zi.x) * tanh_(zg.x);
        float cn1 = sigf(zf.y) * creg[1] + sigf(zi.y) * tanh_(zg.y);
        float cn2 = sigf(zf.z) * creg[2] + sigf(zi.z) * tanh_(zg.z);
        float cn3 = sigf(zf.w) * creg[3] + sigf(zi.w) * tanh_(zg.w);
        float hv0 = sigf(zo.x) * tanh_(cn0);
        float hv1 = sigf(zo.y) * tanh_(cn1);
        float hv2 = sigf(zo.z) * tanh_(cn2);
        float hv3 = sigf(zo.w) * tanh_(cn3);
        creg[0] = cn0; creg[1] = cn1; creg[2] = cn2; creg[3] = cn3;
        unsigned long long* hn = h2d + (size_t)((t + 1) & 1) * 8192
                               + (bg * 32 + row) * 128 + colwg * 16 + hq8 * 2;
        st64(&hn[0], tag2(t + 1, hv0, hv1));
        st64(&hn[1], tag2(t + 1, hv2, hv3));
        if (t == TT - 1) {
          *(float4*)&h_last[(size_t)d * 16384 + (bg * 32 + row) * 256 + colwg * 32 + hq8 * 4]
              = make_float4(hv0, hv1, hv2, hv3);
        }
      }
      __builtin_amdgcn_s_waitcnt(0);
      __syncthreads();
      if (tid == 0) st32(&h2f[d * 16 + sub], (unsigned)(t + 1));   // lagged guard
    }
  }
}

// ------------------------------------------------ head
__global__ __launch_bounds__(256) void k7_d1(const float* __restrict__ h_last,
    const float* __restrict__ d1_W, const float* __restrict__ d1_b, float* __restrict__ d1o)
{
  __shared__ float Asl[64 * 256];
  __shared__ float Bsl[256 * 64];
  const int nt = blockIdx.x, br = blockIdx.y, tid = threadIdx.x;
  const float* hl = h_last + (size_t)br * 16384;
  for (int i = tid; i < 16384; i += 256) Asl[i] = hl[i];
  const float* wp = d1_W + (size_t)br * 65536 + nt * 64;
  for (int i = tid; i < 16384; i += 256) {
    int k = i >> 6, cl = i & 63;
    Bsl[i] = wp[(size_t)k * 256 + cl];
  }
  __syncthreads();
  const int cl = tid & 63, rq = tid >> 6;
  float s[16];
  const float bias = d1_b[br * 256 + nt * 64 + cl];
  #pragma unroll
  for (int i = 0; i < 16; ++i) s[i] = bias;
  for (int k = 0; k < 256; ++k) {
    float bv = Bsl[k * 64 + cl];
    #pragma unroll
    for (int i = 0; i < 16; ++i) s[i] += Asl[(rq * 16 + i) * 256 + k] * bv;
  }
  #pragma unroll
  for (int i = 0; i < 16; ++i)
    d1o[(size_t)br * 16384 + (rq * 16 + i) * 256 + nt * 64 + cl] = fmaxf(s[i], 0.0f);
}

__global__ __launch_bounds__(256) void k8_head(const float* __restrict__ d1o,
    const float* __restrict__ d2_W, const float* __restrict__ d2_b,
    const float* __restrict__ df_W, const float* __restrict__ df_b,
    const float* __restrict__ inputs, float* __restrict__ out)
{
  __shared__ float Asl[64 * 256];
  __shared__ float Bsl[256 * 64];
  __shared__ float d2sT[64 * 65];
  __shared__ float wfs[68];
  const int br = blockIdx.x, tid = threadIdx.x;
  for (int i = tid; i < 16384; i += 256) Asl[i] = d1o[(size_t)br * 16384 + i];
  for (int i = tid; i < 16384; i += 256) Bsl[i] = d2_W[(size_t)br * 16384 + i];
  if (tid < 67) wfs[tid] = df_W[br * 67 + tid];
  __syncthreads();
  const int cl = tid & 63, rq = tid >> 6;
  float s[16];
  const float bias = d2_b[br * 64 + cl];
  #pragma unroll
  for (int i = 0; i < 16; ++i) s[i] = bias;
  for (int k = 0; k < 256; ++k) {
    float bv = Bsl[k * 64 + cl];
    #pragma unroll
    for (int i = 0; i < 16; ++i) s[i] += Asl[(rq * 16 + i) * 256 + k] * bv;
  }
  #pragma unroll
  for (int i = 0; i < 16; ++i) d2sT[cl * 65 + rq * 16 + i] = fmaxf(s[i], 0.0f);
  __syncthreads();
  if (tid < 64) {
    const int b = tid;
    const float* ip = inputs + ((size_t)b * TT + (TT - 1)) * 42;
    float acc = df_b[br] + ip[20 + br] + ip[27] * wfs[64] + ip[27 + br + 1] * wfs[65]
              + ip[27 + br + 8] * wfs[66];
    #pragma unroll 4
    for (int j = 0; j < 64; ++j) acc += d2sT[j * 65 + b] * wfs[j];
    out[b * 7 + br] = acc;
  }
}

// ------------------------------------------------ host
extern "C" void kernel_launch(void* const* d_in, const int* in_sizes, int n_in,
                              void* d_out, int out_size, void* d_ws, size_t ws_size,
                              hipStream_t stream) {
  (void)in_sizes; (void)n_in; (void)out_size;
  const float* inputs  = (const float*)d_in[0];
  const float* eco_Wk  = (const float*)d_in[1];
  const float* eco_Wr  = (const float*)d_in[2];
  const float* eco_b   = (const float*)d_in[3];
  const float* data_Wk = (const float*)d_in[4];
  const float* data_Wr = (const float*)d_in[5];
  const float* data_b  = (const float*)d_in[6];
  const float* att_Wk  = (const float*)d_in[7];
  const float* att_Wr  = (const float*)d_in[8];
  const float* att_b   = (const float*)d_in[9];
  const float* ts_Wk   = (const float*)d_in[10];
  const float* ts_Wr   = (const float*)d_in[11];
  const float* ts_b    = (const float*)d_in[12];
  const float* d1_W    = (const float*)d_in[13];
  const float* d1_b    = (const float*)d_in[14];
  const float* d2_W    = (const float*)d_in[15];
  const float* d2_b    = (const float*)d_in[16];
  const float* df_W    = (const float*)d_in[17];
  const float* df_b    = (const float*)d_in[18];

  char* ws = (char*)d_ws;
  size_t off = 0;
  auto take = [&](size_t bytes) -> void* {
    void* p = ws + off;
    off += (bytes + 255) & ~(size_t)255;
    return p;
  };
  unsigned short* wr_swz = (unsigned short*)take((size_t)22 * 262144 * 2);
  unsigned short* wk_da  = (unsigned short*)take((size_t)14 * 262144 * 2);
  unsigned short* wk_ts  = (unsigned short*)take((size_t)7  * 262144 * 2);
  unsigned short* xw_eco = (unsigned short*)take((size_t)TT * 65536 * 2);
  float*          h_last = (float*)take((size_t)7 * 16384 * 4);
  float*          d1o    = (float*)take((size_t)7 * 16384 * 4);
  // --- sync region (contiguous, memset each launch) ---
  size_t sync_begin = off;
  unsigned long long* hE  = (unsigned long long*)take((size_t)RE * 8192 * 8);
  unsigned long long* hD  = (unsigned long long*)take((size_t)14 * 2 * 8192 * 8);
  unsigned long long* hsD = (unsigned long long*)take((size_t)7 * RS * 8192 * 8);
  unsigned long long* hsA = (unsigned long long*)take((size_t)7 * RS * 8192 * 8);
  unsigned long long* h2  = (unsigned long long*)take((size_t)7 * 2 * 8192 * 8);
  unsigned* hDf = (unsigned*)take(112 * 4);
  unsigned* h2f = (unsigned*)take(112 * 4);
  size_t sync_bytes = off - sync_begin;
  if (off > ws_size) return;   // fail loudly (output stays zero)

  hipMemsetAsync(ws + sync_begin, 0, sync_bytes, stream);
  k0a_wr<<<dim3(8, 8, 22), 256, 0, stream>>>(eco_Wr, data_Wr, att_Wr, ts_Wr, wr_swz);
  k0b_wk<<<dim3(4, 8, 21), 256, 0, stream>>>(data_Wk, att_Wk, ts_Wk, wk_da, wk_ts);
  k1_ecoxw<<<dim3(TT, 4), 256, 0, stream>>>(inputs, eco_Wk, eco_b, xw_eco);
  kP<<<240, 256, 0, stream>>>(wr_swz, wk_da, wk_ts, xw_eco, inputs,
                              data_Wk, att_Wk, data_b, att_b, ts_b,
                              hE, hD, hsD, hsA, h2, hDf, h2f, h_last);
  k7_d1<<<dim3(4, 7), 256, 0, stream>>>(h_last, d1_W, d1_b, d1o);
  k8_head<<<7, 256, 0, stream>>>(d1o, d2_W, d2_b, df_W, df_b, inputs, (float*)d_out);
}